// Round 1
// 998.836 us; speedup vs baseline: 2.1315x; 2.1315x over previous
//
#include <hip/hip_runtime.h>
#include <hip/hip_bf16.h>
#include <math.h>

#define N_POOL 2048
#define D_POOL 4608

typedef __hip_bfloat16 bf16;
typedef __attribute__((ext_vector_type(8))) short bf16x8;
typedef __attribute__((ext_vector_type(4))) float f32x4;

// input indices
#define IX 0
#define IPOOL 1
#define IAW0 2
#define IAB0 3
#define IAW1 4
#define IAB1 5
#define IWQ 6
#define IWK 7
#define ILOG 8
#define ITAU 9
#define IWBASE 10
#define IBBASE 11
#define IGAMMA 12
#define ILNS 13
#define ILNB 14
#define IBW0 15
#define IBB0 16
#define IBW1 17
#define IBB1 18

// ---------- helpers ----------
__device__ inline float wsum(float v) {
#pragma unroll
    for (int off = 32; off > 0; off >>= 1) v += __shfl_xor(v, off, 64);
    return v;
}
__device__ inline float ldin(const void* p, size_t i, int f) {
    if (f) return __bfloat162float(((const bf16*)p)[i]);
    return ((const float*)p)[i];
}
__device__ inline float gelu_f(float x) {
    float t = tanhf(0.7978845608028654f * (x + 0.044715f * x * x * x));
    return 0.5f * x * (1.0f + t);
}
__device__ inline unsigned short bfbits(float f) {
    __hip_bfloat16 h = __float2bfloat16(f);
    return *reinterpret_cast<unsigned short*>(&h);
}

// ---------- per-input dtype detector (insurance; inputs measured all-fp32) ----------
struct P19 { const void* p[19]; long n[19]; };

__global__ void detect_all(P19 ip, int* flags) {
    const int j = blockIdx.x;
    const unsigned short* u = (const unsigned short*)ip.p[j];
    long nelem = ip.n[j];
    long nhalf = nelem >> 1; if (nhalf < 1) nhalf = 1;
    long kstep = (nhalf + 8191) >> 13; if (kstep < 1) kstep = 1;
    int W = 0, S = 0, Z = 0, O = 0, C = 0;
    for (long k = threadIdx.x; k * kstep < nhalf; k += 256) {
        long i = k * kstep * 2;
        unsigned short ev = u[i], od = u[i + 1];
        int e = (ev >> 7) & 0xFF;
        if (ev == 0) Z++;
        else if (e >= 90 && e <= 141) S++;
        else W++;
        if (od) O++;
        C++;
    }
    __shared__ int sw[256], ss[256], sz[256], so[256], sc[256];
    sw[threadIdx.x] = W; ss[threadIdx.x] = S; sz[threadIdx.x] = Z;
    so[threadIdx.x] = O; sc[threadIdx.x] = C;
    __syncthreads();
    if (threadIdx.x == 0) {
        int tw = 0, ts = 0, tz = 0, to = 0, tc = 0;
        for (int i = 0; i < 256; i++) {
            tw += sw[i]; ts += ss[i]; tz += sz[i]; to += so[i]; tc += sc[i];
        }
        int f;
        if (tw * 16 > tc) f = 0;
        else if (ts == 0 && tw == 0) f = (to > 0) ? 0 : 1;
        else f = (ts >= tz) ? 1 : 0;
        flags[j] = f;
    }
}

// ---------- generic 64x64 tiled GEMM: C = act(A@B(^T) + bias), fp32 out ----------
template <int TRANSB>
__global__ __launch_bounds__(256) void gemm64(
    const void* __restrict__ A, int lda, int afi,
    const void* __restrict__ B, int ldb, int bfi, size_t boffs,
    const void* __restrict__ bias, int bifi,
    float* __restrict__ C, int ldc,
    int M, int N, int K, int act, const int* __restrict__ flags)
{
    const int fa = (afi >= 0) ? flags[afi] : 0;
    const int fb = (bfi >= 0) ? flags[bfi] : 0;
    const int fbias = (bifi >= 0) ? flags[bifi] : 0;
    __shared__ __align__(16) float As[16][68];
    __shared__ __align__(16) float Bs[16][68];
    const int tid = threadIdx.x;
    const int tx = tid & 15, ty = tid >> 4;
    const int bx = blockIdx.x, by = blockIdx.y;
    float acc[4][4] = {};
    for (int k0 = 0; k0 < K; k0 += 16) {
#pragma unroll
        for (int i = 0; i < 4; i++) {
            int idx = tid + i * 256;
            int m = idx >> 4, kk = idx & 15;
            As[kk][m] = ldin(A, (size_t)(by * 64 + m) * lda + k0 + kk, fa);
        }
#pragma unroll
        for (int i = 0; i < 4; i++) {
            int idx = tid + i * 256;
            if (TRANSB) {
                int nn2 = idx >> 4, kk = idx & 15;
                Bs[kk][nn2] = ldin(B, boffs + (size_t)(bx * 64 + nn2) * ldb + k0 + kk, fb);
            } else {
                int kk = idx >> 6, nn2 = idx & 63;
                Bs[kk][nn2] = ldin(B, boffs + (size_t)(k0 + kk) * ldb + bx * 64 + nn2, fb);
            }
        }
        __syncthreads();
#pragma unroll
        for (int kk = 0; kk < 16; kk++) {
            float4 av4 = *(const float4*)&As[kk][ty * 4];
            float4 bv4 = *(const float4*)&Bs[kk][tx * 4];
            float av[4] = {av4.x, av4.y, av4.z, av4.w};
            float bv[4] = {bv4.x, bv4.y, bv4.z, bv4.w};
#pragma unroll
            for (int i = 0; i < 4; i++)
#pragma unroll
                for (int j = 0; j < 4; j++) acc[i][j] += av[i] * bv[j];
        }
        __syncthreads();
    }
#pragma unroll
    for (int i = 0; i < 4; i++) {
        int m = by * 64 + ty * 4 + i;
#pragma unroll
        for (int j = 0; j < 4; j++) {
            int n = bx * 64 + tx * 4 + j;
            float v = acc[i][j];
            if (bias) v += ldin(bias, n, fbias);
            if (act == 1) v = gelu_f(v);
            C[(size_t)m * ldc + n] = v;
        }
    }
}

// ---------- split-K 64x64 GEMM: atomically accumulates A@B into pre-initialized C ----------
template <int TRANSB>
__global__ __launch_bounds__(256) void gemm64_splitk(
    const void* __restrict__ A, int lda, int afi,
    const void* __restrict__ B, int ldb, int bfi, size_t boffs,
    float* __restrict__ C, int ldc, int KC, const int* __restrict__ flags)
{
    const int fa = (afi >= 0) ? flags[afi] : 0;
    const int fb = (bfi >= 0) ? flags[bfi] : 0;
    __shared__ __align__(16) float As[16][68];
    __shared__ __align__(16) float Bs[16][68];
    const int tid = threadIdx.x;
    const int tx = tid & 15, ty = tid >> 4;
    const int bx = blockIdx.x, by = blockIdx.y;
    const int kbeg = blockIdx.z * KC;
    float acc[4][4] = {};
    for (int k0 = kbeg; k0 < kbeg + KC; k0 += 16) {
#pragma unroll
        for (int i = 0; i < 4; i++) {
            int idx = tid + i * 256;
            int m = idx >> 4, kk = idx & 15;
            As[kk][m] = ldin(A, (size_t)(by * 64 + m) * lda + k0 + kk, fa);
        }
#pragma unroll
        for (int i = 0; i < 4; i++) {
            int idx = tid + i * 256;
            if (TRANSB) {
                int nn2 = idx >> 4, kk = idx & 15;
                Bs[kk][nn2] = ldin(B, boffs + (size_t)(bx * 64 + nn2) * ldb + k0 + kk, fb);
            } else {
                int kk = idx >> 6, nn2 = idx & 63;
                Bs[kk][nn2] = ldin(B, boffs + (size_t)(k0 + kk) * ldb + bx * 64 + nn2, fb);
            }
        }
        __syncthreads();
#pragma unroll
        for (int kk = 0; kk < 16; kk++) {
            float4 av4 = *(const float4*)&As[kk][ty * 4];
            float4 bv4 = *(const float4*)&Bs[kk][tx * 4];
            float av[4] = {av4.x, av4.y, av4.z, av4.w};
            float bv[4] = {bv4.x, bv4.y, bv4.z, bv4.w};
#pragma unroll
            for (int i = 0; i < 4; i++)
#pragma unroll
                for (int j = 0; j < 4; j++) acc[i][j] += av[i] * bv[j];
        }
        __syncthreads();
    }
#pragma unroll
    for (int i = 0; i < 4; i++) {
        int m = by * 64 + ty * 4 + i;
#pragma unroll
        for (int j = 0; j < 4; j++) {
            int n = bx * 64 + tx * 4 + j;
            atomicAdd(&C[(size_t)m * ldc + n], acc[i][j]);
        }
    }
}

// ---------- C[i] = bias[i % N] (or 0) ----------
__global__ __launch_bounds__(256) void init_bias_kernel(
    float* __restrict__ C, const void* __restrict__ bias, int bifi,
    const int* __restrict__ flags, int N, int total)
{
    int i = blockIdx.x * 256 + threadIdx.x;
    if (i >= total) return;
    float v = 0.f;
    if (bias) v = ldin(bias, i % N, (bifi >= 0) ? flags[bifi] : 0);
    C[i] = v;
}

// ---------- keys GEMM, split-K atomic version ----------
// keys[m, a*64+q] += sum_{k in chunk} pool[m,k] * W_K[a,k,q]
__global__ __launch_bounds__(256) void keys_atomic(
    const void* __restrict__ pool, const void* __restrict__ W_K,
    const int* __restrict__ flags, float* __restrict__ keys_out, int KC)
{
    const int fp = flags[IPOOL], fk = flags[IWK];
    __shared__ __align__(16) float As[16][68];
    __shared__ __align__(16) float Bs[16][68];
    const int tid = threadIdx.x;
    const int tx = tid & 15, ty = tid >> 4;
    const int a = blockIdx.x, by = blockIdx.y;
    const int kbeg = blockIdx.z * KC;
    float acc[4][4] = {};
    for (int k0 = kbeg; k0 < kbeg + KC; k0 += 16) {
#pragma unroll
        for (int i = 0; i < 4; i++) {
            int idx = tid + i * 256;
            int m = idx >> 4, kk = idx & 15;
            As[kk][m] = ldin(pool, (size_t)(by * 64 + m) * 4608 + k0 + kk, fp);
        }
#pragma unroll
        for (int i = 0; i < 4; i++) {
            int idx = tid + i * 256;
            int kk = idx >> 6, nn2 = idx & 63;
            Bs[kk][nn2] = ldin(W_K, (size_t)a * 294912 + (size_t)(k0 + kk) * 64 + nn2, fk);
        }
        __syncthreads();
#pragma unroll
        for (int kk = 0; kk < 16; kk++) {
            float4 av4 = *(const float4*)&As[kk][ty * 4];
            float4 bv4 = *(const float4*)&Bs[kk][tx * 4];
            float av[4] = {av4.x, av4.y, av4.z, av4.w};
            float bv[4] = {bv4.x, bv4.y, bv4.z, bv4.w};
#pragma unroll
            for (int i = 0; i < 4; i++)
#pragma unroll
                for (int j = 0; j < 4; j++) acc[i][j] += av[i] * bv[j];
        }
        __syncthreads();
    }
#pragma unroll
    for (int i = 0; i < 4; i++) {
        int m = by * 64 + ty * 4 + i;
#pragma unroll
        for (int j = 0; j < 4; j++) {
            atomicAdd(&keys_out[(size_t)m * 256 + a * 64 + tx * 4 + j], acc[i][j]);
        }
    }
}

// ---------- per-(n,aspect) normalize: kn = keys / (||keys||+1e-8) ----------
__global__ __launch_bounds__(256) void knorm_kernel(
    const float* __restrict__ keys, float* __restrict__ kn)
{
    const int n = blockIdx.x;
    const int a = threadIdx.x >> 6, q = threadIdx.x & 63;
    float v = keys[(size_t)n * 256 + a * 64 + q];
    float ss = wsum(v * v);
    kn[(size_t)n * 256 + a * 64 + q] = v / (sqrtf(ss) + 1e-8f);
}

// ---------- softmax over 4 aspect logits ----------
__global__ void softmax4_kernel(const void* __restrict__ logits,
                                const int* __restrict__ flags, float* __restrict__ w) {
    if (threadIdx.x == 0) {
        int f = flags[ILOG];
        float l0 = ldin(logits, 0, f), l1 = ldin(logits, 1, f);
        float l2 = ldin(logits, 2, f), l3 = ldin(logits, 3, f);
        float m = fmaxf(fmaxf(l0, l1), fmaxf(l2, l3));
        float e0 = expf(l0 - m), e1 = expf(l1 - m), e2 = expf(l2 - m), e3 = expf(l3 - m);
        float s = e0 + e1 + e2 + e3;
        w[0] = e0 / s; w[1] = e1 / s; w[2] = e2 / s; w[3] = e3 / s;
    }
}

// ---------- queries: normalized, aspect-weight folded ----------
__global__ __launch_bounds__(256) void queries_kernel(
    const float* __restrict__ hA, const void* __restrict__ W_Q,
    const int* __restrict__ flags, const float* __restrict__ w, float* __restrict__ qw)
{
    const int f = flags[IWQ];
    const int b = blockIdx.x;
    const int a = threadIdx.x >> 6, q = threadIdx.x & 63;
    const float* ha = hA + b * 256;
    float s = 0.f;
#pragma unroll 4
    for (int d = 0; d < 256; d++)
        s += ha[d] * ldin(W_Q, (size_t)a * 16384 + (size_t)d * 64 + q, f);
    float nrm = sqrtf(wsum(s * s));
    qw[b * 256 + a * 64 + q] = s / (nrm + 1e-8f) * w[a];
}

// ---------- alpha: fp32 alpha (output, b-major) + bf16 alpha (b-major) ----------
__global__ __launch_bounds__(256) void alpha_kernel(
    const float* __restrict__ scores, const void* __restrict__ tau_p,
    const int* __restrict__ flags,
    float* __restrict__ alpha_out, unsigned short* __restrict__ alpha_bf)
{
    const int b = blockIdx.x;
    const int tid = threadIdx.x;
    const float tauv = ldin(tau_p, 0, flags[ITAU]);
    float ar[8];
    float lsum = 0.f;
#pragma unroll
    for (int i = 0; i < 8; i++) {
        int n = i * 256 + tid;
        float s = scores[b * 2048 + n];
        float g = 1.f / (1.f + expf(-(s - tauv)));  // LAMBDA_SHARP=1
        ar[i] = g * expf(s);                         // TEMPERATURE=1
        lsum += ar[i];
    }
    __shared__ float sb[4];
    float wsv = wsum(lsum);
    if ((tid & 63) == 0) sb[tid >> 6] = wsv;
    __syncthreads();
    float tot = sb[0] + sb[1] + sb[2] + sb[3];
    float inv = 1.f / (tot + 1e-8f);
#pragma unroll
    for (int i = 0; i < 8; i++) {
        int n = i * 256 + tid;
        float al = ar[i] * inv;
        alpha_out[b * 2048 + n] = al;
        alpha_bf[b * 2048 + n] = bfbits(al);
    }
}

// ---------- W_assembled via MFMA ----------
// C[b, c] = sum_n alphaB[b,n] * UV[n, c],  c = dl*8+el within the block's 8d x 8e tile.
// Block: 256 thr (4 waves); M_t=256 (all b), N_t=64, K-step=32; grid (32 dt, 32 et).
// UV generated on the fly into LDS in B-fragment order; frag blocks XOR-swizzled.
#define QS 136  // bf16 stride per (cg,quad) frag block (16 l16 x 8 j + 8 pad)
__global__ __launch_bounds__(256) void assemble_mfma(
    const unsigned short* __restrict__ alphaB,  // bf16 (256 b x 2048 n)
    const void* __restrict__ pool,
    const void* __restrict__ W_base,
    const int* __restrict__ flags,
    float* __restrict__ Wout)                   // (256,256,256) fp32
{
    const int fp = flags[IPOOL], fw = flags[IWBASE];
    const int dt = blockIdx.x, et = blockIdx.y;
    const int d0 = dt * 8, e0 = et * 8;
    const int t = threadIdx.x;
    const int w = t >> 6, l = t & 63;
    const int q = l >> 4, l16 = l & 15;

    // generator mapping: thread covers n-pair (np) x c-quad (cq)
    const int np = t >> 4;              // 0..15 -> k = np*2, np*2+1
    const int cq = t & 15;              // c = cq*4 + i
    const int dl = cq >> 1;
    const int el0 = (cq & 1) * 4;
    const int cgw = cq >> 2;            // c >> 4
    const int l16w0 = (cq & 3) * 4;     // c & 15 base
    const int kq = np >> 2;             // quad of k
    const int j0 = (np * 2) & 7;        // even
    const int pbw = cgw * 4 + (kq ^ cgw);

    __shared__ __align__(16) unsigned short uvb[2][16 * QS];

    f32x4 acc[4][4] = {};

    int p = 0;
    for (int step = 0; step < 64; step++) {
        const int n0 = step * 32;
        // ---- generate UV tile (32n x 64c) in bf16 into uvb[p] ----
        float uv0[4] = {0.f, 0.f, 0.f, 0.f};
        float uv1[4] = {0.f, 0.f, 0.f, 0.f};
        if (fp == 0) {
            const float* p0 = (const float*)pool + (size_t)(n0 + np * 2) * D_POOL;
            const float* p1 = p0 + D_POOL;
            float4 ua0 = *(const float4*)(p0 + (d0 + dl) * 8);
            float4 ub0 = *(const float4*)(p0 + (d0 + dl) * 8 + 4);
            float4 ua1 = *(const float4*)(p1 + (d0 + dl) * 8);
            float4 ub1 = *(const float4*)(p1 + (d0 + dl) * 8 + 4);
            float U0[8] = {ua0.x, ua0.y, ua0.z, ua0.w, ub0.x, ub0.y, ub0.z, ub0.w};
            float U1[8] = {ua1.x, ua1.y, ua1.z, ua1.w, ub1.x, ub1.y, ub1.z, ub1.w};
            const float* v0 = p0 + 2048 + e0 + el0;
            const float* v1 = p1 + 2048 + e0 + el0;
#pragma unroll
            for (int r = 0; r < 8; r++) {
                float4 w0 = *(const float4*)(v0 + r * 256);
                float4 w1 = *(const float4*)(v1 + r * 256);
                uv0[0] += U0[r] * w0.x; uv0[1] += U0[r] * w0.y;
                uv0[2] += U0[r] * w0.z; uv0[3] += U0[r] * w0.w;
                uv1[0] += U1[r] * w1.x; uv1[1] += U1[r] * w1.y;
                uv1[2] += U1[r] * w1.z; uv1[3] += U1[r] * w1.w;
            }
        } else {
            size_t pr0 = (size_t)(n0 + np * 2) * D_POOL;
            size_t pr1 = pr0 + D_POOL;
#pragma unroll
            for (int r = 0; r < 8; r++) {
                float u0 = ldin(pool, pr0 + (d0 + dl) * 8 + r, 1);
                float u1 = ldin(pool, pr1 + (d0 + dl) * 8 + r, 1);
#pragma unroll
                for (int i = 0; i < 4; i++) {
                    uv0[i] += u0 * ldin(pool, pr0 + 2048 + r * 256 + e0 + el0 + i, 1);
                    uv1[i] += u1 * ldin(pool, pr1 + 2048 + r * 256 + e0 + el0 + i, 1);
                }
            }
        }
#pragma unroll
        for (int i = 0; i < 4; i++) {
            unsigned pk = ((unsigned)bfbits(uv1[i]) << 16) | bfbits(uv0[i]);
            *(unsigned*)&uvb[p][pbw * QS + (l16w0 + i) * 8 + j0] = pk;
        }
        __syncthreads();
        // ---- consume: A-frags from global (L2-hot), B-frags from LDS, MFMA ----
        bf16x8 afr[4];
#pragma unroll
        for (int mt = 0; mt < 4; mt++) {
            const unsigned short* ap =
                alphaB + (size_t)(w * 64 + mt * 16 + l16) * 2048 + n0 + q * 8;
            afr[mt] = *(const bf16x8*)ap;
        }
        bf16x8 bfr[4];
#pragma unroll
        for (int cg = 0; cg < 4; cg++) {
            int pbr = cg * 4 + (q ^ cg);
            bfr[cg] = *(const bf16x8*)&uvb[p][pbr * QS + l16 * 8];
        }
#pragma unroll
        for (int mt = 0; mt < 4; mt++)
#pragma unroll
            for (int cg = 0; cg < 4; cg++)
                acc[mt][cg] = __builtin_amdgcn_mfma_f32_16x16x32_bf16(
                    afr[mt], bfr[cg], acc[mt][cg], 0, 0, 0);
        p ^= 1;
    }

    // ---- epilogue: += W_base, store fp32 ----
    float wb[4];
#pragma unroll
    for (int cg = 0; cg < 4; cg++) {
        int c = cg * 16 + l16;
        wb[cg] = ldin(W_base, (size_t)(d0 + (c >> 3)) * 256 + e0 + (c & 7), fw);
    }
#pragma unroll
    for (int mt = 0; mt < 4; mt++) {
#pragma unroll
        for (int cg = 0; cg < 4; cg++) {
            int c = cg * 16 + l16;
            size_t col = (size_t)(d0 + (c >> 3)) * 256 + e0 + (c & 7);
#pragma unroll
            for (int r = 0; r < 4; r++) {
                int b = w * 64 + mt * 16 + q * 4 + r;
                Wout[(size_t)b * 65536 + col] = acc[mt][cg][r] + wb[cg];
            }
        }
    }
}

// ---------- h_t + y (reads fp32 W_assembled) ----------
__global__ __launch_bounds__(256) void hty_kernel(
    const float* __restrict__ Wout, const float* __restrict__ hA,
    const float* __restrict__ bass, const void* __restrict__ gamma_p,
    const int* __restrict__ flags, float* __restrict__ y)
{
    const int b = blockIdx.y;
    const int c = blockIdx.x * 4 + (threadIdx.x >> 6);
    const int lane = threadIdx.x & 63;
    const float4 wv = ((const float4*)(Wout + ((size_t)b * 65536 + c * 256)))[lane];
    const float4 h4 = ((const float4*)(hA + b * 256))[lane];
    float s = wv.x * h4.x + wv.y * h4.y + wv.z * h4.z + wv.w * h4.w;
    s = wsum(s);
    if (lane == 0) {
        float ht = s + bass[b * 256 + c];
        y[b * 256 + c] = hA[b * 256 + c] + ldin(gamma_p, 0, flags[IGAMMA]) * ht;
    }
}

// ---------- layernorm ----------
__global__ __launch_bounds__(256) void ln_kernel(
    const float* __restrict__ y, const void* __restrict__ ln_scale,
    const void* __restrict__ ln_bias, const int* __restrict__ flags,
    float* __restrict__ hmid)
{
    const int fs = flags[ILNS], fb = flags[ILNB];
    const int b = blockIdx.x, tid = threadIdx.x;
    float v = y[b * 256 + tid];
    __shared__ float s1b[4], s2b[4];
    float w1 = wsum(v), w2 = wsum(v * v);
    if ((tid & 63) == 0) { s1b[tid >> 6] = w1; s2b[tid >> 6] = w2; }
    __syncthreads();
    float mu = (s1b[0] + s1b[1] + s1b[2] + s1b[3]) * (1.f / 256.f);
    float ex2 = (s2b[0] + s2b[1] + s2b[2] + s2b[3]) * (1.f / 256.f);
    float var = ex2 - mu * mu;
    float inv = 1.f / sqrtf(var + 1e-6f);
    hmid[b * 256 + tid] = (v - mu) * inv * ldin(ln_scale, tid, fs)
                        + ldin(ln_bias, tid, fb);
}

// ---------- launch ----------
extern "C" void kernel_launch(void* const* d_in, const int* in_sizes, int n_in,
                              void* d_out, int out_size, void* d_ws, size_t ws_size,
                              hipStream_t stream)
{
    (void)out_size; (void)n_in;
    const void* x      = d_in[0];
    const void* pool   = d_in[1];
    const void* A_w0   = d_in[2];
    const void* A_b0   = d_in[3];
    const void* A_w1   = d_in[4];
    const void* A_b1   = d_in[5];
    const void* W_Q    = d_in[6];
    const void* W_K    = d_in[7];
    const void* logits = d_in[8];
    const void* tau    = d_in[9];
    const void* W_base = d_in[10];
    const void* b_base = d_in[11];
    const void* gamma  = d_in[12];
    const void* ln_s   = d_in[13];
    const void* ln_b   = d_in[14];
    const void* B_w0   = d_in[15];
    const void* B_b0   = d_in[16];
    const void* B_w1   = d_in[17];
    const void* B_b1   = d_in[18];

    // Outputs: FP32, concatenated in return order.
    float* out       = (float*)d_out;
    float* out0      = out;               // (256,512)
    float* out_alpha = out + 131072;      // (256,2048)
    float* out_W     = out + 655360;      // (256,256,256)
    float* out_keys  = out + 17432576;    // (2048,4,64)

    // Small scratch, always in d_ws
    float* ws = (float*)d_ws;
    int*   flagp   = (int*)d_ws;          // ints [0,32)
    float* ws_w    = ws + 32;
    float* ws_hA   = ws + 64;             // 65536
    float* ws_qw   = ws + 65600;          // 65536
    float* ws_bass = ws + 131136;         // 65536
    float* ws_y    = ws + 196672;         // 65536
    float* ws_hmid = ws + 262208;         // 65536 -> 327744
    unsigned short* alpha_bf = (unsigned short*)(ws + 327744);  // 524288 bf16 = 262144 f32
    // small region ends at 589888 floats (2.36 MB)

    // Big slots: prefer d_ws; fall back to out_W region (dead until assemble).
    size_t wsf = ws_size / 4;
    bool full = wsf >= 1638464;
    float* slotA;   // G -> scores -> T1
    float* slotB;   // kn
    float* T1;
    float* scr = (float*)out_W;
    if (full) {
        slotA = ws + 589888;    // 524288
        slotB = ws + 1114176;   // 524288 -> 1638464 total
        T1    = slotA;
    } else {
        slotA = scr;
        slotB = scr + 524288;
        T1    = (float*)alpha_bf;  // alpha_bf dead after assemble; 262144 floats fits
    }
    float* G      = slotA;
    float* scores = slotA;
    float* kn     = slotB;

    // 0) per-input dtype detection
    P19 ip;
    for (int i = 0; i < 19; i++) { ip.p[i] = d_in[i]; ip.n[i] = in_sizes[i]; }
    detect_all<<<19, 256, 0, stream>>>(ip, flagp);
    // 1) aspect softmax
    softmax4_kernel<<<1, 64, 0, stream>>>(logits, flagp, ws_w);
    // 2) A-MLP
    gemm64<0><<<dim3(16, 4), 256, 0, stream>>>(
        x, 512, IX, A_w0, 1024, IAW0, 0, A_b0, IAB0,
        G, 1024, 256, 1024, 512, 1, flagp);
    // A-MLP2: split-K atomic (C pre-init with bias), 128 blocks
    init_bias_kernel<<<256, 256, 0, stream>>>(ws_hA, A_b1, IAB1, flagp, 256, 65536);
    gemm64_splitk<0><<<dim3(4, 4, 8), 256, 0, stream>>>(
        G, 1024, -1, A_w1, 256, IAW1, 0,
        ws_hA, 256, 128, flagp);
    // 3) keys: split-K atomic into out_keys (zero-init), then normalize -> kn
    init_bias_kernel<<<2048, 256, 0, stream>>>(out_keys, nullptr, -1, flagp, 256, 524288);
    keys_atomic<<<dim3(4, 32, 12), 256, 0, stream>>>(pool, W_K, flagp, out_keys, 384);
    knorm_kernel<<<2048, 256, 0, stream>>>(out_keys, kn);
    // 4) queries
    queries_kernel<<<256, 256, 0, stream>>>(ws_hA, W_Q, flagp, ws_w, ws_qw);
    // 5) scores = qw @ kn^T
    gemm64<1><<<dim3(32, 4), 256, 0, stream>>>(
        ws_qw, 256, -1, kn, 256, -1, 0, nullptr, -1,
        scores, 2048, 256, 2048, 256, 0, flagp);
    // 6) alpha -> out_alpha (fp32) + alpha_bf (bf16 b-major)
    alpha_kernel<<<256, 256, 0, stream>>>(scores, tau, flagp, out_alpha, alpha_bf);
    // 7) b_assembled = alpha @ pool[:,4096:4352] + b_base: split-K atomic, 128 blocks
    init_bias_kernel<<<256, 256, 0, stream>>>(ws_bass, b_base, IBBASE, flagp, 256, 65536);
    gemm64_splitk<0><<<dim3(4, 4, 8), 256, 0, stream>>>(
        out_alpha, 2048, -1, pool, 4608, IPOOL, 4096,
        ws_bass, 256, 256, flagp);
    // 8) W_assembled via MFMA (dominant)
    assemble_mfma<<<dim3(32, 32), 256, 0, stream>>>(alpha_bf, pool, W_base, flagp, out_W);
    // 9) h_t, y
    hty_kernel<<<dim3(64, 256), 256, 0, stream>>>(out_W, ws_hA, ws_bass, gamma, flagp, ws_y);
    // 10) layernorm
    ln_kernel<<<256, 256, 0, stream>>>(ws_y, ln_s, ln_b, flagp, ws_hmid);
    // 11) B-MLP
    gemm64<0><<<dim3(16, 4), 256, 0, stream>>>(
        ws_hmid, 256, -1, B_w0, 1024, IBW0, 0, B_b0, IBB0,
        T1, 1024, 256, 1024, 256, 1, flagp);
    // B-MLP2: split-K atomic (out0 pre-init with bias), 128 blocks
    init_bias_kernel<<<512, 256, 0, stream>>>(out0, B_b1, IBB1, flagp, 512, 131072);
    gemm64_splitk<0><<<dim3(8, 4, 4), 256, 0, stream>>>(
        T1, 1024, -1, B_w1, 512, IBW1, 0,
        out0, 512, 256, flagp);
}

// Round 2
// 754.804 us; speedup vs baseline: 2.8207x; 1.3233x over previous
//
#include <hip/hip_runtime.h>
#include <hip/hip_bf16.h>
#include <math.h>

#define N_POOL 2048
#define D_POOL 4608

typedef __hip_bfloat16 bf16;
typedef __attribute__((ext_vector_type(8))) short bf16x8;
typedef __attribute__((ext_vector_type(4))) float f32x4;

// input indices
#define IX 0
#define IPOOL 1
#define IAW0 2
#define IAB0 3
#define IAW1 4
#define IAB1 5
#define IWQ 6
#define IWK 7
#define ILOG 8
#define ITAU 9
#define IWBASE 10
#define IBBASE 11
#define IGAMMA 12
#define ILNS 13
#define ILNB 14
#define IBW0 15
#define IBB0 16
#define IBW1 17
#define IBB1 18

// ---------- helpers ----------
__device__ inline float wsum(float v) {
#pragma unroll
    for (int off = 32; off > 0; off >>= 1) v += __shfl_xor(v, off, 64);
    return v;
}
__device__ inline float ldin(const void* p, size_t i, int f) {
    if (f) return __bfloat162float(((const bf16*)p)[i]);
    return ((const float*)p)[i];
}
__device__ inline float gelu_f(float x) {
    float t = tanhf(0.7978845608028654f * (x + 0.044715f * x * x * x));
    return 0.5f * x * (1.0f + t);
}
__device__ inline unsigned short bfbits(float f) {
    __hip_bfloat16 h = __float2bfloat16(f);
    return *reinterpret_cast<unsigned short*>(&h);
}

// ---------- per-input dtype detector (insurance; inputs measured all-fp32) ----------
struct P19 { const void* p[19]; long n[19]; };

__global__ void detect_all(P19 ip, int* flags) {
    const int j = blockIdx.x;
    const unsigned short* u = (const unsigned short*)ip.p[j];
    long nelem = ip.n[j];
    long nhalf = nelem >> 1; if (nhalf < 1) nhalf = 1;
    long kstep = (nhalf + 8191) >> 13; if (kstep < 1) kstep = 1;
    int W = 0, S = 0, Z = 0, O = 0, C = 0;
    for (long k = threadIdx.x; k * kstep < nhalf; k += 256) {
        long i = k * kstep * 2;
        unsigned short ev = u[i], od = u[i + 1];
        int e = (ev >> 7) & 0xFF;
        if (ev == 0) Z++;
        else if (e >= 90 && e <= 141) S++;
        else W++;
        if (od) O++;
        C++;
    }
    __shared__ int sw[256], ss[256], sz[256], so[256], sc[256];
    sw[threadIdx.x] = W; ss[threadIdx.x] = S; sz[threadIdx.x] = Z;
    so[threadIdx.x] = O; sc[threadIdx.x] = C;
    __syncthreads();
    if (threadIdx.x == 0) {
        int tw = 0, ts = 0, tz = 0, to = 0, tc = 0;
        for (int i = 0; i < 256; i++) {
            tw += sw[i]; ts += ss[i]; tz += sz[i]; to += so[i]; tc += sc[i];
        }
        int f;
        if (tw * 16 > tc) f = 0;
        else if (ts == 0 && tw == 0) f = (to > 0) ? 0 : 1;
        else f = (ts >= tz) ? 1 : 0;
        flags[j] = f;
    }
}

// ---------- generic 64x64 tiled GEMM: C = act(A@B(^T) + bias), fp32 out ----------
template <int TRANSB>
__global__ __launch_bounds__(256) void gemm64(
    const void* __restrict__ A, int lda, int afi,
    const void* __restrict__ B, int ldb, int bfi, size_t boffs,
    const void* __restrict__ bias, int bifi,
    float* __restrict__ C, int ldc,
    int M, int N, int K, int act, const int* __restrict__ flags)
{
    const int fa = (afi >= 0) ? flags[afi] : 0;
    const int fb = (bfi >= 0) ? flags[bfi] : 0;
    const int fbias = (bifi >= 0) ? flags[bifi] : 0;
    __shared__ __align__(16) float As[16][68];
    __shared__ __align__(16) float Bs[16][68];
    const int tid = threadIdx.x;
    const int tx = tid & 15, ty = tid >> 4;
    const int bx = blockIdx.x, by = blockIdx.y;
    float acc[4][4] = {};
    for (int k0 = 0; k0 < K; k0 += 16) {
#pragma unroll
        for (int i = 0; i < 4; i++) {
            int idx = tid + i * 256;
            int m = idx >> 4, kk = idx & 15;
            As[kk][m] = ldin(A, (size_t)(by * 64 + m) * lda + k0 + kk, fa);
        }
#pragma unroll
        for (int i = 0; i < 4; i++) {
            int idx = tid + i * 256;
            if (TRANSB) {
                int nn2 = idx >> 4, kk = idx & 15;
                Bs[kk][nn2] = ldin(B, boffs + (size_t)(bx * 64 + nn2) * ldb + k0 + kk, fb);
            } else {
                int kk = idx >> 6, nn2 = idx & 63;
                Bs[kk][nn2] = ldin(B, boffs + (size_t)(k0 + kk) * ldb + bx * 64 + nn2, fb);
            }
        }
        __syncthreads();
#pragma unroll
        for (int kk = 0; kk < 16; kk++) {
            float4 av4 = *(const float4*)&As[kk][ty * 4];
            float4 bv4 = *(const float4*)&Bs[kk][tx * 4];
            float av[4] = {av4.x, av4.y, av4.z, av4.w};
            float bv[4] = {bv4.x, bv4.y, bv4.z, bv4.w};
#pragma unroll
            for (int i = 0; i < 4; i++)
#pragma unroll
                for (int j = 0; j < 4; j++) acc[i][j] += av[i] * bv[j];
        }
        __syncthreads();
    }
#pragma unroll
    for (int i = 0; i < 4; i++) {
        int m = by * 64 + ty * 4 + i;
#pragma unroll
        for (int j = 0; j < 4; j++) {
            int n = bx * 64 + tx * 4 + j;
            float v = acc[i][j];
            if (bias) v += ldin(bias, n, fbias);
            if (act == 1) v = gelu_f(v);
            C[(size_t)m * ldc + n] = v;
        }
    }
}

// ---------- split-K 64x64 GEMM: atomically accumulates A@B into pre-initialized C ----------
template <int TRANSB>
__global__ __launch_bounds__(256) void gemm64_splitk(
    const void* __restrict__ A, int lda, int afi,
    const void* __restrict__ B, int ldb, int bfi, size_t boffs,
    float* __restrict__ C, int ldc, int KC, const int* __restrict__ flags)
{
    const int fa = (afi >= 0) ? flags[afi] : 0;
    const int fb = (bfi >= 0) ? flags[bfi] : 0;
    __shared__ __align__(16) float As[16][68];
    __shared__ __align__(16) float Bs[16][68];
    const int tid = threadIdx.x;
    const int tx = tid & 15, ty = tid >> 4;
    const int bx = blockIdx.x, by = blockIdx.y;
    const int kbeg = blockIdx.z * KC;
    float acc[4][4] = {};
    for (int k0 = kbeg; k0 < kbeg + KC; k0 += 16) {
#pragma unroll
        for (int i = 0; i < 4; i++) {
            int idx = tid + i * 256;
            int m = idx >> 4, kk = idx & 15;
            As[kk][m] = ldin(A, (size_t)(by * 64 + m) * lda + k0 + kk, fa);
        }
#pragma unroll
        for (int i = 0; i < 4; i++) {
            int idx = tid + i * 256;
            if (TRANSB) {
                int nn2 = idx >> 4, kk = idx & 15;
                Bs[kk][nn2] = ldin(B, boffs + (size_t)(bx * 64 + nn2) * ldb + k0 + kk, fb);
            } else {
                int kk = idx >> 6, nn2 = idx & 63;
                Bs[kk][nn2] = ldin(B, boffs + (size_t)(k0 + kk) * ldb + bx * 64 + nn2, fb);
            }
        }
        __syncthreads();
#pragma unroll
        for (int kk = 0; kk < 16; kk++) {
            float4 av4 = *(const float4*)&As[kk][ty * 4];
            float4 bv4 = *(const float4*)&Bs[kk][tx * 4];
            float av[4] = {av4.x, av4.y, av4.z, av4.w};
            float bv[4] = {bv4.x, bv4.y, bv4.z, bv4.w};
#pragma unroll
            for (int i = 0; i < 4; i++)
#pragma unroll
                for (int j = 0; j < 4; j++) acc[i][j] += av[i] * bv[j];
        }
        __syncthreads();
    }
#pragma unroll
    for (int i = 0; i < 4; i++) {
        int m = by * 64 + ty * 4 + i;
#pragma unroll
        for (int j = 0; j < 4; j++) {
            int n = bx * 64 + tx * 4 + j;
            atomicAdd(&C[(size_t)m * ldc + n], acc[i][j]);
        }
    }
}

// ---------- C[i] = bias[i % N] (or 0) ----------
__global__ __launch_bounds__(256) void init_bias_kernel(
    float* __restrict__ C, const void* __restrict__ bias, int bifi,
    const int* __restrict__ flags, int N, int total)
{
    int i = blockIdx.x * 256 + threadIdx.x;
    if (i >= total) return;
    float v = 0.f;
    if (bias) v = ldin(bias, i % N, (bifi >= 0) ? flags[bifi] : 0);
    C[i] = v;
}

// ---------- elementwise gelu in place ----------
__global__ __launch_bounds__(256) void gelu_kernel(float* __restrict__ buf, int total)
{
    int i = blockIdx.x * 256 + threadIdx.x;
    if (i < total) buf[i] = gelu_f(buf[i]);
}

// ---------- keys GEMM, split-K atomic version ----------
__global__ __launch_bounds__(256) void keys_atomic(
    const void* __restrict__ pool, const void* __restrict__ W_K,
    const int* __restrict__ flags, float* __restrict__ keys_out, int KC)
{
    const int fp = flags[IPOOL], fk = flags[IWK];
    __shared__ __align__(16) float As[16][68];
    __shared__ __align__(16) float Bs[16][68];
    const int tid = threadIdx.x;
    const int tx = tid & 15, ty = tid >> 4;
    const int a = blockIdx.x, by = blockIdx.y;
    const int kbeg = blockIdx.z * KC;
    float acc[4][4] = {};
    for (int k0 = kbeg; k0 < kbeg + KC; k0 += 16) {
#pragma unroll
        for (int i = 0; i < 4; i++) {
            int idx = tid + i * 256;
            int m = idx >> 4, kk = idx & 15;
            As[kk][m] = ldin(pool, (size_t)(by * 64 + m) * 4608 + k0 + kk, fp);
        }
#pragma unroll
        for (int i = 0; i < 4; i++) {
            int idx = tid + i * 256;
            int kk = idx >> 6, nn2 = idx & 63;
            Bs[kk][nn2] = ldin(W_K, (size_t)a * 294912 + (size_t)(k0 + kk) * 64 + nn2, fk);
        }
        __syncthreads();
#pragma unroll
        for (int kk = 0; kk < 16; kk++) {
            float4 av4 = *(const float4*)&As[kk][ty * 4];
            float4 bv4 = *(const float4*)&Bs[kk][tx * 4];
            float av[4] = {av4.x, av4.y, av4.z, av4.w};
            float bv[4] = {bv4.x, bv4.y, bv4.z, bv4.w};
#pragma unroll
            for (int i = 0; i < 4; i++)
#pragma unroll
                for (int j = 0; j < 4; j++) acc[i][j] += av[i] * bv[j];
        }
        __syncthreads();
    }
#pragma unroll
    for (int i = 0; i < 4; i++) {
        int m = by * 64 + ty * 4 + i;
#pragma unroll
        for (int j = 0; j < 4; j++) {
            atomicAdd(&keys_out[(size_t)m * 256 + a * 64 + tx * 4 + j], acc[i][j]);
        }
    }
}

// ---------- per-(n,aspect) normalize ----------
__global__ __launch_bounds__(256) void knorm_kernel(
    const float* __restrict__ keys, float* __restrict__ kn)
{
    const int n = blockIdx.x;
    const int a = threadIdx.x >> 6, q = threadIdx.x & 63;
    float v = keys[(size_t)n * 256 + a * 64 + q];
    float ss = wsum(v * v);
    kn[(size_t)n * 256 + a * 64 + q] = v / (sqrtf(ss) + 1e-8f);
}

// ---------- softmax over 4 aspect logits ----------
__global__ void softmax4_kernel(const void* __restrict__ logits,
                                const int* __restrict__ flags, float* __restrict__ w) {
    if (threadIdx.x == 0) {
        int f = flags[ILOG];
        float l0 = ldin(logits, 0, f), l1 = ldin(logits, 1, f);
        float l2 = ldin(logits, 2, f), l3 = ldin(logits, 3, f);
        float m = fmaxf(fmaxf(l0, l1), fmaxf(l2, l3));
        float e0 = expf(l0 - m), e1 = expf(l1 - m), e2 = expf(l2 - m), e3 = expf(l3 - m);
        float s = e0 + e1 + e2 + e3;
        w[0] = e0 / s; w[1] = e1 / s; w[2] = e2 / s; w[3] = e3 / s;
    }
}

// ---------- queries: normalized, aspect-weight folded ----------
__global__ __launch_bounds__(256) void queries_kernel(
    const float* __restrict__ hA, const void* __restrict__ W_Q,
    const int* __restrict__ flags, const float* __restrict__ w, float* __restrict__ qw)
{
    const int f = flags[IWQ];
    const int b = blockIdx.x;
    const int a = threadIdx.x >> 6, q = threadIdx.x & 63;
    const float* ha = hA + b * 256;
    float s = 0.f;
#pragma unroll 4
    for (int d = 0; d < 256; d++)
        s += ha[d] * ldin(W_Q, (size_t)a * 16384 + (size_t)d * 64 + q, f);
    float nrm = sqrtf(wsum(s * s));
    qw[b * 256 + a * 64 + q] = s / (nrm + 1e-8f) * w[a];
}

// ---------- alpha: fp32 alpha (b-major, output) + bf16 alphaT (n-octet-major) ----------
// alphaT layout: [n>>3][b][n&7] bf16  -> MFMA A-frags are 16B/lane coalesced.
__global__ __launch_bounds__(256) void alpha_kernel(
    const float* __restrict__ scores, const void* __restrict__ tau_p,
    const int* __restrict__ flags,
    float* __restrict__ alpha_out, unsigned short* __restrict__ alphaT)
{
    const int b = blockIdx.x;
    const int tid = threadIdx.x;
    const float tauv = ldin(tau_p, 0, flags[ITAU]);
    float ar[8];
    float lsum = 0.f;
#pragma unroll
    for (int i = 0; i < 8; i++) {
        int n = i * 256 + tid;
        float s = scores[b * 2048 + n];
        float g = 1.f / (1.f + expf(-(s - tauv)));  // LAMBDA_SHARP=1
        ar[i] = g * expf(s);                         // TEMPERATURE=1
        lsum += ar[i];
    }
    __shared__ float sb[4];
    float wsv = wsum(lsum);
    if ((tid & 63) == 0) sb[tid >> 6] = wsv;
    __syncthreads();
    float tot = sb[0] + sb[1] + sb[2] + sb[3];
    float inv = 1.f / (tot + 1e-8f);
#pragma unroll
    for (int i = 0; i < 8; i++) {
        int n = i * 256 + tid;
        float al = ar[i] * inv;
        alpha_out[b * 2048 + n] = al;
        alphaT[(size_t)(n >> 3) * 2048 + b * 8 + (n & 7)] = bfbits(al);
    }
}

// ---------- W_assembled via MFMA (pipelined LDS-staged producer/consumer) ----------
// C[b, c] = sum_n alphaT[b,n] * UV[n, c], c in the block's 8d x 8e tile (64 cols).
// Per step (32 n): stage U(32x64) + V(32x64) fp32 into padded LDS (wave-private rows,
// prefetched one step ahead in registers), generate UV in bf16 fragment order into
// uvb, MFMA-consume. Grid (32 dt, 32 et), 256 thr.
#define QS 136  // bf16 stride per (cg,quad) frag block (16 l16 x 8 j + 8 pad)
__global__ __launch_bounds__(256) void assemble_mfma(
    const unsigned short* __restrict__ alphaT,  // bf16 [n/8][256 b][8]
    const void* __restrict__ pool,
    const void* __restrict__ W_base,
    const int* __restrict__ flags,
    float* __restrict__ Wout)                   // (256,256,256) fp32
{
    const int fp = flags[IPOOL], fw = flags[IWBASE];
    const int dt = blockIdx.x, et = blockIdx.y;
    const int d0 = dt * 8, e0 = et * 8;
    const int t = threadIdx.x;
    const int w = t >> 6, l = t & 63;
    const int q = l >> 4, l16 = l & 15;

    // generator mapping: 1 n x (2 dl x 4 e) per thread
    const int nl  = w * 8 + (l >> 3);     // local n 0..32 (wave-private octet)
    const int sub = l & 7;
    const int dlp = sub >> 1;             // dl pair: dl = dlp*2 + {0,1}
    const int el0 = (sub & 1) * 4;        // e offset 0 or 4
    const int kq  = nl >> 3;              // = w
    const int jj  = nl & 7;
    const int cg  = dlp;
    const int pbw = cg * 4 + (kq ^ cg);

    __shared__ __align__(16) float Us[2][32][68];
    __shared__ __align__(16) float Vs[2][32][68];
    __shared__ __align__(16) unsigned short uvb[16 * QS];

    const float4* pool4 = (const float4*)pool;

    f32x4 acc[4][4] = {};

    // ---- staging loader: f = i*64 + l; i<2 -> U, i>=2 -> V (wave-private 8 n rows)
    auto load_stage = [&](int n0, float4* st) {
#pragma unroll
        for (int i = 0; i < 2; i++) {
            int f = i * 64 + l;
            int n = n0 + w * 8 + (f >> 4);
            int q4 = f & 15;
            if (fp == 0) {
                st[i] = pool4[(size_t)n * 1152 + d0 * 2 + q4];
            } else {
                size_t base = (size_t)n * 4608 + (size_t)d0 * 8 + q4 * 4;
                st[i] = make_float4(ldin(pool, base, 1), ldin(pool, base + 1, 1),
                                    ldin(pool, base + 2, 1), ldin(pool, base + 3, 1));
            }
        }
#pragma unroll
        for (int i = 0; i < 2; i++) {
            int f = i * 64 + l;
            int n = n0 + w * 8 + (f >> 4);
            int q4 = f & 15;
            int r = q4 >> 1, ep = q4 & 1;
            if (fp == 0) {
                st[2 + i] = pool4[(size_t)n * 1152 + 512 + r * 64 + (e0 >> 2) + ep];
            } else {
                size_t base = (size_t)n * 4608 + 2048 + r * 256 + e0 + ep * 4;
                st[2 + i] = make_float4(ldin(pool, base, 1), ldin(pool, base + 1, 1),
                                        ldin(pool, base + 2, 1), ldin(pool, base + 3, 1));
            }
        }
    };
    auto store_stage = [&](int p, const float4* st) {
#pragma unroll
        for (int i = 0; i < 2; i++) {
            int f = i * 64 + l;
            int n = w * 8 + (f >> 4);
            int q4 = f & 15;
            *(float4*)&Us[p][n][q4 * 4] = st[i];
        }
#pragma unroll
        for (int i = 0; i < 2; i++) {
            int f = i * 64 + l;
            int n = w * 8 + (f >> 4);
            int q4 = f & 15;
            *(float4*)&Vs[p][n][q4 * 4] = st[2 + i];
        }
    };

    // prologue: stage step 0
    {
        float4 st[4];
        load_stage(0, st);
        store_stage(0, st);
    }
    __syncthreads();

    int p = 0;
    for (int step = 0; step < 64; step++) {
        // ---- phase A: prefetch next tile (regs) + generate UV from LDS[p] ----
        float4 stn[4];
        if (step < 63) load_stage((step + 1) * 32, stn);

        bf16x8 afr[4];
#pragma unroll
        for (int mt = 0; mt < 4; mt++) {
            const unsigned short* ap =
                alphaT + (size_t)(step * 4 + q) * 2048 + (w * 64 + mt * 16 + l16) * 8;
            afr[mt] = *(const bf16x8*)ap;
        }

        {
            const float* Ur = &Us[p][nl][dlp * 16];
            float4 Ua = *(const float4*)(Ur);
            float4 Ub = *(const float4*)(Ur + 4);
            float4 Uc = *(const float4*)(Ur + 8);
            float4 Ud = *(const float4*)(Ur + 12);
            float U0[8] = {Ua.x, Ua.y, Ua.z, Ua.w, Ub.x, Ub.y, Ub.z, Ub.w};
            float U1[8] = {Uc.x, Uc.y, Uc.z, Uc.w, Ud.x, Ud.y, Ud.z, Ud.w};
            float uv0[4] = {0.f, 0.f, 0.f, 0.f};
            float uv1[4] = {0.f, 0.f, 0.f, 0.f};
#pragma unroll
            for (int r = 0; r < 8; r++) {
                float4 vv = *(const float4*)&Vs[p][nl][r * 8 + el0];
                uv0[0] += U0[r] * vv.x; uv0[1] += U0[r] * vv.y;
                uv0[2] += U0[r] * vv.z; uv0[3] += U0[r] * vv.w;
                uv1[0] += U1[r] * vv.x; uv1[1] += U1[r] * vv.y;
                uv1[2] += U1[r] * vv.z; uv1[3] += U1[r] * vv.w;
            }
#pragma unroll
            for (int i = 0; i < 4; i++) {
                uvb[pbw * QS + (el0 + i) * 8 + jj]     = bfbits(uv0[i]);
                uvb[pbw * QS + (8 + el0 + i) * 8 + jj] = bfbits(uv1[i]);
            }
        }
        __syncthreads();

        // ---- phase B: consume uvb + write next stage to LDS[p^1] + MFMA ----
        bf16x8 bfr[4];
#pragma unroll
        for (int cgi = 0; cgi < 4; cgi++) {
            int pbr = cgi * 4 + (q ^ cgi);
            bfr[cgi] = *(const bf16x8*)&uvb[pbr * QS + l16 * 8];
        }
        if (step < 63) store_stage(p ^ 1, stn);
#pragma unroll
        for (int mt = 0; mt < 4; mt++)
#pragma unroll
            for (int cgi = 0; cgi < 4; cgi++)
                acc[mt][cgi] = __builtin_amdgcn_mfma_f32_16x16x32_bf16(
                    afr[mt], bfr[cgi], acc[mt][cgi], 0, 0, 0);
        __syncthreads();
        p ^= 1;
    }

    // ---- epilogue: += W_base, store fp32 ----
    float wb[4];
#pragma unroll
    for (int cgi = 0; cgi < 4; cgi++) {
        int c = cgi * 16 + l16;
        wb[cgi] = ldin(W_base, (size_t)(d0 + (c >> 3)) * 256 + e0 + (c & 7), fw);
    }
#pragma unroll
    for (int mt = 0; mt < 4; mt++) {
#pragma unroll
        for (int cgi = 0; cgi < 4; cgi++) {
            int c = cgi * 16 + l16;
            size_t col = (size_t)(d0 + (c >> 3)) * 256 + e0 + (c & 7);
#pragma unroll
            for (int r = 0; r < 4; r++) {
                int b = w * 64 + mt * 16 + q * 4 + r;
                Wout[(size_t)b * 65536 + col] = acc[mt][cgi][r] + wb[cgi];
            }
        }
    }
}

// ---------- h_t + y (reads fp32 W_assembled) ----------
__global__ __launch_bounds__(256) void hty_kernel(
    const float* __restrict__ Wout, const float* __restrict__ hA,
    const float* __restrict__ bass, const void* __restrict__ gamma_p,
    const int* __restrict__ flags, float* __restrict__ y)
{
    const int b = blockIdx.y;
    const int c = blockIdx.x * 4 + (threadIdx.x >> 6);
    const int lane = threadIdx.x & 63;
    const float4 wv = ((const float4*)(Wout + ((size_t)b * 65536 + c * 256)))[lane];
    const float4 h4 = ((const float4*)(hA + b * 256))[lane];
    float s = wv.x * h4.x + wv.y * h4.y + wv.z * h4.z + wv.w * h4.w;
    s = wsum(s);
    if (lane == 0) {
        float ht = s + bass[b * 256 + c];
        y[b * 256 + c] = hA[b * 256 + c] + ldin(gamma_p, 0, flags[IGAMMA]) * ht;
    }
}

// ---------- layernorm ----------
__global__ __launch_bounds__(256) void ln_kernel(
    const float* __restrict__ y, const void* __restrict__ ln_scale,
    const void* __restrict__ ln_bias, const int* __restrict__ flags,
    float* __restrict__ hmid)
{
    const int fs = flags[ILNS], fb = flags[ILNB];
    const int b = blockIdx.x, tid = threadIdx.x;
    float v = y[b * 256 + tid];
    __shared__ float s1b[4], s2b[4];
    float w1 = wsum(v), w2 = wsum(v * v);
    if ((tid & 63) == 0) { s1b[tid >> 6] = w1; s2b[tid >> 6] = w2; }
    __syncthreads();
    float mu = (s1b[0] + s1b[1] + s1b[2] + s1b[3]) * (1.f / 256.f);
    float ex2 = (s2b[0] + s2b[1] + s2b[2] + s2b[3]) * (1.f / 256.f);
    float var = ex2 - mu * mu;
    float inv = 1.f / sqrtf(var + 1e-6f);
    hmid[b * 256 + tid] = (v - mu) * inv * ldin(ln_scale, tid, fs)
                        + ldin(ln_bias, tid, fb);
}

// ---------- launch ----------
extern "C" void kernel_launch(void* const* d_in, const int* in_sizes, int n_in,
                              void* d_out, int out_size, void* d_ws, size_t ws_size,
                              hipStream_t stream)
{
    (void)out_size; (void)n_in;
    const void* x      = d_in[0];
    const void* pool   = d_in[1];
    const void* A_w0   = d_in[2];
    const void* A_b0   = d_in[3];
    const void* A_w1   = d_in[4];
    const void* A_b1   = d_in[5];
    const void* W_Q    = d_in[6];
    const void* W_K    = d_in[7];
    const void* logits = d_in[8];
    const void* tau    = d_in[9];
    const void* W_base = d_in[10];
    const void* b_base = d_in[11];
    const void* gamma  = d_in[12];
    const void* ln_s   = d_in[13];
    const void* ln_b   = d_in[14];
    const void* B_w0   = d_in[15];
    const void* B_b0   = d_in[16];
    const void* B_w1   = d_in[17];
    const void* B_b1   = d_in[18];

    // Outputs: FP32, concatenated in return order.
    float* out       = (float*)d_out;
    float* out0      = out;               // (256,512)
    float* out_alpha = out + 131072;      // (256,2048)
    float* out_W     = out + 655360;      // (256,256,256)
    float* out_keys  = out + 17432576;    // (2048,4,64)

    // Small scratch, always in d_ws
    float* ws = (float*)d_ws;
    int*   flagp   = (int*)d_ws;          // ints [0,32)
    float* ws_w    = ws + 32;
    float* ws_hA   = ws + 64;             // 65536
    float* ws_qw   = ws + 65600;          // 65536
    float* ws_bass = ws + 131136;         // 65536
    float* ws_y    = ws + 196672;         // 65536
    float* ws_hmid = ws + 262208;         // 65536 -> 327744
    unsigned short* alpha_bf = (unsigned short*)(ws + 327744);  // 524288 bf16 = 262144 f32
    // small region ends at 589888 floats (2.36 MB)

    // Big slots: prefer d_ws; fall back to out_W region (dead until assemble).
    size_t wsf = ws_size / 4;
    bool full = wsf >= 1638464;
    float* slotA;   // G -> scores -> T1
    float* slotB;   // kn
    float* T1;
    float* scr = (float*)out_W;
    if (full) {
        slotA = ws + 589888;    // 524288
        slotB = ws + 1114176;   // 524288 -> 1638464 total
        T1    = slotA;
    } else {
        slotA = scr;
        slotB = scr + 524288;
        T1    = (float*)alpha_bf;  // alphaT dead after assemble; 262144 floats fits
    }
    float* G      = slotA;
    float* scores = slotA;
    float* kn     = slotB;

    // 0) per-input dtype detection
    P19 ip;
    for (int i = 0; i < 19; i++) { ip.p[i] = d_in[i]; ip.n[i] = in_sizes[i]; }
    detect_all<<<19, 256, 0, stream>>>(ip, flagp);
    // 1) aspect softmax
    softmax4_kernel<<<1, 64, 0, stream>>>(logits, flagp, ws_w);
    // 2) A-MLP1: split-K atomic (G pre-init with bias) + gelu pass
    init_bias_kernel<<<1024, 256, 0, stream>>>(G, A_b0, IAB0, flagp, 1024, 262144);
    gemm64_splitk<0><<<dim3(16, 4, 4), 256, 0, stream>>>(
        x, 512, IX, A_w0, 1024, IAW0, 0,
        G, 1024, 128, flagp);
    gelu_kernel<<<1024, 256, 0, stream>>>(G, 262144);
    // A-MLP2: split-K atomic (C pre-init with bias), 128 blocks
    init_bias_kernel<<<256, 256, 0, stream>>>(ws_hA, A_b1, IAB1, flagp, 256, 65536);
    gemm64_splitk<0><<<dim3(4, 4, 8), 256, 0, stream>>>(
        G, 1024, -1, A_w1, 256, IAW1, 0,
        ws_hA, 256, 128, flagp);
    // 3) keys: split-K atomic into out_keys (zero-init), then normalize -> kn
    init_bias_kernel<<<2048, 256, 0, stream>>>(out_keys, nullptr, -1, flagp, 256, 524288);
    keys_atomic<<<dim3(4, 32, 12), 256, 0, stream>>>(pool, W_K, flagp, out_keys, 384);
    knorm_kernel<<<2048, 256, 0, stream>>>(out_keys, kn);
    // 4) queries
    queries_kernel<<<256, 256, 0, stream>>>(ws_hA, W_Q, flagp, ws_w, ws_qw);
    // 5) scores = qw @ kn^T
    gemm64<1><<<dim3(32, 4), 256, 0, stream>>>(
        ws_qw, 256, -1, kn, 256, -1, 0, nullptr, -1,
        scores, 2048, 256, 2048, 256, 0, flagp);
    // 6) alpha -> out_alpha (fp32) + alphaT (bf16 n-octet-major)
    alpha_kernel<<<256, 256, 0, stream>>>(scores, tau, flagp, out_alpha, alpha_bf);
    // 7) b_assembled = alpha @ pool[:,4096:4352] + b_base: split-K atomic, 128 blocks
    init_bias_kernel<<<256, 256, 0, stream>>>(ws_bass, b_base, IBBASE, flagp, 256, 65536);
    gemm64_splitk<0><<<dim3(4, 4, 8), 256, 0, stream>>>(
        out_alpha, 2048, -1, pool, 4608, IPOOL, 4096,
        ws_bass, 256, 256, flagp);
    // 8) W_assembled via MFMA (dominant)
    assemble_mfma<<<dim3(32, 32), 256, 0, stream>>>(alpha_bf, pool, W_base, flagp, out_W);
    // 9) h_t, y
    hty_kernel<<<dim3(64, 256), 256, 0, stream>>>(out_W, ws_hA, ws_bass, gamma, flagp, ws_y);
    // 10) layernorm
    ln_kernel<<<256, 256, 0, stream>>>(ws_y, ln_s, ln_b, flagp, ws_hmid);
    // 11) B-MLP1: split-K atomic (T1 pre-init with bias) + gelu pass
    init_bias_kernel<<<1024, 256, 0, stream>>>(T1, B_b0, IBB0, flagp, 1024, 262144);
    gemm64_splitk<0><<<dim3(16, 4, 2), 256, 0, stream>>>(
        ws_hmid, 256, -1, B_w0, 1024, IBW0, 0,
        T1, 1024, 128, flagp);
    gelu_kernel<<<1024, 256, 0, stream>>>(T1, 262144);
    // B-MLP2: split-K atomic (out0 pre-init with bias), 128 blocks
    init_bias_kernel<<<512, 256, 0, stream>>>(out0, B_b1, IBB1, flagp, 512, 131072);
    gemm64_splitk<0><<<dim3(8, 4, 4), 256, 0, stream>>>(
        T1, 1024, -1, B_w1, 512, IBW1, 0,
        out0, 512, 256, flagp);
}

// Round 3
// 697.291 us; speedup vs baseline: 3.0533x; 1.0825x over previous
//
#include <hip/hip_runtime.h>
#include <hip/hip_bf16.h>
#include <math.h>

#define N_POOL 2048
#define D_POOL 4608

typedef __hip_bfloat16 bf16;
typedef __attribute__((ext_vector_type(8))) short bf16x8;
typedef __attribute__((ext_vector_type(4))) float f32x4;

// input indices
#define IX 0
#define IPOOL 1
#define IAW0 2
#define IAB0 3
#define IAW1 4
#define IAB1 5
#define IWQ 6
#define IWK 7
#define ILOG 8
#define ITAU 9
#define IWBASE 10
#define IBBASE 11
#define IGAMMA 12
#define ILNS 13
#define ILNB 14
#define IBW0 15
#define IBB0 16
#define IBW1 17
#define IBB1 18

// ---------- helpers ----------
__device__ inline float wsum(float v) {
#pragma unroll
    for (int off = 32; off > 0; off >>= 1) v += __shfl_xor(v, off, 64);
    return v;
}
__device__ inline float ldin(const void* p, size_t i, int f) {
    if (f) return __bfloat162float(((const bf16*)p)[i]);
    return ((const float*)p)[i];
}
__device__ inline float gelu_f(float x) {
    float t = tanhf(0.7978845608028654f * (x + 0.044715f * x * x * x));
    return 0.5f * x * (1.0f + t);
}
__device__ inline unsigned short bfbits(float f) {
    __hip_bfloat16 h = __float2bfloat16(f);
    return *reinterpret_cast<unsigned short*>(&h);
}

// ---------- per-input dtype detector (insurance; inputs measured all-fp32) ----------
struct P19 { const void* p[19]; long n[19]; };

__global__ void detect_all(P19 ip, int* flags) {
    const int j = blockIdx.x;
    const unsigned short* u = (const unsigned short*)ip.p[j];
    long nelem = ip.n[j];
    long nhalf = nelem >> 1; if (nhalf < 1) nhalf = 1;
    long kstep = (nhalf + 8191) >> 13; if (kstep < 1) kstep = 1;
    int W = 0, S = 0, Z = 0, O = 0, C = 0;
    for (long k = threadIdx.x; k * kstep < nhalf; k += 256) {
        long i = k * kstep * 2;
        unsigned short ev = u[i], od = u[i + 1];
        int e = (ev >> 7) & 0xFF;
        if (ev == 0) Z++;
        else if (e >= 90 && e <= 141) S++;
        else W++;
        if (od) O++;
        C++;
    }
    __shared__ int sw[256], ss[256], sz[256], so[256], sc[256];
    sw[threadIdx.x] = W; ss[threadIdx.x] = S; sz[threadIdx.x] = Z;
    so[threadIdx.x] = O; sc[threadIdx.x] = C;
    __syncthreads();
    if (threadIdx.x == 0) {
        int tw = 0, ts = 0, tz = 0, to = 0, tc = 0;
        for (int i = 0; i < 256; i++) {
            tw += sw[i]; ts += ss[i]; tz += sz[i]; to += so[i]; tc += sc[i];
        }
        int f;
        if (tw * 16 > tc) f = 0;
        else if (ts == 0 && tw == 0) f = (to > 0) ? 0 : 1;
        else f = (ts >= tz) ? 1 : 0;
        flags[j] = f;
    }
}

// ---------- generic 64x64 tiled GEMM: C = act(A@B(^T) + bias), fp32 out ----------
template <int TRANSB>
__global__ __launch_bounds__(256) void gemm64(
    const void* __restrict__ A, int lda, int afi,
    const void* __restrict__ B, int ldb, int bfi, size_t boffs,
    const void* __restrict__ bias, int bifi,
    float* __restrict__ C, int ldc,
    int M, int N, int K, int act, const int* __restrict__ flags)
{
    const int fa = (afi >= 0) ? flags[afi] : 0;
    const int fb = (bfi >= 0) ? flags[bfi] : 0;
    const int fbias = (bifi >= 0) ? flags[bifi] : 0;
    __shared__ __align__(16) float As[16][68];
    __shared__ __align__(16) float Bs[16][68];
    const int tid = threadIdx.x;
    const int tx = tid & 15, ty = tid >> 4;
    const int bx = blockIdx.x, by = blockIdx.y;
    float acc[4][4] = {};
    for (int k0 = 0; k0 < K; k0 += 16) {
#pragma unroll
        for (int i = 0; i < 4; i++) {
            int idx = tid + i * 256;
            int m = idx >> 4, kk = idx & 15;
            As[kk][m] = ldin(A, (size_t)(by * 64 + m) * lda + k0 + kk, fa);
        }
#pragma unroll
        for (int i = 0; i < 4; i++) {
            int idx = tid + i * 256;
            if (TRANSB) {
                int nn2 = idx >> 4, kk = idx & 15;
                Bs[kk][nn2] = ldin(B, boffs + (size_t)(bx * 64 + nn2) * ldb + k0 + kk, fb);
            } else {
                int kk = idx >> 6, nn2 = idx & 63;
                Bs[kk][nn2] = ldin(B, boffs + (size_t)(k0 + kk) * ldb + bx * 64 + nn2, fb);
            }
        }
        __syncthreads();
#pragma unroll
        for (int kk = 0; kk < 16; kk++) {
            float4 av4 = *(const float4*)&As[kk][ty * 4];
            float4 bv4 = *(const float4*)&Bs[kk][tx * 4];
            float av[4] = {av4.x, av4.y, av4.z, av4.w};
            float bv[4] = {bv4.x, bv4.y, bv4.z, bv4.w};
#pragma unroll
            for (int i = 0; i < 4; i++)
#pragma unroll
                for (int j = 0; j < 4; j++) acc[i][j] += av[i] * bv[j];
        }
        __syncthreads();
    }
#pragma unroll
    for (int i = 0; i < 4; i++) {
        int m = by * 64 + ty * 4 + i;
#pragma unroll
        for (int j = 0; j < 4; j++) {
            int n = bx * 64 + tx * 4 + j;
            float v = acc[i][j];
            if (bias) v += ldin(bias, n, fbias);
            if (act == 1) v = gelu_f(v);
            C[(size_t)m * ldc + n] = v;
        }
    }
}

// ---------- split-K 64x64 GEMM: atomically accumulates A@B into pre-initialized C ----------
template <int TRANSB>
__global__ __launch_bounds__(256) void gemm64_splitk(
    const void* __restrict__ A, int lda, int afi,
    const void* __restrict__ B, int ldb, int bfi, size_t boffs,
    float* __restrict__ C, int ldc, int KC, const int* __restrict__ flags)
{
    const int fa = (afi >= 0) ? flags[afi] : 0;
    const int fb = (bfi >= 0) ? flags[bfi] : 0;
    __shared__ __align__(16) float As[16][68];
    __shared__ __align__(16) float Bs[16][68];
    const int tid = threadIdx.x;
    const int tx = tid & 15, ty = tid >> 4;
    const int bx = blockIdx.x, by = blockIdx.y;
    const int kbeg = blockIdx.z * KC;
    float acc[4][4] = {};
    for (int k0 = kbeg; k0 < kbeg + KC; k0 += 16) {
#pragma unroll
        for (int i = 0; i < 4; i++) {
            int idx = tid + i * 256;
            int m = idx >> 4, kk = idx & 15;
            As[kk][m] = ldin(A, (size_t)(by * 64 + m) * lda + k0 + kk, fa);
        }
#pragma unroll
        for (int i = 0; i < 4; i++) {
            int idx = tid + i * 256;
            if (TRANSB) {
                int nn2 = idx >> 4, kk = idx & 15;
                Bs[kk][nn2] = ldin(B, boffs + (size_t)(bx * 64 + nn2) * ldb + k0 + kk, fb);
            } else {
                int kk = idx >> 6, nn2 = idx & 63;
                Bs[kk][nn2] = ldin(B, boffs + (size_t)(k0 + kk) * ldb + bx * 64 + nn2, fb);
            }
        }
        __syncthreads();
#pragma unroll
        for (int kk = 0; kk < 16; kk++) {
            float4 av4 = *(const float4*)&As[kk][ty * 4];
            float4 bv4 = *(const float4*)&Bs[kk][tx * 4];
            float av[4] = {av4.x, av4.y, av4.z, av4.w};
            float bv[4] = {bv4.x, bv4.y, bv4.z, bv4.w};
#pragma unroll
            for (int i = 0; i < 4; i++)
#pragma unroll
                for (int j = 0; j < 4; j++) acc[i][j] += av[i] * bv[j];
        }
        __syncthreads();
    }
#pragma unroll
    for (int i = 0; i < 4; i++) {
        int m = by * 64 + ty * 4 + i;
#pragma unroll
        for (int j = 0; j < 4; j++) {
            int n = bx * 64 + tx * 4 + j;
            atomicAdd(&C[(size_t)m * ldc + n], acc[i][j]);
        }
    }
}

// ---------- C[i] = bias[i % N] (or 0) ----------
__global__ __launch_bounds__(256) void init_bias_kernel(
    float* __restrict__ C, const void* __restrict__ bias, int bifi,
    const int* __restrict__ flags, int N, int total)
{
    int i = blockIdx.x * 256 + threadIdx.x;
    if (i >= total) return;
    float v = 0.f;
    if (bias) v = ldin(bias, i % N, (bifi >= 0) ? flags[bifi] : 0);
    C[i] = v;
}

// ---------- elementwise gelu in place ----------
__global__ __launch_bounds__(256) void gelu_kernel(float* __restrict__ buf, int total)
{
    int i = blockIdx.x * 256 + threadIdx.x;
    if (i < total) buf[i] = gelu_f(buf[i]);
}

// ---------- keys GEMM, split-K atomic version ----------
__global__ __launch_bounds__(256) void keys_atomic(
    const void* __restrict__ pool, const void* __restrict__ W_K,
    const int* __restrict__ flags, float* __restrict__ keys_out, int KC)
{
    const int fp = flags[IPOOL], fk = flags[IWK];
    __shared__ __align__(16) float As[16][68];
    __shared__ __align__(16) float Bs[16][68];
    const int tid = threadIdx.x;
    const int tx = tid & 15, ty = tid >> 4;
    const int a = blockIdx.x, by = blockIdx.y;
    const int kbeg = blockIdx.z * KC;
    float acc[4][4] = {};
    for (int k0 = kbeg; k0 < kbeg + KC; k0 += 16) {
#pragma unroll
        for (int i = 0; i < 4; i++) {
            int idx = tid + i * 256;
            int m = idx >> 4, kk = idx & 15;
            As[kk][m] = ldin(pool, (size_t)(by * 64 + m) * 4608 + k0 + kk, fp);
        }
#pragma unroll
        for (int i = 0; i < 4; i++) {
            int idx = tid + i * 256;
            int kk = idx >> 6, nn2 = idx & 63;
            Bs[kk][nn2] = ldin(W_K, (size_t)a * 294912 + (size_t)(k0 + kk) * 64 + nn2, fk);
        }
        __syncthreads();
#pragma unroll
        for (int kk = 0; kk < 16; kk++) {
            float4 av4 = *(const float4*)&As[kk][ty * 4];
            float4 bv4 = *(const float4*)&Bs[kk][tx * 4];
            float av[4] = {av4.x, av4.y, av4.z, av4.w};
            float bv[4] = {bv4.x, bv4.y, bv4.z, bv4.w};
#pragma unroll
            for (int i = 0; i < 4; i++)
#pragma unroll
                for (int j = 0; j < 4; j++) acc[i][j] += av[i] * bv[j];
        }
        __syncthreads();
    }
#pragma unroll
    for (int i = 0; i < 4; i++) {
        int m = by * 64 + ty * 4 + i;
#pragma unroll
        for (int j = 0; j < 4; j++) {
            atomicAdd(&keys_out[(size_t)m * 256 + a * 64 + tx * 4 + j], acc[i][j]);
        }
    }
}

// ---------- per-(n,aspect) normalize ----------
__global__ __launch_bounds__(256) void knorm_kernel(
    const float* __restrict__ keys, float* __restrict__ kn)
{
    const int n = blockIdx.x;
    const int a = threadIdx.x >> 6, q = threadIdx.x & 63;
    float v = keys[(size_t)n * 256 + a * 64 + q];
    float ss = wsum(v * v);
    kn[(size_t)n * 256 + a * 64 + q] = v / (sqrtf(ss) + 1e-8f);
}

// ---------- softmax over 4 aspect logits ----------
__global__ void softmax4_kernel(const void* __restrict__ logits,
                                const int* __restrict__ flags, float* __restrict__ w) {
    if (threadIdx.x == 0) {
        int f = flags[ILOG];
        float l0 = ldin(logits, 0, f), l1 = ldin(logits, 1, f);
        float l2 = ldin(logits, 2, f), l3 = ldin(logits, 3, f);
        float m = fmaxf(fmaxf(l0, l1), fmaxf(l2, l3));
        float e0 = expf(l0 - m), e1 = expf(l1 - m), e2 = expf(l2 - m), e3 = expf(l3 - m);
        float s = e0 + e1 + e2 + e3;
        w[0] = e0 / s; w[1] = e1 / s; w[2] = e2 / s; w[3] = e3 / s;
    }
}

// ---------- queries: normalized, aspect-weight folded ----------
__global__ __launch_bounds__(256) void queries_kernel(
    const float* __restrict__ hA, const void* __restrict__ W_Q,
    const int* __restrict__ flags, const float* __restrict__ w, float* __restrict__ qw)
{
    const int f = flags[IWQ];
    const int b = blockIdx.x;
    const int a = threadIdx.x >> 6, q = threadIdx.x & 63;
    const float* ha = hA + b * 256;
    float s = 0.f;
#pragma unroll 4
    for (int d = 0; d < 256; d++)
        s += ha[d] * ldin(W_Q, (size_t)a * 16384 + (size_t)d * 64 + q, f);
    float nrm = sqrtf(wsum(s * s));
    qw[b * 256 + a * 64 + q] = s / (nrm + 1e-8f) * w[a];
}

// ---------- alpha: fp32 alpha (b-major, output) + bf16 alphaT (n-octet-major) ----------
// alphaT layout: [n>>3][b][n&7] bf16  -> MFMA A-frags are 16B/lane coalesced.
__global__ __launch_bounds__(256) void alpha_kernel(
    const float* __restrict__ scores, const void* __restrict__ tau_p,
    const int* __restrict__ flags,
    float* __restrict__ alpha_out, unsigned short* __restrict__ alphaT)
{
    const int b = blockIdx.x;
    const int tid = threadIdx.x;
    const float tauv = ldin(tau_p, 0, flags[ITAU]);
    float ar[8];
    float lsum = 0.f;
#pragma unroll
    for (int i = 0; i < 8; i++) {
        int n = i * 256 + tid;
        float s = scores[b * 2048 + n];
        float g = 1.f / (1.f + expf(-(s - tauv)));  // LAMBDA_SHARP=1
        ar[i] = g * expf(s);                         // TEMPERATURE=1
        lsum += ar[i];
    }
    __shared__ float sb[4];
    float wsv = wsum(lsum);
    if ((tid & 63) == 0) sb[tid >> 6] = wsv;
    __syncthreads();
    float tot = sb[0] + sb[1] + sb[2] + sb[3];
    float inv = 1.f / (tot + 1e-8f);
#pragma unroll
    for (int i = 0; i < 8; i++) {
        int n = i * 256 + tid;
        float al = ar[i] * inv;
        alpha_out[b * 2048 + n] = al;
        alphaT[(size_t)(n >> 3) * 2048 + b * 8 + (n & 7)] = bfbits(al);
    }
}

// ---------- W_assembled via MFMA (v3: 8d x 16e tile, 512 blocks, linear uvb) ----------
// C[b, c] = sum_n alpha[b,n] * UV[n, c], c = dl*16 + el (8 d x 16 e = 128 cols/block).
// Per step (32 n): stage U(32x64) + V(32x128) fp32 into padded LDS (double-buffered,
// reg-prefetched), generate UV in bf16 into uvb (per-cg contiguous 1040B blocks:
// frag reads are lane-linear 1024B streams; writes ~2-way), 32 MFMA/wave.
// Grid: 512 blocks, XCD-swizzled so each XCD owns 2 e-tiles (V-slices L2-resident).
#define QW 520  // shorts per cg block (260 dwords = 1040 B; 16-dword pad kills bank aliasing)
__global__ __launch_bounds__(256, 2) void assemble_mfma(
    const unsigned short* __restrict__ alphaT,  // bf16 [n/8][256 b][8]
    const void* __restrict__ pool,
    const void* __restrict__ W_base,
    const int* __restrict__ flags,
    float* __restrict__ Wout)                   // (256,256,256) fp32
{
    const int fp = flags[IPOOL], fw = flags[IWBASE];
    const int lid = blockIdx.x;
    const int xcd = lid & 7, idx = lid >> 3;
    const int dt = idx & 31;                    // 32 d-tiles
    const int et = ((idx >> 5) << 3) + xcd;     // 16 e-tiles; XCD owns {xcd, xcd+8}
    const int d0 = dt * 8, e0 = et * 16;
    const int t = threadIdx.x;
    const int w = t >> 6, l = t & 63;
    const int q = l >> 4, l16 = l & 15;

    // generator mapping: 1 n x (2 d-rows x 8 e) per thread
    const int nl  = t >> 3;                     // local n 0..31
    const int sub = t & 7;
    const int dlp = sub >> 1;                   // d rows dlp*2, dlp*2+1
    const int eh  = sub & 1;                    // e-half: el = eh*8 + i
    const int jj  = nl & 7;                     // n-octet slot (kq == w)

    __shared__ __align__(16) float Us[2][32][76];
    __shared__ __align__(16) float Vs[2][32][132];
    __shared__ __align__(16) unsigned short uvb[8][QW];

    const float4* pool4 = (const float4*)pool;

    f32x4 acc[4][8] = {};

    // staging: U 2 float4/thread, V 4 float4/thread
    auto load_stage = [&](int n0, float4* st) {
#pragma unroll
        for (int i = 0; i < 2; i++) {
            int f = i * 256 + t;
            int n = n0 + (f >> 4);
            int q4 = f & 15;
            if (fp == 0) {
                st[i] = pool4[(size_t)n * 1152 + d0 * 2 + q4];
            } else {
                size_t base = (size_t)n * 4608 + (size_t)d0 * 8 + q4 * 4;
                st[i] = make_float4(ldin(pool, base, 1), ldin(pool, base + 1, 1),
                                    ldin(pool, base + 2, 1), ldin(pool, base + 3, 1));
            }
        }
#pragma unroll
        for (int i = 0; i < 4; i++) {
            int f = i * 256 + t;
            int n = n0 + (f >> 5);
            int r = (f & 31) >> 2, e4 = f & 3;
            if (fp == 0) {
                st[2 + i] = pool4[(size_t)n * 1152 + 512 + r * 64 + (e0 >> 2) + e4];
            } else {
                size_t base = (size_t)n * 4608 + 2048 + (size_t)r * 256 + e0 + e4 * 4;
                st[2 + i] = make_float4(ldin(pool, base, 1), ldin(pool, base + 1, 1),
                                        ldin(pool, base + 2, 1), ldin(pool, base + 3, 1));
            }
        }
    };
    auto store_stage = [&](int bp, const float4* st) {
#pragma unroll
        for (int i = 0; i < 2; i++) {
            int f = i * 256 + t;
            *(float4*)&Us[bp][f >> 4][(f & 15) * 4] = st[i];
        }
#pragma unroll
        for (int i = 0; i < 4; i++) {
            int f = i * 256 + t;
            int r = (f & 31) >> 2, e4 = f & 3;
            *(float4*)&Vs[bp][f >> 5][r * 16 + e4 * 4] = st[2 + i];
        }
    };

    // prologue: stage step 0
    {
        float4 st[6];
        load_stage(0, st);
        store_stage(0, st);
    }
    __syncthreads();

    int p = 0;
    for (int step = 0; step < 64; step++) {
        const int n0 = step * 32;
        // ---- phase A: prefetch next tile (regs) + A-frags + generate UV ----
        float4 stn[6];
        if (step < 63) load_stage(n0 + 32, stn);

        bf16x8 afr[4];
#pragma unroll
        for (int mt = 0; mt < 4; mt++) {
            const unsigned short* ap =
                alphaT + (size_t)(step * 4 + q) * 2048 + (w * 64 + mt * 16 + l16) * 8;
            afr[mt] = *(const bf16x8*)ap;
        }

        {
            const float* Ur = &Us[p][nl][dlp * 16];
            float4 Ua = *(const float4*)(Ur);
            float4 Ub = *(const float4*)(Ur + 4);
            float4 Uc = *(const float4*)(Ur + 8);
            float4 Ud = *(const float4*)(Ur + 12);
            float U0[8] = {Ua.x, Ua.y, Ua.z, Ua.w, Ub.x, Ub.y, Ub.z, Ub.w};
            float U1[8] = {Uc.x, Uc.y, Uc.z, Uc.w, Ud.x, Ud.y, Ud.z, Ud.w};
            float uv0[8] = {0.f, 0.f, 0.f, 0.f, 0.f, 0.f, 0.f, 0.f};
            float uv1[8] = {0.f, 0.f, 0.f, 0.f, 0.f, 0.f, 0.f, 0.f};
#pragma unroll
            for (int r = 0; r < 8; r++) {
                float4 va = *(const float4*)&Vs[p][nl][r * 16 + eh * 8];
                float4 vb = *(const float4*)&Vs[p][nl][r * 16 + eh * 8 + 4];
                uv0[0] += U0[r] * va.x; uv0[1] += U0[r] * va.y;
                uv0[2] += U0[r] * va.z; uv0[3] += U0[r] * va.w;
                uv0[4] += U0[r] * vb.x; uv0[5] += U0[r] * vb.y;
                uv0[6] += U0[r] * vb.z; uv0[7] += U0[r] * vb.w;
                uv1[0] += U1[r] * va.x; uv1[1] += U1[r] * va.y;
                uv1[2] += U1[r] * va.z; uv1[3] += U1[r] * va.w;
                uv1[4] += U1[r] * vb.x; uv1[5] += U1[r] * vb.y;
                uv1[6] += U1[r] * vb.z; uv1[7] += U1[r] * vb.w;
            }
            const int cg0 = dlp * 2, cg1 = cg0 + 1;
            const int wbase = w * 128 + eh * 64 + jj;
#pragma unroll
            for (int i = 0; i < 8; i++) {
                uvb[cg0][wbase + i * 8] = bfbits(uv0[i]);
                uvb[cg1][wbase + i * 8] = bfbits(uv1[i]);
            }
        }
        __syncthreads();

        // ---- phase B: consume uvb (lane-linear streams) + stage write + MFMA ----
        bf16x8 bfr[8];
#pragma unroll
        for (int cg = 0; cg < 8; cg++)
            bfr[cg] = *(const bf16x8*)&uvb[cg][l * 8];
        if (step < 63) store_stage(p ^ 1, stn);
#pragma unroll
        for (int mt = 0; mt < 4; mt++)
#pragma unroll
            for (int cg = 0; cg < 8; cg++)
                acc[mt][cg] = __builtin_amdgcn_mfma_f32_16x16x32_bf16(
                    afr[mt], bfr[cg], acc[mt][cg], 0, 0, 0);
        __syncthreads();
        p ^= 1;
    }

    // ---- epilogue: += W_base, store fp32 (64 B coalesced runs) ----
    float wb[8];
#pragma unroll
    for (int cg = 0; cg < 8; cg++)
        wb[cg] = ldin(W_base, (size_t)(d0 + cg) * 256 + e0 + l16, fw);
#pragma unroll
    for (int mt = 0; mt < 4; mt++) {
#pragma unroll
        for (int cg = 0; cg < 8; cg++) {
            size_t col = (size_t)(d0 + cg) * 256 + e0 + l16;
#pragma unroll
            for (int r = 0; r < 4; r++) {
                int b = w * 64 + mt * 16 + q * 4 + r;
                Wout[(size_t)b * 65536 + col] = acc[mt][cg][r] + wb[cg];
            }
        }
    }
}

// ---------- h_t + y (reads fp32 W_assembled) ----------
__global__ __launch_bounds__(256) void hty_kernel(
    const float* __restrict__ Wout, const float* __restrict__ hA,
    const float* __restrict__ bass, const void* __restrict__ gamma_p,
    const int* __restrict__ flags, float* __restrict__ y)
{
    const int b = blockIdx.y;
    const int c = blockIdx.x * 4 + (threadIdx.x >> 6);
    const int lane = threadIdx.x & 63;
    const float4 wv = ((const float4*)(Wout + ((size_t)b * 65536 + c * 256)))[lane];
    const float4 h4 = ((const float4*)(hA + b * 256))[lane];
    float s = wv.x * h4.x + wv.y * h4.y + wv.z * h4.z + wv.w * h4.w;
    s = wsum(s);
    if (lane == 0) {
        float ht = s + bass[b * 256 + c];
        y[b * 256 + c] = hA[b * 256 + c] + ldin(gamma_p, 0, flags[IGAMMA]) * ht;
    }
}

// ---------- layernorm ----------
__global__ __launch_bounds__(256) void ln_kernel(
    const float* __restrict__ y, const void* __restrict__ ln_scale,
    const void* __restrict__ ln_bias, const int* __restrict__ flags,
    float* __restrict__ hmid)
{
    const int fs = flags[ILNS], fb = flags[ILNB];
    const int b = blockIdx.x, tid = threadIdx.x;
    float v = y[b * 256 + tid];
    __shared__ float s1b[4], s2b[4];
    float w1 = wsum(v), w2 = wsum(v * v);
    if ((tid & 63) == 0) { s1b[tid >> 6] = w1; s2b[tid >> 6] = w2; }
    __syncthreads();
    float mu = (s1b[0] + s1b[1] + s1b[2] + s1b[3]) * (1.f / 256.f);
    float ex2 = (s2b[0] + s2b[1] + s2b[2] + s2b[3]) * (1.f / 256.f);
    float var = ex2 - mu * mu;
    float inv = 1.f / sqrtf(var + 1e-6f);
    hmid[b * 256 + tid] = (v - mu) * inv * ldin(ln_scale, tid, fs)
                        + ldin(ln_bias, tid, fb);
}

// ---------- launch ----------
extern "C" void kernel_launch(void* const* d_in, const int* in_sizes, int n_in,
                              void* d_out, int out_size, void* d_ws, size_t ws_size,
                              hipStream_t stream)
{
    (void)out_size; (void)n_in;
    const void* x      = d_in[0];
    const void* pool   = d_in[1];
    const void* A_w0   = d_in[2];
    const void* A_b0   = d_in[3];
    const void* A_w1   = d_in[4];
    const void* A_b1   = d_in[5];
    const void* W_Q    = d_in[6];
    const void* W_K    = d_in[7];
    const void* logits = d_in[8];
    const void* tau    = d_in[9];
    const void* W_base = d_in[10];
    const void* b_base = d_in[11];
    const void* gamma  = d_in[12];
    const void* ln_s   = d_in[13];
    const void* ln_b   = d_in[14];
    const void* B_w0   = d_in[15];
    const void* B_b0   = d_in[16];
    const void* B_w1   = d_in[17];
    const void* B_b1   = d_in[18];

    // Outputs: FP32, concatenated in return order.
    float* out       = (float*)d_out;
    float* out0      = out;               // (256,512)
    float* out_alpha = out + 131072;      // (256,2048)
    float* out_W     = out + 655360;      // (256,256,256)
    float* out_keys  = out + 17432576;    // (2048,4,64)

    // Small scratch, always in d_ws
    float* ws = (float*)d_ws;
    int*   flagp   = (int*)d_ws;          // ints [0,32)
    float* ws_w    = ws + 32;
    float* ws_hA   = ws + 64;             // 65536
    float* ws_qw   = ws + 65600;          // 65536
    float* ws_bass = ws + 131136;         // 65536
    float* ws_y    = ws + 196672;         // 65536
    float* ws_hmid = ws + 262208;         // 65536 -> 327744
    unsigned short* alpha_bf = (unsigned short*)(ws + 327744);  // 524288 bf16 = 262144 f32
    // small region ends at 589888 floats (2.36 MB)

    // Big slots: prefer d_ws; fall back to out_W region (dead until assemble).
    size_t wsf = ws_size / 4;
    bool full = wsf >= 1638464;
    float* slotA;   // G -> scores -> T1
    float* slotB;   // kn
    float* T1;
    float* scr = (float*)out_W;
    if (full) {
        slotA = ws + 589888;    // 524288
        slotB = ws + 1114176;   // 524288 -> 1638464 total
        T1    = slotA;
    } else {
        slotA = scr;
        slotB = scr + 524288;
        T1    = (float*)alpha_bf;  // alphaT dead after assemble; 262144 floats fits
    }
    float* G      = slotA;
    float* scores = slotA;
    float* kn     = slotB;

    // 0) per-input dtype detection
    P19 ip;
    for (int i = 0; i < 19; i++) { ip.p[i] = d_in[i]; ip.n[i] = in_sizes[i]; }
    detect_all<<<19, 256, 0, stream>>>(ip, flagp);
    // 1) aspect softmax
    softmax4_kernel<<<1, 64, 0, stream>>>(logits, flagp, ws_w);
    // 2) A-MLP1: split-K atomic (G pre-init with bias) + gelu pass
    init_bias_kernel<<<1024, 256, 0, stream>>>(G, A_b0, IAB0, flagp, 1024, 262144);
    gemm64_splitk<0><<<dim3(16, 4, 4), 256, 0, stream>>>(
        x, 512, IX, A_w0, 1024, IAW0, 0,
        G, 1024, 128, flagp);
    gelu_kernel<<<1024, 256, 0, stream>>>(G, 262144);
    // A-MLP2: split-K atomic (C pre-init with bias), 128 blocks
    init_bias_kernel<<<256, 256, 0, stream>>>(ws_hA, A_b1, IAB1, flagp, 256, 65536);
    gemm64_splitk<0><<<dim3(4, 4, 8), 256, 0, stream>>>(
        G, 1024, -1, A_w1, 256, IAW1, 0,
        ws_hA, 256, 128, flagp);
    // 3) keys: split-K atomic into out_keys (zero-init), then normalize -> kn
    init_bias_kernel<<<2048, 256, 0, stream>>>(out_keys, nullptr, -1, flagp, 256, 524288);
    keys_atomic<<<dim3(4, 32, 12), 256, 0, stream>>>(pool, W_K, flagp, out_keys, 384);
    knorm_kernel<<<2048, 256, 0, stream>>>(out_keys, kn);
    // 4) queries
    queries_kernel<<<256, 256, 0, stream>>>(ws_hA, W_Q, flagp, ws_w, ws_qw);
    // 5) scores = qw @ kn^T
    gemm64<1><<<dim3(32, 4), 256, 0, stream>>>(
        ws_qw, 256, -1, kn, 256, -1, 0, nullptr, -1,
        scores, 2048, 256, 2048, 256, 0, flagp);
    // 6) alpha -> out_alpha (fp32) + alphaT (bf16 n-octet-major)
    alpha_kernel<<<256, 256, 0, stream>>>(scores, tau, flagp, out_alpha, alpha_bf);
    // 7) b_assembled = alpha @ pool[:,4096:4352] + b_base: split-K atomic, 128 blocks
    init_bias_kernel<<<256, 256, 0, stream>>>(ws_bass, b_base, IBBASE, flagp, 256, 65536);
    gemm64_splitk<0><<<dim3(4, 4, 8), 256, 0, stream>>>(
        out_alpha, 2048, -1, pool, 4608, IPOOL, 4096,
        ws_bass, 256, 256, flagp);
    // 8) W_assembled via MFMA (dominant)
    assemble_mfma<<<512, 256, 0, stream>>>(alpha_bf, pool, W_base, flagp, out_W);
    // 9) h_t, y
    hty_kernel<<<dim3(64, 256), 256, 0, stream>>>(out_W, ws_hA, ws_bass, gamma, flagp, ws_y);
    // 10) layernorm
    ln_kernel<<<256, 256, 0, stream>>>(ws_y, ln_s, ln_b, flagp, ws_hmid);
    // 11) B-MLP1: split-K atomic (T1 pre-init with bias) + gelu pass
    init_bias_kernel<<<1024, 256, 0, stream>>>(T1, B_b0, IBB0, flagp, 1024, 262144);
    gemm64_splitk<0><<<dim3(16, 4, 2), 256, 0, stream>>>(
        ws_hmid, 256, -1, B_w0, 1024, IBW0, 0,
        T1, 1024, 128, flagp);
    gelu_kernel<<<1024, 256, 0, stream>>>(T1, 262144);
    // B-MLP2: split-K atomic (out0 pre-init with bias), 128 blocks
    init_bias_kernel<<<512, 256, 0, stream>>>(out0, B_b1, IBB1, flagp, 512, 131072);
    gemm64_splitk<0><<<dim3(8, 4, 4), 256, 0, stream>>>(
        T1, 1024, -1, B_w1, 512, IBW1, 0,
        out0, 512, 256, flagp);
}

// Round 4
// 626.063 us; speedup vs baseline: 3.4007x; 1.1138x over previous
//
#include <hip/hip_runtime.h>
#include <hip/hip_bf16.h>
#include <math.h>

#define N_POOL 2048
#define D_POOL 4608

typedef __hip_bfloat16 bf16;
typedef __attribute__((ext_vector_type(8))) short bf16x8;
typedef __attribute__((ext_vector_type(4))) float f32x4;
typedef __attribute__((ext_vector_type(4))) unsigned short u16x4;

// input indices
#define IX 0
#define IPOOL 1
#define IAW0 2
#define IAB0 3
#define IAW1 4
#define IAB1 5
#define IWQ 6
#define IWK 7
#define ILOG 8
#define ITAU 9
#define IWBASE 10
#define IBBASE 11
#define IGAMMA 12
#define ILNS 13
#define ILNB 14
#define IBW0 15
#define IBB0 16
#define IBW1 17
#define IBB1 18

// ---------- helpers ----------
__device__ inline float wsum(float v) {
#pragma unroll
    for (int off = 32; off > 0; off >>= 1) v += __shfl_xor(v, off, 64);
    return v;
}
__device__ inline float ldin(const void* p, size_t i, int f) {
    if (f) return __bfloat162float(((const bf16*)p)[i]);
    return ((const float*)p)[i];
}
__device__ inline float gelu_f(float x) {
    float t = tanhf(0.7978845608028654f * (x + 0.044715f * x * x * x));
    return 0.5f * x * (1.0f + t);
}
__device__ inline unsigned short bfbits(float f) {
    __hip_bfloat16 h = __float2bfloat16(f);
    return *reinterpret_cast<unsigned short*>(&h);
}

// ---------- per-input dtype detector (insurance; inputs measured all-fp32) ----------
struct P19 { const void* p[19]; long n[19]; };

__global__ void detect_all(P19 ip, int* flags) {
    const int j = blockIdx.x;
    const unsigned short* u = (const unsigned short*)ip.p[j];
    long nelem = ip.n[j];
    long nhalf = nelem >> 1; if (nhalf < 1) nhalf = 1;
    long kstep = (nhalf + 8191) >> 13; if (kstep < 1) kstep = 1;
    int W = 0, S = 0, Z = 0, O = 0, C = 0;
    for (long k = threadIdx.x; k * kstep < nhalf; k += 256) {
        long i = k * kstep * 2;
        unsigned short ev = u[i], od = u[i + 1];
        int e = (ev >> 7) & 0xFF;
        if (ev == 0) Z++;
        else if (e >= 90 && e <= 141) S++;
        else W++;
        if (od) O++;
        C++;
    }
    __shared__ int sw[256], ss[256], sz[256], so[256], sc[256];
    sw[threadIdx.x] = W; ss[threadIdx.x] = S; sz[threadIdx.x] = Z;
    so[threadIdx.x] = O; sc[threadIdx.x] = C;
    __syncthreads();
    if (threadIdx.x == 0) {
        int tw = 0, ts = 0, tz = 0, to = 0, tc = 0;
        for (int i = 0; i < 256; i++) {
            tw += sw[i]; ts += ss[i]; tz += sz[i]; to += so[i]; tc += sc[i];
        }
        int f;
        if (tw * 16 > tc) f = 0;
        else if (ts == 0 && tw == 0) f = (to > 0) ? 0 : 1;
        else f = (ts >= tz) ? 1 : 0;
        flags[j] = f;
    }
}

// ---------- generic 64x64 tiled GEMM: C = act(A@B(^T) + bias), fp32 out ----------
template <int TRANSB>
__global__ __launch_bounds__(256) void gemm64(
    const void* __restrict__ A, int lda, int afi,
    const void* __restrict__ B, int ldb, int bfi, size_t boffs,
    const void* __restrict__ bias, int bifi,
    float* __restrict__ C, int ldc,
    int M, int N, int K, int act, const int* __restrict__ flags)
{
    const int fa = (afi >= 0) ? flags[afi] : 0;
    const int fb = (bfi >= 0) ? flags[bfi] : 0;
    const int fbias = (bifi >= 0) ? flags[bifi] : 0;
    __shared__ __align__(16) float As[16][68];
    __shared__ __align__(16) float Bs[16][68];
    const int tid = threadIdx.x;
    const int tx = tid & 15, ty = tid >> 4;
    const int bx = blockIdx.x, by = blockIdx.y;
    float acc[4][4] = {};
    for (int k0 = 0; k0 < K; k0 += 16) {
#pragma unroll
        for (int i = 0; i < 4; i++) {
            int idx = tid + i * 256;
            int m = idx >> 4, kk = idx & 15;
            As[kk][m] = ldin(A, (size_t)(by * 64 + m) * lda + k0 + kk, fa);
        }
#pragma unroll
        for (int i = 0; i < 4; i++) {
            int idx = tid + i * 256;
            if (TRANSB) {
                int nn2 = idx >> 4, kk = idx & 15;
                Bs[kk][nn2] = ldin(B, boffs + (size_t)(bx * 64 + nn2) * ldb + k0 + kk, fb);
            } else {
                int kk = idx >> 6, nn2 = idx & 63;
                Bs[kk][nn2] = ldin(B, boffs + (size_t)(k0 + kk) * ldb + bx * 64 + nn2, fb);
            }
        }
        __syncthreads();
#pragma unroll
        for (int kk = 0; kk < 16; kk++) {
            float4 av4 = *(const float4*)&As[kk][ty * 4];
            float4 bv4 = *(const float4*)&Bs[kk][tx * 4];
            float av[4] = {av4.x, av4.y, av4.z, av4.w};
            float bv[4] = {bv4.x, bv4.y, bv4.z, bv4.w};
#pragma unroll
            for (int i = 0; i < 4; i++)
#pragma unroll
                for (int j = 0; j < 4; j++) acc[i][j] += av[i] * bv[j];
        }
        __syncthreads();
    }
#pragma unroll
    for (int i = 0; i < 4; i++) {
        int m = by * 64 + ty * 4 + i;
#pragma unroll
        for (int j = 0; j < 4; j++) {
            int n = bx * 64 + tx * 4 + j;
            float v = acc[i][j];
            if (bias) v += ldin(bias, n, fbias);
            if (act == 1) v = gelu_f(v);
            C[(size_t)m * ldc + n] = v;
        }
    }
}

// ---------- split-K 64x64 GEMM: atomically accumulates A@B into pre-initialized C ----------
template <int TRANSB>
__global__ __launch_bounds__(256) void gemm64_splitk(
    const void* __restrict__ A, int lda, int afi,
    const void* __restrict__ B, int ldb, int bfi, size_t boffs,
    float* __restrict__ C, int ldc, int KC, const int* __restrict__ flags)
{
    const int fa = (afi >= 0) ? flags[afi] : 0;
    const int fb = (bfi >= 0) ? flags[bfi] : 0;
    __shared__ __align__(16) float As[16][68];
    __shared__ __align__(16) float Bs[16][68];
    const int tid = threadIdx.x;
    const int tx = tid & 15, ty = tid >> 4;
    const int bx = blockIdx.x, by = blockIdx.y;
    const int kbeg = blockIdx.z * KC;
    float acc[4][4] = {};
    for (int k0 = kbeg; k0 < kbeg + KC; k0 += 16) {
#pragma unroll
        for (int i = 0; i < 4; i++) {
            int idx = tid + i * 256;
            int m = idx >> 4, kk = idx & 15;
            As[kk][m] = ldin(A, (size_t)(by * 64 + m) * lda + k0 + kk, fa);
        }
#pragma unroll
        for (int i = 0; i < 4; i++) {
            int idx = tid + i * 256;
            if (TRANSB) {
                int nn2 = idx >> 4, kk = idx & 15;
                Bs[kk][nn2] = ldin(B, boffs + (size_t)(bx * 64 + nn2) * ldb + k0 + kk, fb);
            } else {
                int kk = idx >> 6, nn2 = idx & 63;
                Bs[kk][nn2] = ldin(B, boffs + (size_t)(k0 + kk) * ldb + bx * 64 + nn2, fb);
            }
        }
        __syncthreads();
#pragma unroll
        for (int kk = 0; kk < 16; kk++) {
            float4 av4 = *(const float4*)&As[kk][ty * 4];
            float4 bv4 = *(const float4*)&Bs[kk][tx * 4];
            float av[4] = {av4.x, av4.y, av4.z, av4.w};
            float bv[4] = {bv4.x, bv4.y, bv4.z, bv4.w};
#pragma unroll
            for (int i = 0; i < 4; i++)
#pragma unroll
                for (int j = 0; j < 4; j++) acc[i][j] += av[i] * bv[j];
        }
        __syncthreads();
    }
#pragma unroll
    for (int i = 0; i < 4; i++) {
        int m = by * 64 + ty * 4 + i;
#pragma unroll
        for (int j = 0; j < 4; j++) {
            int n = bx * 64 + tx * 4 + j;
            atomicAdd(&C[(size_t)m * ldc + n], acc[i][j]);
        }
    }
}

// ---------- bf16 MFMA split-K GEMM, no LDS: C += A@B^T ----------
// A: bf16 row-major [M][lda] (k contiguous). B: bf16 n-major [ncols][ldb]
// (k contiguous per output column). Per blockIdx.y: B += y*64*ldb, C cols y*64+.
// Tile 128m x 64n, 4 waves (wave = 32m x 64n), K-chunk KC (multiple of 32).
__global__ __launch_bounds__(256) void gemm_mfma_atomic(
    const unsigned short* __restrict__ A, int lda,
    const unsigned short* __restrict__ Bmat, int ldb,
    float* __restrict__ C, int ldc, int KC)
{
    const int m0 = blockIdx.x * 128;
    const int n0 = blockIdx.y * 64;
    const unsigned short* B = Bmat + (size_t)blockIdx.y * 64 * ldb;
    const int kbeg = blockIdx.z * KC;
    const int t = threadIdx.x, w = t >> 6, l = t & 63;
    const int q = l >> 4, l16 = l & 15;
    f32x4 acc[2][4] = {};
    for (int k0 = kbeg; k0 < kbeg + KC; k0 += 32) {
        bf16x8 afr[2], bfr[4];
#pragma unroll
        for (int mt = 0; mt < 2; mt++)
            afr[mt] = *(const bf16x8*)&A[(size_t)(m0 + w * 32 + mt * 16 + l16) * lda + k0 + q * 8];
#pragma unroll
        for (int nt = 0; nt < 4; nt++)
            bfr[nt] = *(const bf16x8*)&B[(size_t)(nt * 16 + l16) * ldb + k0 + q * 8];
#pragma unroll
        for (int mt = 0; mt < 2; mt++)
#pragma unroll
            for (int nt = 0; nt < 4; nt++)
                acc[mt][nt] = __builtin_amdgcn_mfma_f32_16x16x32_bf16(
                    afr[mt], bfr[nt], acc[mt][nt], 0, 0, 0);
    }
#pragma unroll
    for (int mt = 0; mt < 2; mt++)
#pragma unroll
        for (int nt = 0; nt < 4; nt++)
#pragma unroll
            for (int r = 0; r < 4; r++) {
                int m = m0 + w * 32 + mt * 16 + q * 4 + r;
                atomicAdd(&C[(size_t)m * ldc + n0 + nt * 16 + l16], acc[mt][nt][r]);
            }
}

// ---------- converts: pool -> bf16 row-major ----------
__global__ __launch_bounds__(256) void pool2bf(
    const void* __restrict__ pool, const int* __restrict__ flags,
    unsigned short* __restrict__ pb)
{
    const int fp = flags[IPOOL];
    const size_t total = (size_t)N_POOL * D_POOL;
    for (size_t i = ((size_t)blockIdx.x * 256 + threadIdx.x) * 4; i < total;
         i += (size_t)gridDim.x * 1024) {
        u16x4 o;
        if (fp == 0) {
            float4 v = *(const float4*)((const float*)pool + i);
            o[0] = bfbits(v.x); o[1] = bfbits(v.y); o[2] = bfbits(v.z); o[3] = bfbits(v.w);
        } else {
            o = *(const u16x4*)((const unsigned short*)pool + i);
        }
        *(u16x4*)&pb[i] = o;
    }
}

// ---------- W_K fp32 [4][4608][64] -> bf16 n-major [4][64][4608] ----------
__global__ __launch_bounds__(256) void wk2bfT(
    const void* __restrict__ W_K, const int* __restrict__ flags,
    unsigned short* __restrict__ out)
{
    const int fk = flags[IWK];
    const int a = blockIdx.y, kb = blockIdx.x, t = threadIdx.x;
#pragma unroll
    for (int i = 0; i < 16; i++) {
        int idx = i * 256 + t;
        int kk = idx >> 6, qq = idx & 63;
        float v = ldin(W_K, (size_t)a * 294912 + (size_t)(kb * 64 + kk) * 64 + qq, fk);
        out[(size_t)(a * 64 + qq) * 4608 + kb * 64 + kk] = bfbits(v);
    }
}

// ---------- pool[:,4096:4352] -> bf16 col-major [256][2048] ----------
__global__ __launch_bounds__(256) void bias2bfT(
    const void* __restrict__ pool, const int* __restrict__ flags,
    unsigned short* __restrict__ out)
{
    const int fp = flags[IPOOL];
    const int nb = blockIdx.x, cb = blockIdx.y, t = threadIdx.x;
#pragma unroll
    for (int i = 0; i < 16; i++) {
        int idx = i * 256 + t;
        int nn = idx >> 6, cc = idx & 63;
        float v = ldin(pool, (size_t)(nb * 64 + nn) * 4608 + 4096 + cb * 64 + cc, fp);
        out[(size_t)(cb * 64 + cc) * 2048 + nb * 64 + nn] = bfbits(v);
    }
}

// ---------- C[i] = bias[i % N] (or 0) ----------
__global__ __launch_bounds__(256) void init_bias_kernel(
    float* __restrict__ C, const void* __restrict__ bias, int bifi,
    const int* __restrict__ flags, int N, int total)
{
    int i = blockIdx.x * 256 + threadIdx.x;
    if (i >= total) return;
    float v = 0.f;
    if (bias) v = ldin(bias, i % N, (bifi >= 0) ? flags[bifi] : 0);
    C[i] = v;
}

// ---------- elementwise gelu in place ----------
__global__ __launch_bounds__(256) void gelu_kernel(float* __restrict__ buf, int total)
{
    int i = blockIdx.x * 256 + threadIdx.x;
    if (i < total) buf[i] = gelu_f(buf[i]);
}

// ---------- per-(n,aspect) normalize ----------
__global__ __launch_bounds__(256) void knorm_kernel(
    const float* __restrict__ keys, float* __restrict__ kn)
{
    const int n = blockIdx.x;
    const int a = threadIdx.x >> 6, q = threadIdx.x & 63;
    float v = keys[(size_t)n * 256 + a * 64 + q];
    float ss = wsum(v * v);
    kn[(size_t)n * 256 + a * 64 + q] = v / (sqrtf(ss) + 1e-8f);
}

// ---------- softmax over 4 aspect logits ----------
__global__ void softmax4_kernel(const void* __restrict__ logits,
                                const int* __restrict__ flags, float* __restrict__ w) {
    if (threadIdx.x == 0) {
        int f = flags[ILOG];
        float l0 = ldin(logits, 0, f), l1 = ldin(logits, 1, f);
        float l2 = ldin(logits, 2, f), l3 = ldin(logits, 3, f);
        float m = fmaxf(fmaxf(l0, l1), fmaxf(l2, l3));
        float e0 = expf(l0 - m), e1 = expf(l1 - m), e2 = expf(l2 - m), e3 = expf(l3 - m);
        float s = e0 + e1 + e2 + e3;
        w[0] = e0 / s; w[1] = e1 / s; w[2] = e2 / s; w[3] = e3 / s;
    }
}

// ---------- queries: normalized, aspect-weight folded ----------
__global__ __launch_bounds__(256) void queries_kernel(
    const float* __restrict__ hA, const void* __restrict__ W_Q,
    const int* __restrict__ flags, const float* __restrict__ w, float* __restrict__ qw)
{
    const int f = flags[IWQ];
    const int b = blockIdx.x;
    const int a = threadIdx.x >> 6, q = threadIdx.x & 63;
    const float* ha = hA + b * 256;
    float s = 0.f;
#pragma unroll 4
    for (int d = 0; d < 256; d++)
        s += ha[d] * ldin(W_Q, (size_t)a * 16384 + (size_t)d * 64 + q, f);
    float nrm = sqrtf(wsum(s * s));
    qw[b * 256 + a * 64 + q] = s / (nrm + 1e-8f) * w[a];
}

// ---------- alpha: fp32 alpha (b-major, output) + bf16 alphaT (n-octet-major)
//            + bf16 alphaB (row-major, for MFMA b_assembled) ----------
__global__ __launch_bounds__(256) void alpha_kernel(
    const float* __restrict__ scores, const void* __restrict__ tau_p,
    const int* __restrict__ flags,
    float* __restrict__ alpha_out, unsigned short* __restrict__ alphaT,
    unsigned short* __restrict__ alphaB)
{
    const int b = blockIdx.x;
    const int tid = threadIdx.x;
    const float tauv = ldin(tau_p, 0, flags[ITAU]);
    float ar[8];
    float lsum = 0.f;
#pragma unroll
    for (int i = 0; i < 8; i++) {
        int n = i * 256 + tid;
        float s = scores[b * 2048 + n];
        float g = 1.f / (1.f + expf(-(s - tauv)));  // LAMBDA_SHARP=1
        ar[i] = g * expf(s);                         // TEMPERATURE=1
        lsum += ar[i];
    }
    __shared__ float sb[4];
    float wsv = wsum(lsum);
    if ((tid & 63) == 0) sb[tid >> 6] = wsv;
    __syncthreads();
    float tot = sb[0] + sb[1] + sb[2] + sb[3];
    float inv = 1.f / (tot + 1e-8f);
#pragma unroll
    for (int i = 0; i < 8; i++) {
        int n = i * 256 + tid;
        float al = ar[i] * inv;
        alpha_out[b * 2048 + n] = al;
        unsigned short bb = bfbits(al);
        alphaT[(size_t)(n >> 3) * 2048 + b * 8 + (n & 7)] = bb;
        alphaB[(size_t)b * 2048 + n] = bb;
    }
}

// ---------- W_assembled via MFMA (v3: 8d x 16e tile, 512 blocks, linear uvb) ----------
#define QW 520  // shorts per cg block (260 dwords = 1040 B)
__global__ __launch_bounds__(256, 2) void assemble_mfma(
    const unsigned short* __restrict__ alphaT,  // bf16 [n/8][256 b][8]
    const void* __restrict__ pool,
    const void* __restrict__ W_base,
    const int* __restrict__ flags,
    float* __restrict__ Wout)                   // (256,256,256) fp32
{
    const int fp = flags[IPOOL], fw = flags[IWBASE];
    const int lid = blockIdx.x;
    const int xcd = lid & 7, idx = lid >> 3;
    const int dt = idx & 31;                    // 32 d-tiles
    const int et = ((idx >> 5) << 3) + xcd;     // 16 e-tiles; XCD owns {xcd, xcd+8}
    const int d0 = dt * 8, e0 = et * 16;
    const int t = threadIdx.x;
    const int w = t >> 6, l = t & 63;
    const int q = l >> 4, l16 = l & 15;

    const int nl  = t >> 3;                     // local n 0..31
    const int sub = t & 7;
    const int dlp = sub >> 1;                   // d rows dlp*2, dlp*2+1
    const int eh  = sub & 1;                    // e-half: el = eh*8 + i
    const int jj  = nl & 7;                     // n-octet slot (kq == w)

    __shared__ __align__(16) float Us[2][32][76];
    __shared__ __align__(16) float Vs[2][32][132];
    __shared__ __align__(16) unsigned short uvb[8][QW];

    const float4* pool4 = (const float4*)pool;

    f32x4 acc[4][8] = {};

    auto load_stage = [&](int n0, float4* st) {
#pragma unroll
        for (int i = 0; i < 2; i++) {
            int f = i * 256 + t;
            int n = n0 + (f >> 4);
            int q4 = f & 15;
            if (fp == 0) {
                st[i] = pool4[(size_t)n * 1152 + d0 * 2 + q4];
            } else {
                size_t base = (size_t)n * 4608 + (size_t)d0 * 8 + q4 * 4;
                st[i] = make_float4(ldin(pool, base, 1), ldin(pool, base + 1, 1),
                                    ldin(pool, base + 2, 1), ldin(pool, base + 3, 1));
            }
        }
#pragma unroll
        for (int i = 0; i < 4; i++) {
            int f = i * 256 + t;
            int n = n0 + (f >> 5);
            int r = (f & 31) >> 2, e4 = f & 3;
            if (fp == 0) {
                st[2 + i] = pool4[(size_t)n * 1152 + 512 + r * 64 + (e0 >> 2) + e4];
            } else {
                size_t base = (size_t)n * 4608 + 2048 + (size_t)r * 256 + e0 + e4 * 4;
                st[2 + i] = make_float4(ldin(pool, base, 1), ldin(pool, base + 1, 1),
                                        ldin(pool, base + 2, 1), ldin(pool, base + 3, 1));
            }
        }
    };
    auto store_stage = [&](int bp, const float4* st) {
#pragma unroll
        for (int i = 0; i < 2; i++) {
            int f = i * 256 + t;
            *(float4*)&Us[bp][f >> 4][(f & 15) * 4] = st[i];
        }
#pragma unroll
        for (int i = 0; i < 4; i++) {
            int f = i * 256 + t;
            int r = (f & 31) >> 2, e4 = f & 3;
            *(float4*)&Vs[bp][f >> 5][r * 16 + e4 * 4] = st[2 + i];
        }
    };

    {
        float4 st[6];
        load_stage(0, st);
        store_stage(0, st);
    }
    __syncthreads();

    int p = 0;
    for (int step = 0; step < 64; step++) {
        const int n0 = step * 32;
        float4 stn[6];
        if (step < 63) load_stage(n0 + 32, stn);

        bf16x8 afr[4];
#pragma unroll
        for (int mt = 0; mt < 4; mt++) {
            const unsigned short* ap =
                alphaT + (size_t)(step * 4 + q) * 2048 + (w * 64 + mt * 16 + l16) * 8;
            afr[mt] = *(const bf16x8*)ap;
        }

        {
            const float* Ur = &Us[p][nl][dlp * 16];
            float4 Ua = *(const float4*)(Ur);
            float4 Ub = *(const float4*)(Ur + 4);
            float4 Uc = *(const float4*)(Ur + 8);
            float4 Ud = *(const float4*)(Ur + 12);
            float U0[8] = {Ua.x, Ua.y, Ua.z, Ua.w, Ub.x, Ub.y, Ub.z, Ub.w};
            float U1[8] = {Uc.x, Uc.y, Uc.z, Uc.w, Ud.x, Ud.y, Ud.z, Ud.w};
            float uv0[8] = {0.f, 0.f, 0.f, 0.f, 0.f, 0.f, 0.f, 0.f};
            float uv1[8] = {0.f, 0.f, 0.f, 0.f, 0.f, 0.f, 0.f, 0.f};
#pragma unroll
            for (int r = 0; r < 8; r++) {
                float4 va = *(const float4*)&Vs[p][nl][r * 16 + eh * 8];
                float4 vb = *(const float4*)&Vs[p][nl][r * 16 + eh * 8 + 4];
                uv0[0] += U0[r] * va.x; uv0[1] += U0[r] * va.y;
                uv0[2] += U0[r] * va.z; uv0[3] += U0[r] * va.w;
                uv0[4] += U0[r] * vb.x; uv0[5] += U0[r] * vb.y;
                uv0[6] += U0[r] * vb.z; uv0[7] += U0[r] * vb.w;
                uv1[0] += U1[r] * va.x; uv1[1] += U1[r] * va.y;
                uv1[2] += U1[r] * va.z; uv1[3] += U1[r] * va.w;
                uv1[4] += U1[r] * vb.x; uv1[5] += U1[r] * vb.y;
                uv1[6] += U1[r] * vb.z; uv1[7] += U1[r] * vb.w;
            }
            const int cg0 = dlp * 2, cg1 = cg0 + 1;
            const int wbase = w * 128 + eh * 64 + jj;
#pragma unroll
            for (int i = 0; i < 8; i++) {
                uvb[cg0][wbase + i * 8] = bfbits(uv0[i]);
                uvb[cg1][wbase + i * 8] = bfbits(uv1[i]);
            }
        }
        __syncthreads();

        bf16x8 bfr[8];
#pragma unroll
        for (int cg = 0; cg < 8; cg++)
            bfr[cg] = *(const bf16x8*)&uvb[cg][l * 8];
        if (step < 63) store_stage(p ^ 1, stn);
#pragma unroll
        for (int mt = 0; mt < 4; mt++)
#pragma unroll
            for (int cg = 0; cg < 8; cg++)
                acc[mt][cg] = __builtin_amdgcn_mfma_f32_16x16x32_bf16(
                    afr[mt], bfr[cg], acc[mt][cg], 0, 0, 0);
        __syncthreads();
        p ^= 1;
    }

    float wb[8];
#pragma unroll
    for (int cg = 0; cg < 8; cg++)
        wb[cg] = ldin(W_base, (size_t)(d0 + cg) * 256 + e0 + l16, fw);
#pragma unroll
    for (int mt = 0; mt < 4; mt++) {
#pragma unroll
        for (int cg = 0; cg < 8; cg++) {
            size_t col = (size_t)(d0 + cg) * 256 + e0 + l16;
#pragma unroll
            for (int r = 0; r < 4; r++) {
                int b = w * 64 + mt * 16 + q * 4 + r;
                Wout[(size_t)b * 65536 + col] = acc[mt][cg][r] + wb[cg];
            }
        }
    }
}

// ---------- h_t + y (reads fp32 W_assembled) ----------
__global__ __launch_bounds__(256) void hty_kernel(
    const float* __restrict__ Wout, const float* __restrict__ hA,
    const float* __restrict__ bass, const void* __restrict__ gamma_p,
    const int* __restrict__ flags, float* __restrict__ y)
{
    const int b = blockIdx.y;
    const int c = blockIdx.x * 4 + (threadIdx.x >> 6);
    const int lane = threadIdx.x & 63;
    const float4 wv = ((const float4*)(Wout + ((size_t)b * 65536 + c * 256)))[lane];
    const float4 h4 = ((const float4*)(hA + b * 256))[lane];
    float s = wv.x * h4.x + wv.y * h4.y + wv.z * h4.z + wv.w * h4.w;
    s = wsum(s);
    if (lane == 0) {
        float ht = s + bass[b * 256 + c];
        y[b * 256 + c] = hA[b * 256 + c] + ldin(gamma_p, 0, flags[IGAMMA]) * ht;
    }
}

// ---------- layernorm ----------
__global__ __launch_bounds__(256) void ln_kernel(
    const float* __restrict__ y, const void* __restrict__ ln_scale,
    const void* __restrict__ ln_bias, const int* __restrict__ flags,
    float* __restrict__ hmid)
{
    const int fs = flags[ILNS], fb = flags[ILNB];
    const int b = blockIdx.x, tid = threadIdx.x;
    float v = y[b * 256 + tid];
    __shared__ float s1b[4], s2b[4];
    float w1 = wsum(v), w2 = wsum(v * v);
    if ((tid & 63) == 0) { s1b[tid >> 6] = w1; s2b[tid >> 6] = w2; }
    __syncthreads();
    float mu = (s1b[0] + s1b[1] + s1b[2] + s1b[3]) * (1.f / 256.f);
    float ex2 = (s2b[0] + s2b[1] + s2b[2] + s2b[3]) * (1.f / 256.f);
    float var = ex2 - mu * mu;
    float inv = 1.f / sqrtf(var + 1e-6f);
    hmid[b * 256 + tid] = (v - mu) * inv * ldin(ln_scale, tid, fs)
                        + ldin(ln_bias, tid, fb);
}

// ---------- launch ----------
extern "C" void kernel_launch(void* const* d_in, const int* in_sizes, int n_in,
                              void* d_out, int out_size, void* d_ws, size_t ws_size,
                              hipStream_t stream)
{
    (void)out_size; (void)n_in;
    const void* x      = d_in[0];
    const void* pool   = d_in[1];
    const void* A_w0   = d_in[2];
    const void* A_b0   = d_in[3];
    const void* A_w1   = d_in[4];
    const void* A_b1   = d_in[5];
    const void* W_Q    = d_in[6];
    const void* W_K    = d_in[7];
    const void* logits = d_in[8];
    const void* tau    = d_in[9];
    const void* W_base = d_in[10];
    const void* b_base = d_in[11];
    const void* gamma  = d_in[12];
    const void* ln_s   = d_in[13];
    const void* ln_b   = d_in[14];
    const void* B_w0   = d_in[15];
    const void* B_b0   = d_in[16];
    const void* B_w1   = d_in[17];
    const void* B_b1   = d_in[18];

    // Outputs: FP32, concatenated in return order.
    float* out       = (float*)d_out;
    float* out0      = out;               // (256,512)
    float* out_alpha = out + 131072;      // (256,2048)
    float* out_W     = out + 655360;      // (256,256,256) = 16.7M floats
    float* out_keys  = out + 17432576;    // (2048,4,64)

    // Small scratch, always in d_ws
    float* ws = (float*)d_ws;
    int*   flagp   = (int*)d_ws;          // ints [0,32)
    float* ws_w    = ws + 32;
    float* ws_hA   = ws + 64;             // 65536
    float* ws_qw   = ws + 65600;          // 65536
    float* ws_bass = ws + 131136;         // 65536
    float* ws_y    = ws + 196672;         // 65536
    float* ws_hmid = ws + 262208;         // 65536 -> 327744
    unsigned short* alpha_bf = (unsigned short*)(ws + 327744);  // alphaT: 524288 bf16
    // small region ends at 589888 floats (2.36 MB)

    // Big slots: prefer d_ws; fall back to out_W region (dead until assemble).
    size_t wsf = ws_size / 4;
    bool full = wsf >= 1638464;
    float* slotA;   // G -> scores -> T1
    float* slotB;   // kn
    float* T1;
    float* scr = (float*)out_W;
    if (full) {
        slotA = ws + 589888;
        slotB = ws + 1114176;
        T1    = slotA;
    } else {
        slotA = scr;
        slotB = scr + 524288;
        T1    = (float*)alpha_bf;  // alphaT dead after assemble; 262144 floats fits
    }
    float* G      = slotA;
    float* scores = slotA;
    float* kn     = slotB;

    // bf16 staging buffers live in the dead out_W region (all dead before assemble):
    unsigned short* poolbf = (unsigned short*)(scr + 2097152);   // 9.44M shorts
    unsigned short* wkbT   = (unsigned short*)(scr + 7340032);   // 1.18M shorts
    unsigned short* biasT  = (unsigned short*)(scr + 8388608);   // 524288 shorts
    unsigned short* alphaB = (unsigned short*)(scr + 8912896);   // 524288 shorts

    // 0) per-input dtype detection
    P19 ip;
    for (int i = 0; i < 19; i++) { ip.p[i] = d_in[i]; ip.n[i] = in_sizes[i]; }
    detect_all<<<19, 256, 0, stream>>>(ip, flagp);
    // 1) aspect softmax
    softmax4_kernel<<<1, 64, 0, stream>>>(logits, flagp, ws_w);
    // 1b) bf16 converts for MFMA GEMMs
    pool2bf<<<2048, 256, 0, stream>>>(pool, flagp, poolbf);
    wk2bfT<<<dim3(72, 4), 256, 0, stream>>>(W_K, flagp, wkbT);
    bias2bfT<<<dim3(32, 4), 256, 0, stream>>>(pool, flagp, biasT);
    // 2) A-MLP1: split-K atomic (G pre-init with bias) + gelu pass
    init_bias_kernel<<<1024, 256, 0, stream>>>(G, A_b0, IAB0, flagp, 1024, 262144);
    gemm64_splitk<0><<<dim3(16, 4, 4), 256, 0, stream>>>(
        x, 512, IX, A_w0, 1024, IAW0, 0,
        G, 1024, 128, flagp);
    gelu_kernel<<<1024, 256, 0, stream>>>(G, 262144);
    // A-MLP2: split-K atomic (C pre-init with bias), 128 blocks
    init_bias_kernel<<<256, 256, 0, stream>>>(ws_hA, A_b1, IAB1, flagp, 256, 65536);
    gemm64_splitk<0><<<dim3(4, 4, 8), 256, 0, stream>>>(
        G, 1024, -1, A_w1, 256, IAW1, 0,
        ws_hA, 256, 128, flagp);
    // 3) keys = poolbf @ wkbT^T via MFMA split-K atomic, then normalize -> kn
    init_bias_kernel<<<2048, 256, 0, stream>>>(out_keys, nullptr, -1, flagp, 256, 524288);
    gemm_mfma_atomic<<<dim3(16, 4, 16), 256, 0, stream>>>(
        poolbf, 4608, wkbT, 4608, out_keys, 256, 288);
    knorm_kernel<<<2048, 256, 0, stream>>>(out_keys, kn);
    // 4) queries
    queries_kernel<<<256, 256, 0, stream>>>(ws_hA, W_Q, flagp, ws_w, ws_qw);
    // 5) scores = qw @ kn^T
    gemm64<1><<<dim3(32, 4), 256, 0, stream>>>(
        ws_qw, 256, -1, kn, 256, -1, 0, nullptr, -1,
        scores, 2048, 256, 2048, 256, 0, flagp);
    // 6) alpha -> out_alpha (fp32) + alphaT (n-octet bf16) + alphaB (row-major bf16)
    alpha_kernel<<<256, 256, 0, stream>>>(scores, tau, flagp, out_alpha, alpha_bf, alphaB);
    // 7) b_assembled = alpha @ biasT^T + b_base via MFMA split-K atomic
    init_bias_kernel<<<256, 256, 0, stream>>>(ws_bass, b_base, IBBASE, flagp, 256, 65536);
    gemm_mfma_atomic<<<dim3(2, 4, 8), 256, 0, stream>>>(
        alphaB, 2048, biasT, 2048, ws_bass, 256, 256);
    // 8) W_assembled via MFMA (dominant)
    assemble_mfma<<<512, 256, 0, stream>>>(alpha_bf, pool, W_base, flagp, out_W);
    // 9) h_t, y
    hty_kernel<<<dim3(64, 256), 256, 0, stream>>>(out_W, ws_hA, ws_bass, gamma, flagp, ws_y);
    // 10) layernorm
    ln_kernel<<<256, 256, 0, stream>>>(ws_y, ln_s, ln_b, flagp, ws_hmid);
    // 11) B-MLP1: split-K atomic (T1 pre-init with bias) + gelu pass
    init_bias_kernel<<<1024, 256, 0, stream>>>(T1, B_b0, IBB0, flagp, 1024, 262144);
    gemm64_splitk<0><<<dim3(16, 4, 2), 256, 0, stream>>>(
        ws_hmid, 256, -1, B_w0, 1024, IBW0, 0,
        T1, 1024, 128, flagp);
    gelu_kernel<<<1024, 256, 0, stream>>>(T1, 262144);
    // B-MLP2: split-K atomic (out0 pre-init with bias), 128 blocks
    init_bias_kernel<<<512, 256, 0, stream>>>(out0, B_b1, IBB1, flagp, 512, 131072);
    gemm64_splitk<0><<<dim3(8, 4, 4), 256, 0, stream>>>(
        T1, 1024, -1, B_w1, 512, IBW1, 0,
        out0, 512, 256, flagp);
}

// Round 5
// 567.700 us; speedup vs baseline: 3.7503x; 1.1028x over previous
//
#include <hip/hip_runtime.h>
#include <hip/hip_bf16.h>
#include <math.h>

#define N_POOL 2048
#define D_POOL 4608

typedef __hip_bfloat16 bf16;
typedef __attribute__((ext_vector_type(8))) short bf16x8;
typedef __attribute__((ext_vector_type(4))) float f32x4;
typedef __attribute__((ext_vector_type(4))) unsigned short u16x4;

// input indices
#define IX 0
#define IPOOL 1
#define IAW0 2
#define IAB0 3
#define IAW1 4
#define IAB1 5
#define IWQ 6
#define IWK 7
#define ILOG 8
#define ITAU 9
#define IWBASE 10
#define IBBASE 11
#define IGAMMA 12
#define ILNS 13
#define ILNB 14
#define IBW0 15
#define IBB0 16
#define IBW1 17
#define IBB1 18

// ---------- helpers ----------
__device__ inline float wsum(float v) {
#pragma unroll
    for (int off = 32; off > 0; off >>= 1) v += __shfl_xor(v, off, 64);
    return v;
}
__device__ inline float ldin(const void* p, size_t i, int f) {
    if (f) return __bfloat162float(((const bf16*)p)[i]);
    return ((const float*)p)[i];
}
__device__ inline float gelu_f(float x) {
    float t = tanhf(0.7978845608028654f * (x + 0.044715f * x * x * x));
    return 0.5f * x * (1.0f + t);
}
__device__ inline unsigned short bfbits(float f) {
    __hip_bfloat16 h = __float2bfloat16(f);
    return *reinterpret_cast<unsigned short*>(&h);
}

// ---------- per-input dtype detector (insurance; inputs measured all-fp32) ----------
struct P19 { const void* p[19]; long n[19]; };

__global__ void detect_all(P19 ip, int* flags) {
    const int j = blockIdx.x;
    const unsigned short* u = (const unsigned short*)ip.p[j];
    long nelem = ip.n[j];
    long nhalf = nelem >> 1; if (nhalf < 1) nhalf = 1;
    long kstep = (nhalf + 8191) >> 13; if (kstep < 1) kstep = 1;
    int W = 0, S = 0, Z = 0, O = 0, C = 0;
    for (long k = threadIdx.x; k * kstep < nhalf; k += 256) {
        long i = k * kstep * 2;
        unsigned short ev = u[i], od = u[i + 1];
        int e = (ev >> 7) & 0xFF;
        if (ev == 0) Z++;
        else if (e >= 90 && e <= 141) S++;
        else W++;
        if (od) O++;
        C++;
    }
    __shared__ int sw[256], ss[256], sz[256], so[256], sc[256];
    sw[threadIdx.x] = W; ss[threadIdx.x] = S; sz[threadIdx.x] = Z;
    so[threadIdx.x] = O; sc[threadIdx.x] = C;
    __syncthreads();
    if (threadIdx.x == 0) {
        int tw = 0, ts = 0, tz = 0, to = 0, tc = 0;
        for (int i = 0; i < 256; i++) {
            tw += sw[i]; ts += ss[i]; tz += sz[i]; to += so[i]; tc += sc[i];
        }
        int f;
        if (tw * 16 > tc) f = 0;
        else if (ts == 0 && tw == 0) f = (to > 0) ? 0 : 1;
        else f = (ts >= tz) ? 1 : 0;
        flags[j] = f;
    }
}

// ---------- split-K 64x64 GEMM (fp32): atomically accumulates A@B into pre-init C ----------
template <int TRANSB>
__global__ __launch_bounds__(256) void gemm64_splitk(
    const void* __restrict__ A, int lda, int afi,
    const void* __restrict__ B, int ldb, int bfi, size_t boffs,
    float* __restrict__ C, int ldc, int KC, const int* __restrict__ flags)
{
    const int fa = (afi >= 0) ? flags[afi] : 0;
    const int fb = (bfi >= 0) ? flags[bfi] : 0;
    __shared__ __align__(16) float As[16][68];
    __shared__ __align__(16) float Bs[16][68];
    const int tid = threadIdx.x;
    const int tx = tid & 15, ty = tid >> 4;
    const int bx = blockIdx.x, by = blockIdx.y;
    const int kbeg = blockIdx.z * KC;
    float acc[4][4] = {};
    for (int k0 = kbeg; k0 < kbeg + KC; k0 += 16) {
#pragma unroll
        for (int i = 0; i < 4; i++) {
            int idx = tid + i * 256;
            int m = idx >> 4, kk = idx & 15;
            As[kk][m] = ldin(A, (size_t)(by * 64 + m) * lda + k0 + kk, fa);
        }
#pragma unroll
        for (int i = 0; i < 4; i++) {
            int idx = tid + i * 256;
            if (TRANSB) {
                int nn2 = idx >> 4, kk = idx & 15;
                Bs[kk][nn2] = ldin(B, boffs + (size_t)(bx * 64 + nn2) * ldb + k0 + kk, fb);
            } else {
                int kk = idx >> 6, nn2 = idx & 63;
                Bs[kk][nn2] = ldin(B, boffs + (size_t)(k0 + kk) * ldb + bx * 64 + nn2, fb);
            }
        }
        __syncthreads();
#pragma unroll
        for (int kk = 0; kk < 16; kk++) {
            float4 av4 = *(const float4*)&As[kk][ty * 4];
            float4 bv4 = *(const float4*)&Bs[kk][tx * 4];
            float av[4] = {av4.x, av4.y, av4.z, av4.w};
            float bv[4] = {bv4.x, bv4.y, bv4.z, bv4.w};
#pragma unroll
            for (int i = 0; i < 4; i++)
#pragma unroll
                for (int j = 0; j < 4; j++) acc[i][j] += av[i] * bv[j];
        }
        __syncthreads();
    }
#pragma unroll
    for (int i = 0; i < 4; i++) {
        int m = by * 64 + ty * 4 + i;
#pragma unroll
        for (int j = 0; j < 4; j++) {
            int n = bx * 64 + tx * 4 + j;
            atomicAdd(&C[(size_t)m * ldc + n], acc[i][j]);
        }
    }
}

// ---------- bf16 MFMA split-K GEMM, no LDS: C += A@B^T (atomic) ----------
// A: bf16 row-major [M][lda]. B: bf16 n-major [ncols][ldb]. Tile 128m x 64n.
__global__ __launch_bounds__(256) void gemm_mfma_atomic(
    const unsigned short* __restrict__ A, int lda,
    const unsigned short* __restrict__ Bmat, int ldb,
    float* __restrict__ C, int ldc, int KC)
{
    const int m0 = blockIdx.x * 128;
    const int n0 = blockIdx.y * 64;
    const unsigned short* B = Bmat + (size_t)blockIdx.y * 64 * ldb;
    const int kbeg = blockIdx.z * KC;
    const int t = threadIdx.x, w = t >> 6, l = t & 63;
    const int q = l >> 4, l16 = l & 15;
    f32x4 acc[2][4] = {};
    for (int k0 = kbeg; k0 < kbeg + KC; k0 += 32) {
        bf16x8 afr[2], bfr[4];
#pragma unroll
        for (int mt = 0; mt < 2; mt++)
            afr[mt] = *(const bf16x8*)&A[(size_t)(m0 + w * 32 + mt * 16 + l16) * lda + k0 + q * 8];
#pragma unroll
        for (int nt = 0; nt < 4; nt++)
            bfr[nt] = *(const bf16x8*)&B[(size_t)(nt * 16 + l16) * ldb + k0 + q * 8];
#pragma unroll
        for (int mt = 0; mt < 2; mt++)
#pragma unroll
            for (int nt = 0; nt < 4; nt++)
                acc[mt][nt] = __builtin_amdgcn_mfma_f32_16x16x32_bf16(
                    afr[mt], bfr[nt], acc[mt][nt], 0, 0, 0);
    }
#pragma unroll
    for (int mt = 0; mt < 2; mt++)
#pragma unroll
        for (int nt = 0; nt < 4; nt++)
#pragma unroll
            for (int r = 0; r < 4; r++) {
                int m = m0 + w * 32 + mt * 16 + q * 4 + r;
                atomicAdd(&C[(size_t)m * ldc + n0 + nt * 16 + l16], acc[mt][nt][r]);
            }
}

// ---------- bf16 MFMA fused GEMM, direct store: out = act(A@B^T + bias) ----------
// Single K-pass (no split). Optional fp32 and/or bf16 outputs.
template <int ACT>
__global__ __launch_bounds__(256) void gemm_mfma_fused(
    const unsigned short* __restrict__ A, int lda,
    const unsigned short* __restrict__ Bmat, int ldb,
    const void* __restrict__ bias, int bifi, const int* __restrict__ flags,
    float* __restrict__ Cf, unsigned short* __restrict__ Cbf,
    int ldc, int K)
{
    const int m0 = blockIdx.x * 128;
    const int n0 = blockIdx.y * 64;
    const unsigned short* B = Bmat + (size_t)blockIdx.y * 64 * ldb;
    const int t = threadIdx.x, w = t >> 6, l = t & 63;
    const int q = l >> 4, l16 = l & 15;
    f32x4 acc[2][4] = {};
    for (int k0 = 0; k0 < K; k0 += 32) {
        bf16x8 afr[2], bfr[4];
#pragma unroll
        for (int mt = 0; mt < 2; mt++)
            afr[mt] = *(const bf16x8*)&A[(size_t)(m0 + w * 32 + mt * 16 + l16) * lda + k0 + q * 8];
#pragma unroll
        for (int nt = 0; nt < 4; nt++)
            bfr[nt] = *(const bf16x8*)&B[(size_t)(nt * 16 + l16) * ldb + k0 + q * 8];
#pragma unroll
        for (int mt = 0; mt < 2; mt++)
#pragma unroll
            for (int nt = 0; nt < 4; nt++)
                acc[mt][nt] = __builtin_amdgcn_mfma_f32_16x16x32_bf16(
                    afr[mt], bfr[nt], acc[mt][nt], 0, 0, 0);
    }
    float bv[4];
#pragma unroll
    for (int nt = 0; nt < 4; nt++)
        bv[nt] = bias ? ldin(bias, n0 + nt * 16 + l16, (bifi >= 0) ? flags[bifi] : 0) : 0.f;
#pragma unroll
    for (int mt = 0; mt < 2; mt++)
#pragma unroll
        for (int nt = 0; nt < 4; nt++)
#pragma unroll
            for (int r = 0; r < 4; r++) {
                int m = m0 + w * 32 + mt * 16 + q * 4 + r;
                int n = n0 + nt * 16 + l16;
                float v = acc[mt][nt][r] + bv[nt];
                if (ACT == 1) v = gelu_f(v);
                if (Cf)  Cf[(size_t)m * ldc + n] = v;
                if (Cbf) Cbf[(size_t)m * ldc + n] = bfbits(v);
            }
}

// ---------- converts: pool -> bf16 row-major ----------
__global__ __launch_bounds__(256) void pool2bf(
    const void* __restrict__ pool, const int* __restrict__ flags,
    unsigned short* __restrict__ pb)
{
    const int fp = flags[IPOOL];
    const size_t total = (size_t)N_POOL * D_POOL;
    for (size_t i = ((size_t)blockIdx.x * 256 + threadIdx.x) * 4; i < total;
         i += (size_t)gridDim.x * 1024) {
        u16x4 o;
        if (fp == 0) {
            float4 v = *(const float4*)((const float*)pool + i);
            o[0] = bfbits(v.x); o[1] = bfbits(v.y); o[2] = bfbits(v.z); o[3] = bfbits(v.w);
        } else {
            o = *(const u16x4*)((const unsigned short*)pool + i);
        }
        *(u16x4*)&pb[i] = o;
    }
}

// ---------- generic fp32/bf16 -> bf16 row-major convert ----------
__global__ __launch_bounds__(256) void cvt2bf(
    const void* __restrict__ src, int fi, const int* __restrict__ flags,
    unsigned short* __restrict__ dst, int total)
{
    const int f = (fi >= 0) ? flags[fi] : 0;
    int i = (blockIdx.x * 256 + threadIdx.x) * 4;
    if (i >= total) return;
    if (f == 0) {
        float4 v = *(const float4*)((const float*)src + i);
        u16x4 o;
        o[0] = bfbits(v.x); o[1] = bfbits(v.y); o[2] = bfbits(v.z); o[3] = bfbits(v.w);
        *(u16x4*)&dst[i] = o;
    } else {
        *(u16x4*)&dst[i] = *(const u16x4*)((const unsigned short*)src + i);
    }
}

// ---------- transpose to bf16: dst[z][c][r] = src[z][r][c]; rows,cols mult of 64 ----------
__global__ __launch_bounds__(256) void transp_bf(
    const void* __restrict__ src, int fi, const int* __restrict__ flags,
    unsigned short* __restrict__ dst, int rows, int cols)
{
    const int f = (fi >= 0) ? flags[fi] : 0;
    const size_t zoff = (size_t)blockIdx.z * rows * cols;
    const int rb = blockIdx.y * 64, cb = blockIdx.x * 64;
    __shared__ float tile[64][65];
    const int t = threadIdx.x;
    const int lr = t >> 6, lc = t & 63;
#pragma unroll
    for (int i = 0; i < 16; i++) {
        int r = i * 4 + lr;
        tile[r][lc] = ldin(src, zoff + (size_t)(rb + r) * cols + cb + lc, f);
    }
    __syncthreads();
#pragma unroll
    for (int i = 0; i < 16; i++) {
        int c = i * 4 + lr;
        dst[zoff + (size_t)(cb + c) * rows + rb + lc] = bfbits(tile[lc][c]);
    }
}

// ---------- W_K fp32 [4][4608][64] -> bf16 n-major [4][64][4608] ----------
__global__ __launch_bounds__(256) void wk2bfT(
    const void* __restrict__ W_K, const int* __restrict__ flags,
    unsigned short* __restrict__ out)
{
    const int fk = flags[IWK];
    const int a = blockIdx.y, kb = blockIdx.x, t = threadIdx.x;
#pragma unroll
    for (int i = 0; i < 16; i++) {
        int idx = i * 256 + t;
        int kk = idx >> 6, qq = idx & 63;
        float v = ldin(W_K, (size_t)a * 294912 + (size_t)(kb * 64 + kk) * 64 + qq, fk);
        out[(size_t)(a * 64 + qq) * 4608 + kb * 64 + kk] = bfbits(v);
    }
}

// ---------- pool[:,4096:4352] -> bf16 col-major [256][2048] ----------
__global__ __launch_bounds__(256) void bias2bfT(
    const void* __restrict__ pool, const int* __restrict__ flags,
    unsigned short* __restrict__ out)
{
    const int fp = flags[IPOOL];
    const int nb = blockIdx.x, cb = blockIdx.y, t = threadIdx.x;
#pragma unroll
    for (int i = 0; i < 16; i++) {
        int idx = i * 256 + t;
        int nn = idx >> 6, cc = idx & 63;
        float v = ldin(pool, (size_t)(nb * 64 + nn) * 4608 + 4096 + cb * 64 + cc, fp);
        out[(size_t)(cb * 64 + cc) * 2048 + nb * 64 + nn] = bfbits(v);
    }
}

// ---------- C[i] = bias[i % N] (or 0) ----------
__global__ __launch_bounds__(256) void init_bias_kernel(
    float* __restrict__ C, const void* __restrict__ bias, int bifi,
    const int* __restrict__ flags, int N, int total)
{
    int i = blockIdx.x * 256 + threadIdx.x;
    if (i >= total) return;
    float v = 0.f;
    if (bias) v = ldin(bias, i % N, (bifi >= 0) ? flags[bifi] : 0);
    C[i] = v;
}

// ---------- elementwise gelu in place ----------
__global__ __launch_bounds__(256) void gelu_kernel(float* __restrict__ buf, int total)
{
    int i = blockIdx.x * 256 + threadIdx.x;
    if (i < total) buf[i] = gelu_f(buf[i]);
}

// ---------- per-(n,aspect) normalize -> bf16 ----------
__global__ __launch_bounds__(256) void knorm_kernel(
    const float* __restrict__ keys, unsigned short* __restrict__ knbf)
{
    const int n = blockIdx.x;
    const int a = threadIdx.x >> 6, q = threadIdx.x & 63;
    float v = keys[(size_t)n * 256 + a * 64 + q];
    float ss = wsum(v * v);
    knbf[(size_t)n * 256 + a * 64 + q] = bfbits(v / (sqrtf(ss) + 1e-8f));
}

// ---------- query normalize + aspect-weight fold -> bf16 ----------
__global__ __launch_bounds__(256) void qnorm_kernel(
    const float* __restrict__ qraw, const float* __restrict__ w,
    unsigned short* __restrict__ qwbf)
{
    const int b = blockIdx.x;
    const int a = threadIdx.x >> 6, q = threadIdx.x & 63;
    float v = qraw[b * 256 + a * 64 + q];
    float ss = wsum(v * v);
    qwbf[b * 256 + a * 64 + q] = bfbits(v / (sqrtf(ss) + 1e-8f) * w[a]);
}

// ---------- softmax over 4 aspect logits ----------
__global__ void softmax4_kernel(const void* __restrict__ logits,
                                const int* __restrict__ flags, float* __restrict__ w) {
    if (threadIdx.x == 0) {
        int f = flags[ILOG];
        float l0 = ldin(logits, 0, f), l1 = ldin(logits, 1, f);
        float l2 = ldin(logits, 2, f), l3 = ldin(logits, 3, f);
        float m = fmaxf(fmaxf(l0, l1), fmaxf(l2, l3));
        float e0 = expf(l0 - m), e1 = expf(l1 - m), e2 = expf(l2 - m), e3 = expf(l3 - m);
        float s = e0 + e1 + e2 + e3;
        w[0] = e0 / s; w[1] = e1 / s; w[2] = e2 / s; w[3] = e3 / s;
    }
}

// ---------- alpha: fp32 alpha (b-major, output) + bf16 alphaT (n-octet-major)
//            + bf16 alphaB (row-major) ----------
__global__ __launch_bounds__(256) void alpha_kernel(
    const float* __restrict__ scores, const void* __restrict__ tau_p,
    const int* __restrict__ flags,
    float* __restrict__ alpha_out, unsigned short* __restrict__ alphaT,
    unsigned short* __restrict__ alphaB)
{
    const int b = blockIdx.x;
    const int tid = threadIdx.x;
    const float tauv = ldin(tau_p, 0, flags[ITAU]);
    float ar[8];
    float lsum = 0.f;
#pragma unroll
    for (int i = 0; i < 8; i++) {
        int n = i * 256 + tid;
        float s = scores[b * 2048 + n];
        float g = 1.f / (1.f + expf(-(s - tauv)));  // LAMBDA_SHARP=1
        ar[i] = g * expf(s);                         // TEMPERATURE=1
        lsum += ar[i];
    }
    __shared__ float sb[4];
    float wsv = wsum(lsum);
    if ((tid & 63) == 0) sb[tid >> 6] = wsv;
    __syncthreads();
    float tot = sb[0] + sb[1] + sb[2] + sb[3];
    float inv = 1.f / (tot + 1e-8f);
#pragma unroll
    for (int i = 0; i < 8; i++) {
        int n = i * 256 + tid;
        float al = ar[i] * inv;
        alpha_out[b * 2048 + n] = al;
        unsigned short bb = bfbits(al);
        alphaT[(size_t)(n >> 3) * 2048 + b * 8 + (n & 7)] = bb;
        alphaB[(size_t)b * 2048 + n] = bb;
    }
}

// ---------- W_assembled via MFMA (v3: 8d x 16e tile, 512 blocks, linear uvb) ----------
#define QW 520  // shorts per cg block (260 dwords = 1040 B)
__global__ __launch_bounds__(256, 2) void assemble_mfma(
    const unsigned short* __restrict__ alphaT,  // bf16 [n/8][256 b][8]
    const void* __restrict__ pool,
    const void* __restrict__ W_base,
    const int* __restrict__ flags,
    float* __restrict__ Wout)                   // (256,256,256) fp32
{
    const int fp = flags[IPOOL], fw = flags[IWBASE];
    const int lid = blockIdx.x;
    const int xcd = lid & 7, idx = lid >> 3;
    const int dt = idx & 31;                    // 32 d-tiles
    const int et = ((idx >> 5) << 3) + xcd;     // 16 e-tiles; XCD owns {xcd, xcd+8}
    const int d0 = dt * 8, e0 = et * 16;
    const int t = threadIdx.x;
    const int w = t >> 6, l = t & 63;
    const int q = l >> 4, l16 = l & 15;

    const int nl  = t >> 3;                     // local n 0..31
    const int sub = t & 7;
    const int dlp = sub >> 1;                   // d rows dlp*2, dlp*2+1
    const int eh  = sub & 1;                    // e-half: el = eh*8 + i
    const int jj  = nl & 7;                     // n-octet slot (kq == w)

    __shared__ __align__(16) float Us[2][32][76];
    __shared__ __align__(16) float Vs[2][32][132];
    __shared__ __align__(16) unsigned short uvb[8][QW];

    const float4* pool4 = (const float4*)pool;

    f32x4 acc[4][8] = {};

    auto load_stage = [&](int n0, float4* st) {
#pragma unroll
        for (int i = 0; i < 2; i++) {
            int f = i * 256 + t;
            int n = n0 + (f >> 4);
            int q4 = f & 15;
            if (fp == 0) {
                st[i] = pool4[(size_t)n * 1152 + d0 * 2 + q4];
            } else {
                size_t base = (size_t)n * 4608 + (size_t)d0 * 8 + q4 * 4;
                st[i] = make_float4(ldin(pool, base, 1), ldin(pool, base + 1, 1),
                                    ldin(pool, base + 2, 1), ldin(pool, base + 3, 1));
            }
        }
#pragma unroll
        for (int i = 0; i < 4; i++) {
            int f = i * 256 + t;
            int n = n0 + (f >> 5);
            int r = (f & 31) >> 2, e4 = f & 3;
            if (fp == 0) {
                st[2 + i] = pool4[(size_t)n * 1152 + 512 + r * 64 + (e0 >> 2) + e4];
            } else {
                size_t base = (size_t)n * 4608 + 2048 + (size_t)r * 256 + e0 + e4 * 4;
                st[2 + i] = make_float4(ldin(pool, base, 1), ldin(pool, base + 1, 1),
                                        ldin(pool, base + 2, 1), ldin(pool, base + 3, 1));
            }
        }
    };
    auto store_stage = [&](int bp, const float4* st) {
#pragma unroll
        for (int i = 0; i < 2; i++) {
            int f = i * 256 + t;
            *(float4*)&Us[bp][f >> 4][(f & 15) * 4] = st[i];
        }
#pragma unroll
        for (int i = 0; i < 4; i++) {
            int f = i * 256 + t;
            int r = (f & 31) >> 2, e4 = f & 3;
            *(float4*)&Vs[bp][f >> 5][r * 16 + e4 * 4] = st[2 + i];
        }
    };

    {
        float4 st[6];
        load_stage(0, st);
        store_stage(0, st);
    }
    __syncthreads();

    int p = 0;
    for (int step = 0; step < 64; step++) {
        const int n0 = step * 32;
        float4 stn[6];
        if (step < 63) load_stage(n0 + 32, stn);

        bf16x8 afr[4];
#pragma unroll
        for (int mt = 0; mt < 4; mt++) {
            const unsigned short* ap =
                alphaT + (size_t)(step * 4 + q) * 2048 + (w * 64 + mt * 16 + l16) * 8;
            afr[mt] = *(const bf16x8*)ap;
        }

        {
            const float* Ur = &Us[p][nl][dlp * 16];
            float4 Ua = *(const float4*)(Ur);
            float4 Ub = *(const float4*)(Ur + 4);
            float4 Uc = *(const float4*)(Ur + 8);
            float4 Ud = *(const float4*)(Ur + 12);
            float U0[8] = {Ua.x, Ua.y, Ua.z, Ua.w, Ub.x, Ub.y, Ub.z, Ub.w};
            float U1[8] = {Uc.x, Uc.y, Uc.z, Uc.w, Ud.x, Ud.y, Ud.z, Ud.w};
            float uv0[8] = {0.f, 0.f, 0.f, 0.f, 0.f, 0.f, 0.f, 0.f};
            float uv1[8] = {0.f, 0.f, 0.f, 0.f, 0.f, 0.f, 0.f, 0.f};
#pragma unroll
            for (int r = 0; r < 8; r++) {
                float4 va = *(const float4*)&Vs[p][nl][r * 16 + eh * 8];
                float4 vb = *(const float4*)&Vs[p][nl][r * 16 + eh * 8 + 4];
                uv0[0] += U0[r] * va.x; uv0[1] += U0[r] * va.y;
                uv0[2] += U0[r] * va.z; uv0[3] += U0[r] * va.w;
                uv0[4] += U0[r] * vb.x; uv0[5] += U0[r] * vb.y;
                uv0[6] += U0[r] * vb.z; uv0[7] += U0[r] * vb.w;
                uv1[0] += U1[r] * va.x; uv1[1] += U1[r] * va.y;
                uv1[2] += U1[r] * va.z; uv1[3] += U1[r] * va.w;
                uv1[4] += U1[r] * vb.x; uv1[5] += U1[r] * vb.y;
                uv1[6] += U1[r] * vb.z; uv1[7] += U1[r] * vb.w;
            }
            const int cg0 = dlp * 2, cg1 = cg0 + 1;
            const int wbase = w * 128 + eh * 64 + jj;
#pragma unroll
            for (int i = 0; i < 8; i++) {
                uvb[cg0][wbase + i * 8] = bfbits(uv0[i]);
                uvb[cg1][wbase + i * 8] = bfbits(uv1[i]);
            }
        }
        __syncthreads();

        bf16x8 bfr[8];
#pragma unroll
        for (int cg = 0; cg < 8; cg++)
            bfr[cg] = *(const bf16x8*)&uvb[cg][l * 8];
        if (step < 63) store_stage(p ^ 1, stn);
#pragma unroll
        for (int mt = 0; mt < 4; mt++)
#pragma unroll
            for (int cg = 0; cg < 8; cg++)
                acc[mt][cg] = __builtin_amdgcn_mfma_f32_16x16x32_bf16(
                    afr[mt], bfr[cg], acc[mt][cg], 0, 0, 0);
        __syncthreads();
        p ^= 1;
    }

    float wb[8];
#pragma unroll
    for (int cg = 0; cg < 8; cg++)
        wb[cg] = ldin(W_base, (size_t)(d0 + cg) * 256 + e0 + l16, fw);
#pragma unroll
    for (int mt = 0; mt < 4; mt++) {
#pragma unroll
        for (int cg = 0; cg < 8; cg++) {
            size_t col = (size_t)(d0 + cg) * 256 + e0 + l16;
#pragma unroll
            for (int r = 0; r < 4; r++) {
                int b = w * 64 + mt * 16 + q * 4 + r;
                Wout[(size_t)b * 65536 + col] = acc[mt][cg][r] + wb[cg];
            }
        }
    }
}

// ---------- h_t + y (reads fp32 W_assembled) ----------
__global__ __launch_bounds__(256) void hty_kernel(
    const float* __restrict__ Wout, const float* __restrict__ hA,
    const float* __restrict__ bass, const void* __restrict__ gamma_p,
    const int* __restrict__ flags, float* __restrict__ y)
{
    const int b = blockIdx.y;
    const int c = blockIdx.x * 4 + (threadIdx.x >> 6);
    const int lane = threadIdx.x & 63;
    const float4 wv = ((const float4*)(Wout + ((size_t)b * 65536 + c * 256)))[lane];
    const float4 h4 = ((const float4*)(hA + b * 256))[lane];
    float s = wv.x * h4.x + wv.y * h4.y + wv.z * h4.z + wv.w * h4.w;
    s = wsum(s);
    if (lane == 0) {
        float ht = s + bass[b * 256 + c];
        y[b * 256 + c] = hA[b * 256 + c] + ldin(gamma_p, 0, flags[IGAMMA]) * ht;
    }
}

// ---------- layernorm ----------
__global__ __launch_bounds__(256) void ln_kernel(
    const float* __restrict__ y, const void* __restrict__ ln_scale,
    const void* __restrict__ ln_bias, const int* __restrict__ flags,
    float* __restrict__ hmid)
{
    const int fs = flags[ILNS], fb = flags[ILNB];
    const int b = blockIdx.x, tid = threadIdx.x;
    float v = y[b * 256 + tid];
    __shared__ float s1b[4], s2b[4];
    float w1 = wsum(v), w2 = wsum(v * v);
    if ((tid & 63) == 0) { s1b[tid >> 6] = w1; s2b[tid >> 6] = w2; }
    __syncthreads();
    float mu = (s1b[0] + s1b[1] + s1b[2] + s1b[3]) * (1.f / 256.f);
    float ex2 = (s2b[0] + s2b[1] + s2b[2] + s2b[3]) * (1.f / 256.f);
    float var = ex2 - mu * mu;
    float inv = 1.f / sqrtf(var + 1e-6f);
    hmid[b * 256 + tid] = (v - mu) * inv * ldin(ln_scale, tid, fs)
                        + ldin(ln_bias, tid, fb);
}

// ---------- launch ----------
extern "C" void kernel_launch(void* const* d_in, const int* in_sizes, int n_in,
                              void* d_out, int out_size, void* d_ws, size_t ws_size,
                              hipStream_t stream)
{
    (void)out_size; (void)n_in;
    const void* x      = d_in[0];
    const void* pool   = d_in[1];
    const void* A_w0   = d_in[2];
    const void* A_b0   = d_in[3];
    const void* A_w1   = d_in[4];
    const void* A_b1   = d_in[5];
    const void* W_Q    = d_in[6];
    const void* W_K    = d_in[7];
    const void* logits = d_in[8];
    const void* tau    = d_in[9];
    const void* W_base = d_in[10];
    const void* b_base = d_in[11];
    const void* gamma  = d_in[12];
    const void* ln_s   = d_in[13];
    const void* ln_b   = d_in[14];
    const void* B_w0   = d_in[15];
    const void* B_b0   = d_in[16];
    const void* B_w1   = d_in[17];
    const void* B_b1   = d_in[18];

    // Outputs: FP32, concatenated in return order.
    float* out       = (float*)d_out;
    float* out0      = out;               // (256,512)
    float* out_alpha = out + 131072;      // (256,2048)
    float* out_W     = out + 655360;      // (256,256,256) = 16.7M floats
    float* out_keys  = out + 17432576;    // (2048,4,64)

    // Small scratch, always in d_ws
    float* ws = (float*)d_ws;
    int*   flagp   = (int*)d_ws;          // ints [0,32)
    float* ws_w    = ws + 32;
    float* ws_hA   = ws + 64;             // 65536
    float* ws_qw   = ws + 65600;          // 65536 (unused this round)
    float* ws_bass = ws + 131136;         // 65536
    float* ws_y    = ws + 196672;         // 65536
    float* ws_hmid = ws + 262208;         // 65536 -> 327744
    unsigned short* alpha_bf = (unsigned short*)(ws + 327744);  // alphaT: 524288 bf16
    // small region ends at 589888 floats (2.36 MB)

    // Big slots: prefer d_ws; fall back to out_W region (dead until assemble).
    size_t wsf = ws_size / 4;
    bool full = wsf >= 1638464;
    float* slotA;   // scores -> T1
    float* slotB;   // knbf
    float* T1;
    float* scr = (float*)out_W;
    if (full) {
        slotA = ws + 589888;
        slotB = ws + 1114176;
        T1    = slotA;
    } else {
        slotA = scr;
        slotB = scr + 524288;
        T1    = (float*)alpha_bf;  // alphaT dead after assemble; 262144 floats fits
    }
    float* scores = slotA;                               // 524288 f
    unsigned short* knbf = (unsigned short*)slotB;       // 524288 sh

    // bf16/fp32 staging buffers in the dead out_W region (all dead before assemble):
    unsigned short* xbf    = (unsigned short*)(scr + 1048576);   // 131072 sh
    unsigned short* aw0T   = (unsigned short*)(scr + 1114112);   // 524288 sh
    unsigned short* aw1T   = (unsigned short*)(scr + 1376256);   // 262144 sh
    unsigned short* wqT    = (unsigned short*)(scr + 1507328);   // 65536 sh
    unsigned short* Gbf    = (unsigned short*)(scr + 1540096);   // 262144 sh
    unsigned short* hAbf   = (unsigned short*)(scr + 1671168);   // 65536 sh
    float*          qraw   = scr + 1703936;                      // 65536 f
    unsigned short* qwbf   = (unsigned short*)(scr + 1769472);   // 65536 sh
    unsigned short* poolbf = (unsigned short*)(scr + 2097152);   // 9.44M sh
    unsigned short* wkbT   = (unsigned short*)(scr + 7340032);   // 1.18M sh
    unsigned short* biasT  = (unsigned short*)(scr + 8388608);   // 524288 sh
    unsigned short* alphaB = (unsigned short*)(scr + 8912896);   // 524288 sh

    // 0) per-input dtype detection
    P19 ip;
    for (int i = 0; i < 19; i++) { ip.p[i] = d_in[i]; ip.n[i] = in_sizes[i]; }
    detect_all<<<19, 256, 0, stream>>>(ip, flagp);
    // 1) aspect softmax
    softmax4_kernel<<<1, 64, 0, stream>>>(logits, flagp, ws_w);
    // 1b) bf16 converts / transposes for MFMA GEMMs
    pool2bf<<<2048, 256, 0, stream>>>(pool, flagp, poolbf);
    wk2bfT<<<dim3(72, 4), 256, 0, stream>>>(W_K, flagp, wkbT);
    bias2bfT<<<dim3(32, 4), 256, 0, stream>>>(pool, flagp, biasT);
    cvt2bf<<<128, 256, 0, stream>>>(x, IX, flagp, xbf, 131072);
    transp_bf<<<dim3(16, 8, 1), 256, 0, stream>>>(A_w0, IAW0, flagp, aw0T, 512, 1024);
    transp_bf<<<dim3(4, 16, 1), 256, 0, stream>>>(A_w1, IAW1, flagp, aw1T, 1024, 256);
    transp_bf<<<dim3(1, 4, 4), 256, 0, stream>>>(W_Q, IWQ, flagp, wqT, 256, 64);
    // 2) A-MLP via fused MFMA: G = gelu(x@A_w0 + b0) -> bf16; hA = G@A_w1 + b1 (f32 + bf16)
    gemm_mfma_fused<1><<<dim3(2, 16), 256, 0, stream>>>(
        xbf, 512, aw0T, 512, A_b0, IAB0, flagp, nullptr, Gbf, 1024, 512);
    gemm_mfma_fused<0><<<dim3(2, 4), 256, 0, stream>>>(
        Gbf, 1024, aw1T, 1024, A_b1, IAB1, flagp, ws_hA, hAbf, 256, 1024);
    // 3) keys = poolbf @ wkbT^T via MFMA split-K atomic, then normalize -> knbf
    init_bias_kernel<<<2048, 256, 0, stream>>>(out_keys, nullptr, -1, flagp, 256, 524288);
    gemm_mfma_atomic<<<dim3(16, 4, 16), 256, 0, stream>>>(
        poolbf, 4608, wkbT, 4608, out_keys, 256, 288);
    knorm_kernel<<<2048, 256, 0, stream>>>(out_keys, knbf);
    // 4) queries: qraw = hAbf @ wqT^T; qnorm folds w[a] -> qwbf
    gemm_mfma_fused<0><<<dim3(2, 4), 256, 0, stream>>>(
        hAbf, 256, wqT, 256, nullptr, -1, flagp, qraw, nullptr, 256, 256);
    qnorm_kernel<<<256, 256, 0, stream>>>(qraw, ws_w, qwbf);
    // 5) scores = qwbf @ knbf^T (direct store)
    gemm_mfma_fused<0><<<dim3(2, 32), 256, 0, stream>>>(
        qwbf, 256, knbf, 256, nullptr, -1, flagp, scores, nullptr, 2048, 256);
    // 6) alpha -> out_alpha (fp32) + alphaT (n-octet bf16) + alphaB (row-major bf16)
    alpha_kernel<<<256, 256, 0, stream>>>(scores, tau, flagp, out_alpha, alpha_bf, alphaB);
    // 7) b_assembled = alpha @ biasT^T + b_base via MFMA split-K atomic
    init_bias_kernel<<<256, 256, 0, stream>>>(ws_bass, b_base, IBBASE, flagp, 256, 65536);
    gemm_mfma_atomic<<<dim3(2, 4, 8), 256, 0, stream>>>(
        alphaB, 2048, biasT, 2048, ws_bass, 256, 256);
    // 8) W_assembled via MFMA (dominant)
    assemble_mfma<<<512, 256, 0, stream>>>(alpha_bf, pool, W_base, flagp, out_W);
    // 9) h_t, y
    hty_kernel<<<dim3(64, 256), 256, 0, stream>>>(out_W, ws_hA, ws_bass, gamma, flagp, ws_y);
    // 10) layernorm
    ln_kernel<<<256, 256, 0, stream>>>(ws_y, ln_s, ln_b, flagp, ws_hmid);
    // 11) B-MLP (kept fp32 for out0 accuracy headroom)
    init_bias_kernel<<<1024, 256, 0, stream>>>(T1, B_b0, IBB0, flagp, 1024, 262144);
    gemm64_splitk<0><<<dim3(16, 4, 2), 256, 0, stream>>>(
        ws_hmid, 256, -1, B_w0, 1024, IBW0, 0,
        T1, 1024, 128, flagp);
    gelu_kernel<<<1024, 256, 0, stream>>>(T1, 262144);
    init_bias_kernel<<<512, 256, 0, stream>>>(out0, B_b1, IBB1, flagp, 512, 131072);
    gemm64_splitk<0><<<dim3(8, 4, 4), 256, 0, stream>>>(
        T1, 1024, -1, B_w1, 512, IBW1, 0,
        out0, 512, 256, flagp);
}

// Round 6
// 556.162 us; speedup vs baseline: 3.8281x; 1.0207x over previous
//
#include <hip/hip_runtime.h>
#include <hip/hip_bf16.h>
#include <math.h>

#define N_POOL 2048
#define D_POOL 4608

typedef __hip_bfloat16 bf16;
typedef __attribute__((ext_vector_type(8))) short bf16x8;
typedef __attribute__((ext_vector_type(4))) float f32x4;
typedef __attribute__((ext_vector_type(4))) unsigned short u16x4;

// input indices
#define IX 0
#define IPOOL 1
#define IAW0 2
#define IAB0 3
#define IAW1 4
#define IAB1 5
#define IWQ 6
#define IWK 7
#define ILOG 8
#define ITAU 9
#define IWBASE 10
#define IBBASE 11
#define IGAMMA 12
#define ILNS 13
#define ILNB 14
#define IBW0 15
#define IBB0 16
#define IBW1 17
#define IBB1 18

// ---------- helpers ----------
__device__ inline float wsum(float v) {
#pragma unroll
    for (int off = 32; off > 0; off >>= 1) v += __shfl_xor(v, off, 64);
    return v;
}
__device__ inline float ldin(const void* p, size_t i, int f) {
    if (f) return __bfloat162float(((const bf16*)p)[i]);
    return ((const float*)p)[i];
}
__device__ inline float gelu_f(float x) {
    float t = tanhf(0.7978845608028654f * (x + 0.044715f * x * x * x));
    return 0.5f * x * (1.0f + t);
}
__device__ inline unsigned short bfbits(float f) {
    __hip_bfloat16 h = __float2bfloat16(f);
    return *reinterpret_cast<unsigned short*>(&h);
}

// ---------- per-input dtype detector (insurance; inputs measured all-fp32) ----------
struct P19 { const void* p[19]; long n[19]; };

__global__ void detect_all(P19 ip, int* flags) {
    const int j = blockIdx.x;
    const unsigned short* u = (const unsigned short*)ip.p[j];
    long nelem = ip.n[j];
    long nhalf = nelem >> 1; if (nhalf < 1) nhalf = 1;
    long kstep = (nhalf + 8191) >> 13; if (kstep < 1) kstep = 1;
    int W = 0, S = 0, Z = 0, O = 0, C = 0;
    for (long k = threadIdx.x; k * kstep < nhalf; k += 256) {
        long i = k * kstep * 2;
        unsigned short ev = u[i], od = u[i + 1];
        int e = (ev >> 7) & 0xFF;
        if (ev == 0) Z++;
        else if (e >= 90 && e <= 141) S++;
        else W++;
        if (od) O++;
        C++;
    }
    __shared__ int sw[256], ss[256], sz[256], so[256], sc[256];
    sw[threadIdx.x] = W; ss[threadIdx.x] = S; sz[threadIdx.x] = Z;
    so[threadIdx.x] = O; sc[threadIdx.x] = C;
    __syncthreads();
    if (threadIdx.x == 0) {
        int tw = 0, ts = 0, tz = 0, to = 0, tc = 0;
        for (int i = 0; i < 256; i++) {
            tw += sw[i]; ts += ss[i]; tz += sz[i]; to += so[i]; tc += sc[i];
        }
        int f;
        if (tw * 16 > tc) f = 0;
        else if (ts == 0 && tw == 0) f = (to > 0) ? 0 : 1;
        else f = (ts >= tz) ? 1 : 0;
        flags[j] = f;
    }
}

// ---------- split-K 64x64 GEMM (fp32 math): atomic accumulate into pre-init C ----------
// afi == -2 means "A is bf16" (literal, no flags lookup).
template <int TRANSB>
__global__ __launch_bounds__(256) void gemm64_splitk(
    const void* __restrict__ A, int lda, int afi,
    const void* __restrict__ B, int ldb, int bfi, size_t boffs,
    float* __restrict__ C, int ldc, int KC, const int* __restrict__ flags)
{
    const int fa = (afi == -2) ? 1 : ((afi >= 0) ? flags[afi] : 0);
    const int fb = (bfi >= 0) ? flags[bfi] : 0;
    __shared__ __align__(16) float As[16][68];
    __shared__ __align__(16) float Bs[16][68];
    const int tid = threadIdx.x;
    const int tx = tid & 15, ty = tid >> 4;
    const int bx = blockIdx.x, by = blockIdx.y;
    const int kbeg = blockIdx.z * KC;
    float acc[4][4] = {};
    for (int k0 = kbeg; k0 < kbeg + KC; k0 += 16) {
#pragma unroll
        for (int i = 0; i < 4; i++) {
            int idx = tid + i * 256;
            int m = idx >> 4, kk = idx & 15;
            As[kk][m] = ldin(A, (size_t)(by * 64 + m) * lda + k0 + kk, fa);
        }
#pragma unroll
        for (int i = 0; i < 4; i++) {
            int idx = tid + i * 256;
            if (TRANSB) {
                int nn2 = idx >> 4, kk = idx & 15;
                Bs[kk][nn2] = ldin(B, boffs + (size_t)(bx * 64 + nn2) * ldb + k0 + kk, fb);
            } else {
                int kk = idx >> 6, nn2 = idx & 63;
                Bs[kk][nn2] = ldin(B, boffs + (size_t)(k0 + kk) * ldb + bx * 64 + nn2, fb);
            }
        }
        __syncthreads();
#pragma unroll
        for (int kk = 0; kk < 16; kk++) {
            float4 av4 = *(const float4*)&As[kk][ty * 4];
            float4 bv4 = *(const float4*)&Bs[kk][tx * 4];
            float av[4] = {av4.x, av4.y, av4.z, av4.w};
            float bv[4] = {bv4.x, bv4.y, bv4.z, bv4.w};
#pragma unroll
            for (int i = 0; i < 4; i++)
#pragma unroll
                for (int j = 0; j < 4; j++) acc[i][j] += av[i] * bv[j];
        }
        __syncthreads();
    }
#pragma unroll
    for (int i = 0; i < 4; i++) {
        int m = by * 64 + ty * 4 + i;
#pragma unroll
        for (int j = 0; j < 4; j++) {
            int n = bx * 64 + tx * 4 + j;
            atomicAdd(&C[(size_t)m * ldc + n], acc[i][j]);
        }
    }
}

// ---------- bf16 MFMA split-K GEMM, no LDS: C += A@B^T (atomic) ----------
// A: bf16 row-major [M][lda]. B: bf16 n-major [ncols][ldb]. Tile 128m x 64n.
__global__ __launch_bounds__(256) void gemm_mfma_atomic(
    const unsigned short* __restrict__ A, int lda,
    const unsigned short* __restrict__ Bmat, int ldb,
    float* __restrict__ C, int ldc, int KC)
{
    const int m0 = blockIdx.x * 128;
    const int n0 = blockIdx.y * 64;
    const unsigned short* B = Bmat + (size_t)blockIdx.y * 64 * ldb;
    const int kbeg = blockIdx.z * KC;
    const int t = threadIdx.x, w = t >> 6, l = t & 63;
    const int q = l >> 4, l16 = l & 15;
    f32x4 acc[2][4] = {};
    for (int k0 = kbeg; k0 < kbeg + KC; k0 += 32) {
        bf16x8 afr[2], bfr[4];
#pragma unroll
        for (int mt = 0; mt < 2; mt++)
            afr[mt] = *(const bf16x8*)&A[(size_t)(m0 + w * 32 + mt * 16 + l16) * lda + k0 + q * 8];
#pragma unroll
        for (int nt = 0; nt < 4; nt++)
            bfr[nt] = *(const bf16x8*)&B[(size_t)(nt * 16 + l16) * ldb + k0 + q * 8];
#pragma unroll
        for (int mt = 0; mt < 2; mt++)
#pragma unroll
            for (int nt = 0; nt < 4; nt++)
                acc[mt][nt] = __builtin_amdgcn_mfma_f32_16x16x32_bf16(
                    afr[mt], bfr[nt], acc[mt][nt], 0, 0, 0);
    }
#pragma unroll
    for (int mt = 0; mt < 2; mt++)
#pragma unroll
        for (int nt = 0; nt < 4; nt++)
#pragma unroll
            for (int r = 0; r < 4; r++) {
                int m = m0 + w * 32 + mt * 16 + q * 4 + r;
                atomicAdd(&C[(size_t)m * ldc + n0 + nt * 16 + l16], acc[mt][nt][r]);
            }
}

// ---------- bf16 MFMA fused GEMM, direct store: out = act(A@B^T + bias) ----------
template <int ACT>
__global__ __launch_bounds__(256) void gemm_mfma_fused(
    const unsigned short* __restrict__ A, int lda,
    const unsigned short* __restrict__ Bmat, int ldb,
    const void* __restrict__ bias, int bifi, const int* __restrict__ flags,
    float* __restrict__ Cf, unsigned short* __restrict__ Cbf,
    int ldc, int K)
{
    const int m0 = blockIdx.x * 128;
    const int n0 = blockIdx.y * 64;
    const unsigned short* B = Bmat + (size_t)blockIdx.y * 64 * ldb;
    const int t = threadIdx.x, w = t >> 6, l = t & 63;
    const int q = l >> 4, l16 = l & 15;
    f32x4 acc[2][4] = {};
    for (int k0 = 0; k0 < K; k0 += 32) {
        bf16x8 afr[2], bfr[4];
#pragma unroll
        for (int mt = 0; mt < 2; mt++)
            afr[mt] = *(const bf16x8*)&A[(size_t)(m0 + w * 32 + mt * 16 + l16) * lda + k0 + q * 8];
#pragma unroll
        for (int nt = 0; nt < 4; nt++)
            bfr[nt] = *(const bf16x8*)&B[(size_t)(nt * 16 + l16) * ldb + k0 + q * 8];
#pragma unroll
        for (int mt = 0; mt < 2; mt++)
#pragma unroll
            for (int nt = 0; nt < 4; nt++)
                acc[mt][nt] = __builtin_amdgcn_mfma_f32_16x16x32_bf16(
                    afr[mt], bfr[nt], acc[mt][nt], 0, 0, 0);
    }
    float bv[4];
#pragma unroll
    for (int nt = 0; nt < 4; nt++)
        bv[nt] = bias ? ldin(bias, n0 + nt * 16 + l16, (bifi >= 0) ? flags[bifi] : 0) : 0.f;
#pragma unroll
    for (int mt = 0; mt < 2; mt++)
#pragma unroll
        for (int nt = 0; nt < 4; nt++)
#pragma unroll
            for (int r = 0; r < 4; r++) {
                int m = m0 + w * 32 + mt * 16 + q * 4 + r;
                int n = n0 + nt * 16 + l16;
                float v = acc[mt][nt][r] + bv[nt];
                if (ACT == 1) v = gelu_f(v);
                if (Cf)  Cf[(size_t)m * ldc + n] = v;
                if (Cbf) Cbf[(size_t)m * ldc + n] = bfbits(v);
            }
}

// ---------- converts: pool -> bf16 row-major ----------
__global__ __launch_bounds__(256) void pool2bf(
    const void* __restrict__ pool, const int* __restrict__ flags,
    unsigned short* __restrict__ pb)
{
    const int fp = flags[IPOOL];
    const size_t total = (size_t)N_POOL * D_POOL;
    for (size_t i = ((size_t)blockIdx.x * 256 + threadIdx.x) * 4; i < total;
         i += (size_t)gridDim.x * 1024) {
        u16x4 o;
        if (fp == 0) {
            float4 v = *(const float4*)((const float*)pool + i);
            o[0] = bfbits(v.x); o[1] = bfbits(v.y); o[2] = bfbits(v.z); o[3] = bfbits(v.w);
        } else {
            o = *(const u16x4*)((const unsigned short*)pool + i);
        }
        *(u16x4*)&pb[i] = o;
    }
}

// ---------- generic fp32/bf16 -> bf16 row-major convert ----------
__global__ __launch_bounds__(256) void cvt2bf(
    const void* __restrict__ src, int fi, const int* __restrict__ flags,
    unsigned short* __restrict__ dst, int total)
{
    const int f = (fi >= 0) ? flags[fi] : 0;
    int i = (blockIdx.x * 256 + threadIdx.x) * 4;
    if (i >= total) return;
    if (f == 0) {
        float4 v = *(const float4*)((const float*)src + i);
        u16x4 o;
        o[0] = bfbits(v.x); o[1] = bfbits(v.y); o[2] = bfbits(v.z); o[3] = bfbits(v.w);
        *(u16x4*)&dst[i] = o;
    } else {
        *(u16x4*)&dst[i] = *(const u16x4*)((const unsigned short*)src + i);
    }
}

// ---------- transpose to bf16: dst[z][c][r] = src[z][r][c]; rows,cols mult of 64 ----------
__global__ __launch_bounds__(256) void transp_bf(
    const void* __restrict__ src, int fi, const int* __restrict__ flags,
    unsigned short* __restrict__ dst, int rows, int cols)
{
    const int f = (fi >= 0) ? flags[fi] : 0;
    const size_t zoff = (size_t)blockIdx.z * rows * cols;
    const int rb = blockIdx.y * 64, cb = blockIdx.x * 64;
    __shared__ float tile[64][65];
    const int t = threadIdx.x;
    const int lr = t >> 6, lc = t & 63;
#pragma unroll
    for (int i = 0; i < 16; i++) {
        int r = i * 4 + lr;
        tile[r][lc] = ldin(src, zoff + (size_t)(rb + r) * cols + cb + lc, f);
    }
    __syncthreads();
#pragma unroll
    for (int i = 0; i < 16; i++) {
        int c = i * 4 + lr;
        dst[zoff + (size_t)(cb + c) * rows + rb + lc] = bfbits(tile[lc][c]);
    }
}

// ---------- W_K fp32 [4][4608][64] -> bf16 n-major [4][64][4608] ----------
__global__ __launch_bounds__(256) void wk2bfT(
    const void* __restrict__ W_K, const int* __restrict__ flags,
    unsigned short* __restrict__ out)
{
    const int fk = flags[IWK];
    const int a = blockIdx.y, kb = blockIdx.x, t = threadIdx.x;
#pragma unroll
    for (int i = 0; i < 16; i++) {
        int idx = i * 256 + t;
        int kk = idx >> 6, qq = idx & 63;
        float v = ldin(W_K, (size_t)a * 294912 + (size_t)(kb * 64 + kk) * 64 + qq, fk);
        out[(size_t)(a * 64 + qq) * 4608 + kb * 64 + kk] = bfbits(v);
    }
}

// ---------- pool[:,4096:4352] -> bf16 col-major [256][2048] ----------
__global__ __launch_bounds__(256) void bias2bfT(
    const void* __restrict__ pool, const int* __restrict__ flags,
    unsigned short* __restrict__ out)
{
    const int fp = flags[IPOOL];
    const int nb = blockIdx.x, cb = blockIdx.y, t = threadIdx.x;
#pragma unroll
    for (int i = 0; i < 16; i++) {
        int idx = i * 256 + t;
        int nn = idx >> 6, cc = idx & 63;
        float v = ldin(pool, (size_t)(nb * 64 + nn) * 4608 + 4096 + cb * 64 + cc, fp);
        out[(size_t)(cb * 64 + cc) * 2048 + nb * 64 + nn] = bfbits(v);
    }
}

// ---------- C[i] = bias[i % N] (or 0) ----------
__global__ __launch_bounds__(256) void init_bias_kernel(
    float* __restrict__ C, const void* __restrict__ bias, int bifi,
    const int* __restrict__ flags, int N, int total)
{
    int i = blockIdx.x * 256 + threadIdx.x;
    if (i >= total) return;
    float v = 0.f;
    if (bias) v = ldin(bias, i % N, (bifi >= 0) ? flags[bifi] : 0);
    C[i] = v;
}

// ---------- per-(n,aspect) normalize -> bf16 ----------
__global__ __launch_bounds__(256) void knorm_kernel(
    const float* __restrict__ keys, unsigned short* __restrict__ knbf)
{
    const int n = blockIdx.x;
    const int a = threadIdx.x >> 6, q = threadIdx.x & 63;
    float v = keys[(size_t)n * 256 + a * 64 + q];
    float ss = wsum(v * v);
    knbf[(size_t)n * 256 + a * 64 + q] = bfbits(v / (sqrtf(ss) + 1e-8f));
}

// ---------- query normalize + aspect-weight fold -> bf16 ----------
__global__ __launch_bounds__(256) void qnorm_kernel(
    const float* __restrict__ qraw, const float* __restrict__ w,
    unsigned short* __restrict__ qwbf)
{
    const int b = blockIdx.x;
    const int a = threadIdx.x >> 6, q = threadIdx.x & 63;
    float v = qraw[b * 256 + a * 64 + q];
    float ss = wsum(v * v);
    qwbf[b * 256 + a * 64 + q] = bfbits(v / (sqrtf(ss) + 1e-8f) * w[a]);
}

// ---------- softmax over 4 aspect logits ----------
__global__ void softmax4_kernel(const void* __restrict__ logits,
                                const int* __restrict__ flags, float* __restrict__ w) {
    if (threadIdx.x == 0) {
        int f = flags[ILOG];
        float l0 = ldin(logits, 0, f), l1 = ldin(logits, 1, f);
        float l2 = ldin(logits, 2, f), l3 = ldin(logits, 3, f);
        float m = fmaxf(fmaxf(l0, l1), fmaxf(l2, l3));
        float e0 = expf(l0 - m), e1 = expf(l1 - m), e2 = expf(l2 - m), e3 = expf(l3 - m);
        float s = e0 + e1 + e2 + e3;
        w[0] = e0 / s; w[1] = e1 / s; w[2] = e2 / s; w[3] = e3 / s;
    }
}

// ---------- alpha: fp32 alpha (b-major, output) + bf16 alphaT (n-octet-major)
//            + bf16 alphaB (row-major) ----------
__global__ __launch_bounds__(256) void alpha_kernel(
    const float* __restrict__ scores, const void* __restrict__ tau_p,
    const int* __restrict__ flags,
    float* __restrict__ alpha_out, unsigned short* __restrict__ alphaT,
    unsigned short* __restrict__ alphaB)
{
    const int b = blockIdx.x;
    const int tid = threadIdx.x;
    const float tauv = ldin(tau_p, 0, flags[ITAU]);
    float ar[8];
    float lsum = 0.f;
#pragma unroll
    for (int i = 0; i < 8; i++) {
        int n = i * 256 + tid;
        float s = scores[b * 2048 + n];
        float g = 1.f / (1.f + expf(-(s - tauv)));  // LAMBDA_SHARP=1
        ar[i] = g * expf(s);                         // TEMPERATURE=1
        lsum += ar[i];
    }
    __shared__ float sb[4];
    float wsv = wsum(lsum);
    if ((tid & 63) == 0) sb[tid >> 6] = wsv;
    __syncthreads();
    float tot = sb[0] + sb[1] + sb[2] + sb[3];
    float inv = 1.f / (tot + 1e-8f);
#pragma unroll
    for (int i = 0; i < 8; i++) {
        int n = i * 256 + tid;
        float al = ar[i] * inv;
        alpha_out[b * 2048 + n] = al;
        unsigned short bb = bfbits(al);
        alphaT[(size_t)(n >> 3) * 2048 + b * 8 + (n & 7)] = bb;
        alphaB[(size_t)b * 2048 + n] = bb;
    }
}

// ---------- W_assembled via MFMA (v4: 4d x 4e generator mapping) ----------
// C[b, c] = sum_n alpha[b,n] * UV[n, c], c = dl*16 + el (8 d x 16 e per block).
// Generator: thread (nl, dh, eq) computes 4d x 4e; U read = 8 contiguous b128,
// V read = 8 b128 (one float4 per r) -> 16 staged reads/thread (was 20).
#define QW 520  // shorts per cg block (260 dwords = 1040 B)
__global__ __launch_bounds__(256, 2) void assemble_mfma(
    const unsigned short* __restrict__ alphaT,  // bf16 [n/8][256 b][8]
    const void* __restrict__ pool,
    const void* __restrict__ W_base,
    const int* __restrict__ flags,
    float* __restrict__ Wout)                   // (256,256,256) fp32
{
    const int fp = flags[IPOOL], fw = flags[IWBASE];
    const int lid = blockIdx.x;
    const int xcd = lid & 7, idx = lid >> 3;
    const int dt = idx & 31;                    // 32 d-tiles
    const int et = ((idx >> 5) << 3) + xcd;     // 16 e-tiles; XCD owns {xcd, xcd+8}
    const int d0 = dt * 8, e0 = et * 16;
    const int t = threadIdx.x;
    const int w = t >> 6, l = t & 63;
    const int q = l >> 4, l16 = l & 15;

    // generator mapping: 1 n x (4 d-rows x 4 e) per thread
    const int nl  = t >> 3;                     // local n 0..31
    const int sub = t & 7;
    const int dh  = sub >> 2;                   // d rows dh*4 .. dh*4+3
    const int eq  = sub & 3;                    // e = eq*4 .. +3
    const int kq  = nl >> 3;                    // == w
    const int jn  = nl & 7;                     // n-octet slot

    __shared__ __align__(16) float Us[2][32][68];   // [n][d_local*8 + r]
    __shared__ __align__(16) float Vs[2][32][132];  // [n][r*16 + e]
    __shared__ __align__(16) unsigned short uvb[8][QW];

    const float4* pool4 = (const float4*)pool;

    f32x4 acc[4][8] = {};

    auto load_stage = [&](int n0, float4* st) {
#pragma unroll
        for (int i = 0; i < 2; i++) {
            int f = i * 256 + t;
            int n = n0 + (f >> 4);
            int q4 = f & 15;
            if (fp == 0) {
                st[i] = pool4[(size_t)n * 1152 + d0 * 2 + q4];
            } else {
                size_t base = (size_t)n * 4608 + (size_t)d0 * 8 + q4 * 4;
                st[i] = make_float4(ldin(pool, base, 1), ldin(pool, base + 1, 1),
                                    ldin(pool, base + 2, 1), ldin(pool, base + 3, 1));
            }
        }
#pragma unroll
        for (int i = 0; i < 4; i++) {
            int f = i * 256 + t;
            int n = n0 + (f >> 5);
            int r = (f & 31) >> 2, e4 = f & 3;
            if (fp == 0) {
                st[2 + i] = pool4[(size_t)n * 1152 + 512 + r * 64 + (e0 >> 2) + e4];
            } else {
                size_t base = (size_t)n * 4608 + 2048 + (size_t)r * 256 + e0 + e4 * 4;
                st[2 + i] = make_float4(ldin(pool, base, 1), ldin(pool, base + 1, 1),
                                        ldin(pool, base + 2, 1), ldin(pool, base + 3, 1));
            }
        }
    };
    auto store_stage = [&](int bp, const float4* st) {
#pragma unroll
        for (int i = 0; i < 2; i++) {
            int f = i * 256 + t;
            *(float4*)&Us[bp][f >> 4][(f & 15) * 4] = st[i];
        }
#pragma unroll
        for (int i = 0; i < 4; i++) {
            int f = i * 256 + t;
            int r = (f & 31) >> 2, e4 = f & 3;
            *(float4*)&Vs[bp][f >> 5][r * 16 + e4 * 4] = st[2 + i];
        }
    };

    {
        float4 st[6];
        load_stage(0, st);
        store_stage(0, st);
    }
    __syncthreads();

    int p = 0;
    for (int step = 0; step < 64; step++) {
        const int n0 = step * 32;
        float4 stn[6];
        if (step < 63) load_stage(n0 + 32, stn);

        bf16x8 afr[4];
#pragma unroll
        for (int mt = 0; mt < 4; mt++) {
            const unsigned short* ap =
                alphaT + (size_t)(step * 4 + q) * 2048 + (w * 64 + mt * 16 + l16) * 8;
            afr[mt] = *(const bf16x8*)ap;
        }

        {
            const float* Ur = &Us[p][nl][dh * 32];
            float U[4][8];
#pragma unroll
            for (int j = 0; j < 4; j++) {
                float4 a = *(const float4*)(Ur + j * 8);
                float4 b = *(const float4*)(Ur + j * 8 + 4);
                U[j][0] = a.x; U[j][1] = a.y; U[j][2] = a.z; U[j][3] = a.w;
                U[j][4] = b.x; U[j][5] = b.y; U[j][6] = b.z; U[j][7] = b.w;
            }
            float uv[4][4] = {};
#pragma unroll
            for (int r = 0; r < 8; r++) {
                float4 v = *(const float4*)&Vs[p][nl][r * 16 + eq * 4];
#pragma unroll
                for (int j = 0; j < 4; j++) {
                    uv[j][0] += U[j][r] * v.x;
                    uv[j][1] += U[j][r] * v.y;
                    uv[j][2] += U[j][r] * v.z;
                    uv[j][3] += U[j][r] * v.w;
                }
            }
#pragma unroll
            for (int j = 0; j < 4; j++) {
                const int cg = dh * 4 + j;
                const int base = kq * 128 + eq * 32 + jn;
#pragma unroll
                for (int i = 0; i < 4; i++)
                    uvb[cg][base + i * 8] = bfbits(uv[j][i]);
            }
        }
        __syncthreads();

        bf16x8 bfr[8];
#pragma unroll
        for (int cg = 0; cg < 8; cg++)
            bfr[cg] = *(const bf16x8*)&uvb[cg][l * 8];
        if (step < 63) store_stage(p ^ 1, stn);
#pragma unroll
        for (int mt = 0; mt < 4; mt++)
#pragma unroll
            for (int cg = 0; cg < 8; cg++)
                acc[mt][cg] = __builtin_amdgcn_mfma_f32_16x16x32_bf16(
                    afr[mt], bfr[cg], acc[mt][cg], 0, 0, 0);
        __syncthreads();
        p ^= 1;
    }

    float wb[8];
#pragma unroll
    for (int cg = 0; cg < 8; cg++)
        wb[cg] = ldin(W_base, (size_t)(d0 + cg) * 256 + e0 + l16, fw);
#pragma unroll
    for (int mt = 0; mt < 4; mt++) {
#pragma unroll
        for (int cg = 0; cg < 8; cg++) {
            size_t col = (size_t)(d0 + cg) * 256 + e0 + l16;
#pragma unroll
            for (int r = 0; r < 4; r++) {
                int b = w * 64 + mt * 16 + q * 4 + r;
                Wout[(size_t)b * 65536 + col] = acc[mt][cg][r] + wb[cg];
            }
        }
    }
}

// ---------- h_t + y (reads fp32 W_assembled) ----------
__global__ __launch_bounds__(256) void hty_kernel(
    const float* __restrict__ Wout, const float* __restrict__ hA,
    const float* __restrict__ bass, const void* __restrict__ gamma_p,
    const int* __restrict__ flags, float* __restrict__ y)
{
    const int b = blockIdx.y;
    const int c = blockIdx.x * 4 + (threadIdx.x >> 6);
    const int lane = threadIdx.x & 63;
    const float4 wv = ((const float4*)(Wout + ((size_t)b * 65536 + c * 256)))[lane];
    const float4 h4 = ((const float4*)(hA + b * 256))[lane];
    float s = wv.x * h4.x + wv.y * h4.y + wv.z * h4.z + wv.w * h4.w;
    s = wsum(s);
    if (lane == 0) {
        float ht = s + bass[b * 256 + c];
        y[b * 256 + c] = hA[b * 256 + c] + ldin(gamma_p, 0, flags[IGAMMA]) * ht;
    }
}

// ---------- layernorm -> bf16 ----------
__global__ __launch_bounds__(256) void ln_kernel(
    const float* __restrict__ y, const void* __restrict__ ln_scale,
    const void* __restrict__ ln_bias, const int* __restrict__ flags,
    unsigned short* __restrict__ hmidbf)
{
    const int fs = flags[ILNS], fb = flags[ILNB];
    const int b = blockIdx.x, tid = threadIdx.x;
    float v = y[b * 256 + tid];
    __shared__ float s1b[4], s2b[4];
    float w1 = wsum(v), w2 = wsum(v * v);
    if ((tid & 63) == 0) { s1b[tid >> 6] = w1; s2b[tid >> 6] = w2; }
    __syncthreads();
    float mu = (s1b[0] + s1b[1] + s1b[2] + s1b[3]) * (1.f / 256.f);
    float ex2 = (s2b[0] + s2b[1] + s2b[2] + s2b[3]) * (1.f / 256.f);
    float var = ex2 - mu * mu;
    float inv = 1.f / sqrtf(var + 1e-6f);
    float hm = (v - mu) * inv * ldin(ln_scale, tid, fs) + ldin(ln_bias, tid, fb);
    hmidbf[b * 256 + tid] = bfbits(hm);
}

// ---------- launch ----------
extern "C" void kernel_launch(void* const* d_in, const int* in_sizes, int n_in,
                              void* d_out, int out_size, void* d_ws, size_t ws_size,
                              hipStream_t stream)
{
    (void)out_size; (void)n_in;
    const void* x      = d_in[0];
    const void* pool   = d_in[1];
    const void* A_w0   = d_in[2];
    const void* A_b0   = d_in[3];
    const void* A_w1   = d_in[4];
    const void* A_b1   = d_in[5];
    const void* W_Q    = d_in[6];
    const void* W_K    = d_in[7];
    const void* logits = d_in[8];
    const void* tau    = d_in[9];
    const void* W_base = d_in[10];
    const void* b_base = d_in[11];
    const void* gamma  = d_in[12];
    const void* ln_s   = d_in[13];
    const void* ln_b   = d_in[14];
    const void* B_w0   = d_in[15];
    const void* B_b0   = d_in[16];
    const void* B_w1   = d_in[17];
    const void* B_b1   = d_in[18];

    // Outputs: FP32, concatenated in return order.
    float* out       = (float*)d_out;
    float* out0      = out;               // (256,512)
    float* out_alpha = out + 131072;      // (256,2048)
    float* out_W     = out + 655360;      // (256,256,256) = 16.7M floats
    float* out_keys  = out + 17432576;    // (2048,4,64)

    // Small scratch, always in d_ws
    float* ws = (float*)d_ws;
    int*   flagp   = (int*)d_ws;          // ints [0,32)
    float* ws_w    = ws + 32;
    float* ws_hA   = ws + 64;             // 65536
    float* ws_bass = ws + 131136;         // 65536
    float* ws_y    = ws + 196672;         // 65536
    unsigned short* hmidbf = (unsigned short*)(ws + 262208);    // 65536 sh (in 65536 f slot)
    unsigned short* alpha_bf = (unsigned short*)(ws + 327744);  // alphaT: 524288 bf16
    // small region ends at 589888 floats (2.36 MB)

    // Big slots: prefer d_ws; fall back to out_W region (dead until assemble).
    size_t wsf = ws_size / 4;
    bool full = wsf >= 1638464;
    float* slotA;   // scores
    float* slotB;   // knbf
    float* Treg;    // post-assemble scratch: T1bf + bw0T (262144 floats)
    float* scr = (float*)out_W;
    if (full) {
        slotA = ws + 589888;
        slotB = ws + 1114176;
        Treg  = ws + 589888;        // reused after assemble
    } else {
        slotA = scr;
        slotB = scr + 524288;
        Treg  = ws + 327744;        // alphaT region, dead after assemble
    }
    float* scores = slotA;                               // 524288 f
    unsigned short* knbf = (unsigned short*)slotB;       // 524288 sh
    unsigned short* T1bf = (unsigned short*)Treg;        // 262144 sh = 131072 f
    unsigned short* bw0T = (unsigned short*)(Treg + 131072);  // 262144 sh

    // bf16/fp32 staging buffers in the dead out_W region (all dead before assemble):
    unsigned short* xbf    = (unsigned short*)(scr + 1048576);   // 131072 sh
    unsigned short* aw0T   = (unsigned short*)(scr + 1114112);   // 524288 sh
    unsigned short* aw1T   = (unsigned short*)(scr + 1376256);   // 262144 sh
    unsigned short* wqT    = (unsigned short*)(scr + 1507328);   // 65536 sh
    unsigned short* Gbf    = (unsigned short*)(scr + 1540096);   // 262144 sh
    unsigned short* hAbf   = (unsigned short*)(scr + 1671168);   // 65536 sh
    float*          qraw   = scr + 1703936;                      // 65536 f
    unsigned short* qwbf   = (unsigned short*)(scr + 1769472);   // 65536 sh
    unsigned short* poolbf = (unsigned short*)(scr + 2097152);   // 9.44M sh
    unsigned short* wkbT   = (unsigned short*)(scr + 7340032);   // 1.18M sh
    unsigned short* biasT  = (unsigned short*)(scr + 8388608);   // 524288 sh
    unsigned short* alphaB = (unsigned short*)(scr + 8912896);   // 524288 sh

    // 0) per-input dtype detection
    P19 ip;
    for (int i = 0; i < 19; i++) { ip.p[i] = d_in[i]; ip.n[i] = in_sizes[i]; }
    detect_all<<<19, 256, 0, stream>>>(ip, flagp);
    // 1) aspect softmax
    softmax4_kernel<<<1, 64, 0, stream>>>(logits, flagp, ws_w);
    // 1b) bf16 converts / transposes for MFMA GEMMs
    pool2bf<<<2048, 256, 0, stream>>>(pool, flagp, poolbf);
    wk2bfT<<<dim3(72, 4), 256, 0, stream>>>(W_K, flagp, wkbT);
    bias2bfT<<<dim3(32, 4), 256, 0, stream>>>(pool, flagp, biasT);
    cvt2bf<<<128, 256, 0, stream>>>(x, IX, flagp, xbf, 131072);
    transp_bf<<<dim3(16, 8, 1), 256, 0, stream>>>(A_w0, IAW0, flagp, aw0T, 512, 1024);
    transp_bf<<<dim3(4, 16, 1), 256, 0, stream>>>(A_w1, IAW1, flagp, aw1T, 1024, 256);
    transp_bf<<<dim3(1, 4, 4), 256, 0, stream>>>(W_Q, IWQ, flagp, wqT, 256, 64);
    // 2) A-MLP via fused MFMA
    gemm_mfma_fused<1><<<dim3(2, 16), 256, 0, stream>>>(
        xbf, 512, aw0T, 512, A_b0, IAB0, flagp, nullptr, Gbf, 1024, 512);
    gemm_mfma_fused<0><<<dim3(2, 4), 256, 0, stream>>>(
        Gbf, 1024, aw1T, 1024, A_b1, IAB1, flagp, ws_hA, hAbf, 256, 1024);
    // 3) keys = poolbf @ wkbT^T via MFMA split-K atomic (z=8), then normalize -> knbf
    init_bias_kernel<<<2048, 256, 0, stream>>>(out_keys, nullptr, -1, flagp, 256, 524288);
    gemm_mfma_atomic<<<dim3(16, 4, 8), 256, 0, stream>>>(
        poolbf, 4608, wkbT, 4608, out_keys, 256, 576);
    knorm_kernel<<<2048, 256, 0, stream>>>(out_keys, knbf);
    // 4) queries: qraw = hAbf @ wqT^T; qnorm folds w[a] -> qwbf
    gemm_mfma_fused<0><<<dim3(2, 4), 256, 0, stream>>>(
        hAbf, 256, wqT, 256, nullptr, -1, flagp, qraw, nullptr, 256, 256);
    qnorm_kernel<<<256, 256, 0, stream>>>(qraw, ws_w, qwbf);
    // 5) scores = qwbf @ knbf^T (direct store)
    gemm_mfma_fused<0><<<dim3(2, 32), 256, 0, stream>>>(
        qwbf, 256, knbf, 256, nullptr, -1, flagp, scores, nullptr, 2048, 256);
    // 6) alpha -> out_alpha (fp32) + alphaT (n-octet bf16) + alphaB (row-major bf16)
    alpha_kernel<<<256, 256, 0, stream>>>(scores, tau, flagp, out_alpha, alpha_bf, alphaB);
    // 7) b_assembled = alpha @ biasT^T + b_base via MFMA split-K atomic
    init_bias_kernel<<<256, 256, 0, stream>>>(ws_bass, b_base, IBBASE, flagp, 256, 65536);
    gemm_mfma_atomic<<<dim3(2, 4, 8), 256, 0, stream>>>(
        alphaB, 2048, biasT, 2048, ws_bass, 256, 256);
    // 8) W_assembled via MFMA (dominant)
    assemble_mfma<<<512, 256, 0, stream>>>(alpha_bf, pool, W_base, flagp, out_W);
    // 8b) B_w0^T transpose (into post-assemble scratch; alphaT region now dead)
    transp_bf<<<dim3(16, 4, 1), 256, 0, stream>>>(B_w0, IBW0, flagp, bw0T, 256, 1024);
    // 9) h_t, y
    hty_kernel<<<dim3(64, 256), 256, 0, stream>>>(out_W, ws_hA, ws_bass, gamma, flagp, ws_y);
    // 10) layernorm -> bf16
    ln_kernel<<<256, 256, 0, stream>>>(ws_y, ln_s, ln_b, flagp, hmidbf);
    // 11) B-MLP1 via fused MFMA (gelu fused) -> T1 bf16
    gemm_mfma_fused<1><<<dim3(2, 16), 256, 0, stream>>>(
        hmidbf, 256, bw0T, 256, B_b0, IBB0, flagp, nullptr, T1bf, 1024, 256);
    // B-MLP2: fp32 split-K atomic reading bf16 T1 (afi=-2), fp32 B_w1
    init_bias_kernel<<<512, 256, 0, stream>>>(out0, B_b1, IBB1, flagp, 512, 131072);
    gemm64_splitk<0><<<dim3(8, 4, 4), 256, 0, stream>>>(
        T1bf, 1024, -2, B_w1, 512, IBW1, 0,
        out0, 512, 256, flagp);
}

// Round 7
// 514.043 us; speedup vs baseline: 4.1418x; 1.0819x over previous
//
#include <hip/hip_runtime.h>
#include <hip/hip_bf16.h>
#include <math.h>

#define N_POOL 2048
#define D_POOL 4608

typedef __hip_bfloat16 bf16;
typedef __attribute__((ext_vector_type(8))) short bf16x8;
typedef __attribute__((ext_vector_type(4))) float f32x4;
typedef __attribute__((ext_vector_type(4))) unsigned short u16x4;

// input indices
#define IX 0
#define IPOOL 1
#define IAW0 2
#define IAB0 3
#define IAW1 4
#define IAB1 5
#define IWQ 6
#define IWK 7
#define ILOG 8
#define ITAU 9
#define IWBASE 10
#define IBBASE 11
#define IGAMMA 12
#define ILNS 13
#define ILNB 14
#define IBW0 15
#define IBB0 16
#define IBW1 17
#define IBB1 18

// ---------- helpers ----------
__device__ inline float wsum(float v) {
#pragma unroll
    for (int off = 32; off > 0; off >>= 1) v += __shfl_xor(v, off, 64);
    return v;
}
__device__ inline float ldin(const void* p, size_t i, int f) {
    if (f) return __bfloat162float(((const bf16*)p)[i]);
    return ((const float*)p)[i];
}
__device__ inline float gelu_f(float x) {
    float t = tanhf(0.7978845608028654f * (x + 0.044715f * x * x * x));
    return 0.5f * x * (1.0f + t);
}
__device__ inline unsigned short bfbits(float f) {
    __hip_bfloat16 h = __float2bfloat16(f);
    return *reinterpret_cast<unsigned short*>(&h);
}

// ---------- per-input dtype detector (insurance; inputs measured all-fp32) ----------
struct P19 { const void* p[19]; long n[19]; };

__global__ void detect_all(P19 ip, int* flags) {
    const int j = blockIdx.x;
    const unsigned short* u = (const unsigned short*)ip.p[j];
    long nelem = ip.n[j];
    long nhalf = nelem >> 1; if (nhalf < 1) nhalf = 1;
    long kstep = (nhalf + 2047) >> 11; if (kstep < 1) kstep = 1;
    int W = 0, S = 0, Z = 0, O = 0, C = 0;
    for (long k = threadIdx.x; k * kstep < nhalf; k += 256) {
        long i = k * kstep * 2;
        unsigned short ev = u[i], od = u[i + 1];
        int e = (ev >> 7) & 0xFF;
        if (ev == 0) Z++;
        else if (e >= 90 && e <= 141) S++;
        else W++;
        if (od) O++;
        C++;
    }
    __shared__ int sw[256], ss[256], sz[256], so[256], sc[256];
    sw[threadIdx.x] = W; ss[threadIdx.x] = S; sz[threadIdx.x] = Z;
    so[threadIdx.x] = O; sc[threadIdx.x] = C;
    __syncthreads();
    if (threadIdx.x == 0) {
        int tw = 0, ts = 0, tz = 0, to = 0, tc = 0;
        for (int i = 0; i < 256; i++) {
            tw += sw[i]; ts += ss[i]; tz += sz[i]; to += so[i]; tc += sc[i];
        }
        int f;
        if (tw * 16 > tc) f = 0;
        else if (ts == 0 && tw == 0) f = (to > 0) ? 0 : 1;
        else f = (ts >= tz) ? 1 : 0;
        flags[j] = f;
    }
}

// ---------- split-K 64x64 GEMM (fp32 math): atomic accumulate into pre-init C ----------
// afi == -2 means "A is bf16" (literal, no flags lookup).
template <int TRANSB>
__global__ __launch_bounds__(256) void gemm64_splitk(
    const void* __restrict__ A, int lda, int afi,
    const void* __restrict__ B, int ldb, int bfi, size_t boffs,
    float* __restrict__ C, int ldc, int KC, const int* __restrict__ flags)
{
    const int fa = (afi == -2) ? 1 : ((afi >= 0) ? flags[afi] : 0);
    const int fb = (bfi >= 0) ? flags[bfi] : 0;
    __shared__ __align__(16) float As[16][68];
    __shared__ __align__(16) float Bs[16][68];
    const int tid = threadIdx.x;
    const int tx = tid & 15, ty = tid >> 4;
    const int bx = blockIdx.x, by = blockIdx.y;
    const int kbeg = blockIdx.z * KC;
    float acc[4][4] = {};
    for (int k0 = kbeg; k0 < kbeg + KC; k0 += 16) {
#pragma unroll
        for (int i = 0; i < 4; i++) {
            int idx = tid + i * 256;
            int m = idx >> 4, kk = idx & 15;
            As[kk][m] = ldin(A, (size_t)(by * 64 + m) * lda + k0 + kk, fa);
        }
#pragma unroll
        for (int i = 0; i < 4; i++) {
            int idx = tid + i * 256;
            if (TRANSB) {
                int nn2 = idx >> 4, kk = idx & 15;
                Bs[kk][nn2] = ldin(B, boffs + (size_t)(bx * 64 + nn2) * ldb + k0 + kk, fb);
            } else {
                int kk = idx >> 6, nn2 = idx & 63;
                Bs[kk][nn2] = ldin(B, boffs + (size_t)(k0 + kk) * ldb + bx * 64 + nn2, fb);
            }
        }
        __syncthreads();
#pragma unroll
        for (int kk = 0; kk < 16; kk++) {
            float4 av4 = *(const float4*)&As[kk][ty * 4];
            float4 bv4 = *(const float4*)&Bs[kk][tx * 4];
            float av[4] = {av4.x, av4.y, av4.z, av4.w};
            float bv[4] = {bv4.x, bv4.y, bv4.z, bv4.w};
#pragma unroll
            for (int i = 0; i < 4; i++)
#pragma unroll
                for (int j = 0; j < 4; j++) acc[i][j] += av[i] * bv[j];
        }
        __syncthreads();
    }
#pragma unroll
    for (int i = 0; i < 4; i++) {
        int m = by * 64 + ty * 4 + i;
#pragma unroll
        for (int j = 0; j < 4; j++) {
            int n = bx * 64 + tx * 4 + j;
            atomicAdd(&C[(size_t)m * ldc + n], acc[i][j]);
        }
    }
}

// ---------- bf16 MFMA split-K GEMM, 1-wave blocks, no LDS: C += A@B^T (atomic) ----------
// A: bf16 row-major [M][lda]. B: bf16 n-major [ncols][ldb]. Tile 32m x 64n per block.
__global__ __launch_bounds__(64) void gemm_mfma_atomic(
    const unsigned short* __restrict__ A, int lda,
    const unsigned short* __restrict__ Bmat, int ldb,
    float* __restrict__ C, int ldc, int KC)
{
    const int m0 = blockIdx.x * 32;
    const int n0 = blockIdx.y * 64;
    const unsigned short* B = Bmat + (size_t)blockIdx.y * 64 * ldb;
    const int kbeg = blockIdx.z * KC;
    const int l = threadIdx.x;
    const int q = l >> 4, l16 = l & 15;
    f32x4 acc[2][4] = {};
    for (int k0 = kbeg; k0 < kbeg + KC; k0 += 32) {
        bf16x8 afr[2], bfr[4];
#pragma unroll
        for (int mt = 0; mt < 2; mt++)
            afr[mt] = *(const bf16x8*)&A[(size_t)(m0 + mt * 16 + l16) * lda + k0 + q * 8];
#pragma unroll
        for (int nt = 0; nt < 4; nt++)
            bfr[nt] = *(const bf16x8*)&B[(size_t)(nt * 16 + l16) * ldb + k0 + q * 8];
#pragma unroll
        for (int mt = 0; mt < 2; mt++)
#pragma unroll
            for (int nt = 0; nt < 4; nt++)
                acc[mt][nt] = __builtin_amdgcn_mfma_f32_16x16x32_bf16(
                    afr[mt], bfr[nt], acc[mt][nt], 0, 0, 0);
    }
#pragma unroll
    for (int mt = 0; mt < 2; mt++)
#pragma unroll
        for (int nt = 0; nt < 4; nt++)
#pragma unroll
            for (int r = 0; r < 4; r++) {
                int m = m0 + mt * 16 + q * 4 + r;
                atomicAdd(&C[(size_t)m * ldc + n0 + nt * 16 + l16], acc[mt][nt][r]);
            }
}

// ---------- bf16 MFMA fused GEMM, 1-wave blocks: out = act(A@B^T + bias) ----------
template <int ACT>
__global__ __launch_bounds__(64) void gemm_mfma_fused(
    const unsigned short* __restrict__ A, int lda,
    const unsigned short* __restrict__ Bmat, int ldb,
    const void* __restrict__ bias, int bifi, const int* __restrict__ flags,
    float* __restrict__ Cf, unsigned short* __restrict__ Cbf,
    int ldc, int K)
{
    const int m0 = blockIdx.x * 32;
    const int n0 = blockIdx.y * 64;
    const unsigned short* B = Bmat + (size_t)blockIdx.y * 64 * ldb;
    const int l = threadIdx.x;
    const int q = l >> 4, l16 = l & 15;
    f32x4 acc[2][4] = {};
    for (int k0 = 0; k0 < K; k0 += 32) {
        bf16x8 afr[2], bfr[4];
#pragma unroll
        for (int mt = 0; mt < 2; mt++)
            afr[mt] = *(const bf16x8*)&A[(size_t)(m0 + mt * 16 + l16) * lda + k0 + q * 8];
#pragma unroll
        for (int nt = 0; nt < 4; nt++)
            bfr[nt] = *(const bf16x8*)&B[(size_t)(nt * 16 + l16) * ldb + k0 + q * 8];
#pragma unroll
        for (int mt = 0; mt < 2; mt++)
#pragma unroll
            for (int nt = 0; nt < 4; nt++)
                acc[mt][nt] = __builtin_amdgcn_mfma_f32_16x16x32_bf16(
                    afr[mt], bfr[nt], acc[mt][nt], 0, 0, 0);
    }
    float bv[4];
#pragma unroll
    for (int nt = 0; nt < 4; nt++)
        bv[nt] = bias ? ldin(bias, n0 + nt * 16 + l16, (bifi >= 0) ? flags[bifi] : 0) : 0.f;
#pragma unroll
    for (int mt = 0; mt < 2; mt++)
#pragma unroll
        for (int nt = 0; nt < 4; nt++)
#pragma unroll
            for (int r = 0; r < 4; r++) {
                int m = m0 + mt * 16 + q * 4 + r;
                int n = n0 + nt * 16 + l16;
                float v = acc[mt][nt][r] + bv[nt];
                if (ACT == 1) v = gelu_f(v);
                if (Cf)  Cf[(size_t)m * ldc + n] = v;
                if (Cbf) Cbf[(size_t)m * ldc + n] = bfbits(v);
            }
}

// ---------- converts: pool -> bf16 row-major ----------
__global__ __launch_bounds__(256) void pool2bf(
    const void* __restrict__ pool, const int* __restrict__ flags,
    unsigned short* __restrict__ pb)
{
    const int fp = flags[IPOOL];
    const size_t total = (size_t)N_POOL * D_POOL;
    for (size_t i = ((size_t)blockIdx.x * 256 + threadIdx.x) * 4; i < total;
         i += (size_t)gridDim.x * 1024) {
        u16x4 o;
        if (fp == 0) {
            float4 v = *(const float4*)((const float*)pool + i);
            o[0] = bfbits(v.x); o[1] = bfbits(v.y); o[2] = bfbits(v.z); o[3] = bfbits(v.w);
        } else {
            o = *(const u16x4*)((const unsigned short*)pool + i);
        }
        *(u16x4*)&pb[i] = o;
    }
}

// ---------- generic fp32/bf16 -> bf16 row-major convert ----------
__global__ __launch_bounds__(256) void cvt2bf(
    const void* __restrict__ src, int fi, const int* __restrict__ flags,
    unsigned short* __restrict__ dst, int total)
{
    const int f = (fi >= 0) ? flags[fi] : 0;
    int i = (blockIdx.x * 256 + threadIdx.x) * 4;
    if (i >= total) return;
    if (f == 0) {
        float4 v = *(const float4*)((const float*)src + i);
        u16x4 o;
        o[0] = bfbits(v.x); o[1] = bfbits(v.y); o[2] = bfbits(v.z); o[3] = bfbits(v.w);
        *(u16x4*)&dst[i] = o;
    } else {
        *(u16x4*)&dst[i] = *(const u16x4*)((const unsigned short*)src + i);
    }
}

// ---------- transpose to bf16: dst[z][c][r] = src[z][r][c]; rows,cols mult of 64 ----------
__global__ __launch_bounds__(256) void transp_bf(
    const void* __restrict__ src, int fi, const int* __restrict__ flags,
    unsigned short* __restrict__ dst, int rows, int cols)
{
    const int f = (fi >= 0) ? flags[fi] : 0;
    const size_t zoff = (size_t)blockIdx.z * rows * cols;
    const int rb = blockIdx.y * 64, cb = blockIdx.x * 64;
    __shared__ float tile[64][65];
    const int t = threadIdx.x;
    const int lr = t >> 6, lc = t & 63;
#pragma unroll
    for (int i = 0; i < 16; i++) {
        int r = i * 4 + lr;
        tile[r][lc] = ldin(src, zoff + (size_t)(rb + r) * cols + cb + lc, f);
    }
    __syncthreads();
#pragma unroll
    for (int i = 0; i < 16; i++) {
        int c = i * 4 + lr;
        dst[zoff + (size_t)(cb + c) * rows + rb + lc] = bfbits(tile[lc][c]);
    }
}

// ---------- W_K fp32 [4][4608][64] -> bf16 n-major [4][64][4608] ----------
__global__ __launch_bounds__(256) void wk2bfT(
    const void* __restrict__ W_K, const int* __restrict__ flags,
    unsigned short* __restrict__ out)
{
    const int fk = flags[IWK];
    const int a = blockIdx.y, kb = blockIdx.x, t = threadIdx.x;
#pragma unroll
    for (int i = 0; i < 16; i++) {
        int idx = i * 256 + t;
        int kk = idx >> 6, qq = idx & 63;
        float v = ldin(W_K, (size_t)a * 294912 + (size_t)(kb * 64 + kk) * 64 + qq, fk);
        out[(size_t)(a * 64 + qq) * 4608 + kb * 64 + kk] = bfbits(v);
    }
}

// ---------- pool[:,4096:4352] -> bf16 col-major [256][2048] ----------
__global__ __launch_bounds__(256) void bias2bfT(
    const void* __restrict__ pool, const int* __restrict__ flags,
    unsigned short* __restrict__ out)
{
    const int fp = flags[IPOOL];
    const int nb = blockIdx.x, cb = blockIdx.y, t = threadIdx.x;
#pragma unroll
    for (int i = 0; i < 16; i++) {
        int idx = i * 256 + t;
        int nn = idx >> 6, cc = idx & 63;
        float v = ldin(pool, (size_t)(nb * 64 + nn) * 4608 + 4096 + cb * 64 + cc, fp);
        out[(size_t)(cb * 64 + cc) * 2048 + nb * 64 + nn] = bfbits(v);
    }
}

// ---------- C[i] = bias[i % N] (or 0) ----------
__global__ __launch_bounds__(256) void init_bias_kernel(
    float* __restrict__ C, const void* __restrict__ bias, int bifi,
    const int* __restrict__ flags, int N, int total)
{
    int i = blockIdx.x * 256 + threadIdx.x;
    if (i >= total) return;
    float v = 0.f;
    if (bias) v = ldin(bias, i % N, (bifi >= 0) ? flags[bifi] : 0);
    C[i] = v;
}

// ---------- per-(n,aspect) normalize -> bf16 ----------
__global__ __launch_bounds__(256) void knorm_kernel(
    const float* __restrict__ keys, unsigned short* __restrict__ knbf)
{
    const int n = blockIdx.x;
    const int a = threadIdx.x >> 6, q = threadIdx.x & 63;
    float v = keys[(size_t)n * 256 + a * 64 + q];
    float ss = wsum(v * v);
    knbf[(size_t)n * 256 + a * 64 + q] = bfbits(v / (sqrtf(ss) + 1e-8f));
}

// ---------- query normalize + aspect-weight fold -> bf16 ----------
__global__ __launch_bounds__(256) void qnorm_kernel(
    const float* __restrict__ qraw, const float* __restrict__ w,
    unsigned short* __restrict__ qwbf)
{
    const int b = blockIdx.x;
    const int a = threadIdx.x >> 6, q = threadIdx.x & 63;
    float v = qraw[b * 256 + a * 64 + q];
    float ss = wsum(v * v);
    qwbf[b * 256 + a * 64 + q] = bfbits(v / (sqrtf(ss) + 1e-8f) * w[a]);
}

// ---------- softmax over 4 aspect logits ----------
__global__ void softmax4_kernel(const void* __restrict__ logits,
                                const int* __restrict__ flags, float* __restrict__ w) {
    if (threadIdx.x == 0) {
        int f = flags[ILOG];
        float l0 = ldin(logits, 0, f), l1 = ldin(logits, 1, f);
        float l2 = ldin(logits, 2, f), l3 = ldin(logits, 3, f);
        float m = fmaxf(fmaxf(l0, l1), fmaxf(l2, l3));
        float e0 = expf(l0 - m), e1 = expf(l1 - m), e2 = expf(l2 - m), e3 = expf(l3 - m);
        float s = e0 + e1 + e2 + e3;
        w[0] = e0 / s; w[1] = e1 / s; w[2] = e2 / s; w[3] = e3 / s;
    }
}

// ---------- alpha: fp32 alpha (b-major, output) + bf16 alphaT (n-octet-major)
//            + bf16 alphaB (row-major) ----------
__global__ __launch_bounds__(256) void alpha_kernel(
    const float* __restrict__ scores, const void* __restrict__ tau_p,
    const int* __restrict__ flags,
    float* __restrict__ alpha_out, unsigned short* __restrict__ alphaT,
    unsigned short* __restrict__ alphaB)
{
    const int b = blockIdx.x;
    const int tid = threadIdx.x;
    const float tauv = ldin(tau_p, 0, flags[ITAU]);
    float ar[8];
    float lsum = 0.f;
#pragma unroll
    for (int i = 0; i < 8; i++) {
        int n = i * 256 + tid;
        float s = scores[b * 2048 + n];
        float g = 1.f / (1.f + expf(-(s - tauv)));  // LAMBDA_SHARP=1
        ar[i] = g * expf(s);                         // TEMPERATURE=1
        lsum += ar[i];
    }
    __shared__ float sb[4];
    float wsv = wsum(lsum);
    if ((tid & 63) == 0) sb[tid >> 6] = wsv;
    __syncthreads();
    float tot = sb[0] + sb[1] + sb[2] + sb[3];
    float inv = 1.f / (tot + 1e-8f);
#pragma unroll
    for (int i = 0; i < 8; i++) {
        int n = i * 256 + tid;
        float al = ar[i] * inv;
        alpha_out[b * 2048 + n] = al;
        unsigned short bb = bfbits(al);
        alphaT[(size_t)(n >> 3) * 2048 + b * 8 + (n & 7)] = bb;
        alphaB[(size_t)b * 2048 + n] = bb;
    }
}

// ---------- W_assembled via MFMA (v3: 8d x 16e tile, 512 blocks, linear uvb) ----------
// REVERTED to the proven round-4/5 version (140.5-141.4 us measured).
#define QW 520  // shorts per cg block (260 dwords = 1040 B)
__global__ __launch_bounds__(256, 2) void assemble_mfma(
    const unsigned short* __restrict__ alphaT,  // bf16 [n/8][256 b][8]
    const void* __restrict__ pool,
    const void* __restrict__ W_base,
    const int* __restrict__ flags,
    float* __restrict__ Wout)                   // (256,256,256) fp32
{
    const int fp = flags[IPOOL], fw = flags[IWBASE];
    const int lid = blockIdx.x;
    const int xcd = lid & 7, idx = lid >> 3;
    const int dt = idx & 31;                    // 32 d-tiles
    const int et = ((idx >> 5) << 3) + xcd;     // 16 e-tiles; XCD owns {xcd, xcd+8}
    const int d0 = dt * 8, e0 = et * 16;
    const int t = threadIdx.x;
    const int w = t >> 6, l = t & 63;
    const int q = l >> 4, l16 = l & 15;

    const int nl  = t >> 3;                     // local n 0..31
    const int sub = t & 7;
    const int dlp = sub >> 1;                   // d rows dlp*2, dlp*2+1
    const int eh  = sub & 1;                    // e-half: el = eh*8 + i
    const int jj  = nl & 7;                     // n-octet slot (kq == w)

    __shared__ __align__(16) float Us[2][32][76];
    __shared__ __align__(16) float Vs[2][32][132];
    __shared__ __align__(16) unsigned short uvb[8][QW];

    const float4* pool4 = (const float4*)pool;

    f32x4 acc[4][8] = {};

    auto load_stage = [&](int n0, float4* st) {
#pragma unroll
        for (int i = 0; i < 2; i++) {
            int f = i * 256 + t;
            int n = n0 + (f >> 4);
            int q4 = f & 15;
            if (fp == 0) {
                st[i] = pool4[(size_t)n * 1152 + d0 * 2 + q4];
            } else {
                size_t base = (size_t)n * 4608 + (size_t)d0 * 8 + q4 * 4;
                st[i] = make_float4(ldin(pool, base, 1), ldin(pool, base + 1, 1),
                                    ldin(pool, base + 2, 1), ldin(pool, base + 3, 1));
            }
        }
#pragma unroll
        for (int i = 0; i < 4; i++) {
            int f = i * 256 + t;
            int n = n0 + (f >> 5);
            int r = (f & 31) >> 2, e4 = f & 3;
            if (fp == 0) {
                st[2 + i] = pool4[(size_t)n * 1152 + 512 + r * 64 + (e0 >> 2) + e4];
            } else {
                size_t base = (size_t)n * 4608 + 2048 + (size_t)r * 256 + e0 + e4 * 4;
                st[2 + i] = make_float4(ldin(pool, base, 1), ldin(pool, base + 1, 1),
                                        ldin(pool, base + 2, 1), ldin(pool, base + 3, 1));
            }
        }
    };
    auto store_stage = [&](int bp, const float4* st) {
#pragma unroll
        for (int i = 0; i < 2; i++) {
            int f = i * 256 + t;
            *(float4*)&Us[bp][f >> 4][(f & 15) * 4] = st[i];
        }
#pragma unroll
        for (int i = 0; i < 4; i++) {
            int f = i * 256 + t;
            int r = (f & 31) >> 2, e4 = f & 3;
            *(float4*)&Vs[bp][f >> 5][r * 16 + e4 * 4] = st[2 + i];
        }
    };

    {
        float4 st[6];
        load_stage(0, st);
        store_stage(0, st);
    }
    __syncthreads();

    int p = 0;
    for (int step = 0; step < 64; step++) {
        const int n0 = step * 32;
        float4 stn[6];
        if (step < 63) load_stage(n0 + 32, stn);

        bf16x8 afr[4];
#pragma unroll
        for (int mt = 0; mt < 4; mt++) {
            const unsigned short* ap =
                alphaT + (size_t)(step * 4 + q) * 2048 + (w * 64 + mt * 16 + l16) * 8;
            afr[mt] = *(const bf16x8*)ap;
        }

        {
            const float* Ur = &Us[p][nl][dlp * 16];
            float4 Ua = *(const float4*)(Ur);
            float4 Ub = *(const float4*)(Ur + 4);
            float4 Uc = *(const float4*)(Ur + 8);
            float4 Ud = *(const float4*)(Ur + 12);
            float U0[8] = {Ua.x, Ua.y, Ua.z, Ua.w, Ub.x, Ub.y, Ub.z, Ub.w};
            float U1[8] = {Uc.x, Uc.y, Uc.z, Uc.w, Ud.x, Ud.y, Ud.z, Ud.w};
            float uv0[8] = {0.f, 0.f, 0.f, 0.f, 0.f, 0.f, 0.f, 0.f};
            float uv1[8] = {0.f, 0.f, 0.f, 0.f, 0.f, 0.f, 0.f, 0.f};
#pragma unroll
            for (int r = 0; r < 8; r++) {
                float4 va = *(const float4*)&Vs[p][nl][r * 16 + eh * 8];
                float4 vb = *(const float4*)&Vs[p][nl][r * 16 + eh * 8 + 4];
                uv0[0] += U0[r] * va.x; uv0[1] += U0[r] * va.y;
                uv0[2] += U0[r] * va.z; uv0[3] += U0[r] * va.w;
                uv0[4] += U0[r] * vb.x; uv0[5] += U0[r] * vb.y;
                uv0[6] += U0[r] * vb.z; uv0[7] += U0[r] * vb.w;
                uv1[0] += U1[r] * va.x; uv1[1] += U1[r] * va.y;
                uv1[2] += U1[r] * va.z; uv1[3] += U1[r] * va.w;
                uv1[4] += U1[r] * vb.x; uv1[5] += U1[r] * vb.y;
                uv1[6] += U1[r] * vb.z; uv1[7] += U1[r] * vb.w;
            }
            const int cg0 = dlp * 2, cg1 = cg0 + 1;
            const int wbase = w * 128 + eh * 64 + jj;
#pragma unroll
            for (int i = 0; i < 8; i++) {
                uvb[cg0][wbase + i * 8] = bfbits(uv0[i]);
                uvb[cg1][wbase + i * 8] = bfbits(uv1[i]);
            }
        }
        __syncthreads();

        bf16x8 bfr[8];
#pragma unroll
        for (int cg = 0; cg < 8; cg++)
            bfr[cg] = *(const bf16x8*)&uvb[cg][l * 8];
        if (step < 63) store_stage(p ^ 1, stn);
#pragma unroll
        for (int mt = 0; mt < 4; mt++)
#pragma unroll
            for (int cg = 0; cg < 8; cg++)
                acc[mt][cg] = __builtin_amdgcn_mfma_f32_16x16x32_bf16(
                    afr[mt], bfr[cg], acc[mt][cg], 0, 0, 0);
        __syncthreads();
        p ^= 1;
    }

    float wb[8];
#pragma unroll
    for (int cg = 0; cg < 8; cg++)
        wb[cg] = ldin(W_base, (size_t)(d0 + cg) * 256 + e0 + l16, fw);
#pragma unroll
    for (int mt = 0; mt < 4; mt++) {
#pragma unroll
        for (int cg = 0; cg < 8; cg++) {
            size_t col = (size_t)(d0 + cg) * 256 + e0 + l16;
#pragma unroll
            for (int r = 0; r < 4; r++) {
                int b = w * 64 + mt * 16 + q * 4 + r;
                Wout[(size_t)b * 65536 + col] = acc[mt][cg][r] + wb[cg];
            }
        }
    }
}

// ---------- h_t + y (reads fp32 W_assembled) ----------
__global__ __launch_bounds__(256) void hty_kernel(
    const float* __restrict__ Wout, const float* __restrict__ hA,
    const float* __restrict__ bass, const void* __restrict__ gamma_p,
    const int* __restrict__ flags, float* __restrict__ y)
{
    const int b = blockIdx.y;
    const int c = blockIdx.x * 4 + (threadIdx.x >> 6);
    const int lane = threadIdx.x & 63;
    const float4 wv = ((const float4*)(Wout + ((size_t)b * 65536 + c * 256)))[lane];
    const float4 h4 = ((const float4*)(hA + b * 256))[lane];
    float s = wv.x * h4.x + wv.y * h4.y + wv.z * h4.z + wv.w * h4.w;
    s = wsum(s);
    if (lane == 0) {
        float ht = s + bass[b * 256 + c];
        y[b * 256 + c] = hA[b * 256 + c] + ldin(gamma_p, 0, flags[IGAMMA]) * ht;
    }
}

// ---------- layernorm -> bf16 ----------
__global__ __launch_bounds__(256) void ln_kernel(
    const float* __restrict__ y, const void* __restrict__ ln_scale,
    const void* __restrict__ ln_bias, const int* __restrict__ flags,
    unsigned short* __restrict__ hmidbf)
{
    const int fs = flags[ILNS], fb = flags[ILNB];
    const int b = blockIdx.x, tid = threadIdx.x;
    float v = y[b * 256 + tid];
    __shared__ float s1b[4], s2b[4];
    float w1 = wsum(v), w2 = wsum(v * v);
    if ((tid & 63) == 0) { s1b[tid >> 6] = w1; s2b[tid >> 6] = w2; }
    __syncthreads();
    float mu = (s1b[0] + s1b[1] + s1b[2] + s1b[3]) * (1.f / 256.f);
    float ex2 = (s2b[0] + s2b[1] + s2b[2] + s2b[3]) * (1.f / 256.f);
    float var = ex2 - mu * mu;
    float inv = 1.f / sqrtf(var + 1e-6f);
    float hm = (v - mu) * inv * ldin(ln_scale, tid, fs) + ldin(ln_bias, tid, fb);
    hmidbf[b * 256 + tid] = bfbits(hm);
}

// ---------- launch ----------
extern "C" void kernel_launch(void* const* d_in, const int* in_sizes, int n_in,
                              void* d_out, int out_size, void* d_ws, size_t ws_size,
                              hipStream_t stream)
{
    (void)out_size; (void)n_in;
    const void* x      = d_in[0];
    const void* pool   = d_in[1];
    const void* A_w0   = d_in[2];
    const void* A_b0   = d_in[3];
    const void* A_w1   = d_in[4];
    const void* A_b1   = d_in[5];
    const void* W_Q    = d_in[6];
    const void* W_K    = d_in[7];
    const void* logits = d_in[8];
    const void* tau    = d_in[9];
    const void* W_base = d_in[10];
    const void* b_base = d_in[11];
    const void* gamma  = d_in[12];
    const void* ln_s   = d_in[13];
    const void* ln_b   = d_in[14];
    const void* B_w0   = d_in[15];
    const void* B_b0   = d_in[16];
    const void* B_w1   = d_in[17];
    const void* B_b1   = d_in[18];

    // Outputs: FP32, concatenated in return order.
    float* out       = (float*)d_out;
    float* out0      = out;               // (256,512)
    float* out_alpha = out + 131072;      // (256,2048)
    float* out_W     = out + 655360;      // (256,256,256) = 16.7M floats
    float* out_keys  = out + 17432576;    // (2048,4,64)

    // Small scratch, always in d_ws
    float* ws = (float*)d_ws;
    int*   flagp   = (int*)d_ws;          // ints [0,32)
    float* ws_w    = ws + 32;
    float* ws_hA   = ws + 64;             // 65536
    float* ws_bass = ws + 131136;         // 65536
    float* ws_y    = ws + 196672;         // 65536
    unsigned short* hmidbf = (unsigned short*)(ws + 262208);    // 65536 sh
    unsigned short* alpha_bf = (unsigned short*)(ws + 327744);  // alphaT: 524288 bf16
    // small region ends at 589888 floats (2.36 MB)

    // Big slots: prefer d_ws; fall back to out_W region (dead until assemble).
    size_t wsf = ws_size / 4;
    bool full = wsf >= 1638464;
    float* slotA;   // scores
    float* slotB;   // knbf
    float* Treg;    // post-assemble scratch: T1bf + bw0T (262144 floats)
    float* scr = (float*)out_W;
    if (full) {
        slotA = ws + 589888;
        slotB = ws + 1114176;
        Treg  = ws + 589888;        // reused after assemble
    } else {
        slotA = scr;
        slotB = scr + 524288;
        Treg  = ws + 327744;        // alphaT region, dead after assemble
    }
    float* scores = slotA;                               // 524288 f
    unsigned short* knbf = (unsigned short*)slotB;       // 524288 sh
    unsigned short* T1bf = (unsigned short*)Treg;        // 262144 sh = 131072 f
    unsigned short* bw0T = (unsigned short*)(Treg + 131072);  // 262144 sh

    // bf16/fp32 staging buffers in the dead out_W region (all dead before assemble):
    unsigned short* xbf    = (unsigned short*)(scr + 1048576);   // 131072 sh
    unsigned short* aw0T   = (unsigned short*)(scr + 1114112);   // 524288 sh
    unsigned short* aw1T   = (unsigned short*)(scr + 1376256);   // 262144 sh
    unsigned short* wqT    = (unsigned short*)(scr + 1507328);   // 65536 sh
    unsigned short* Gbf    = (unsigned short*)(scr + 1540096);   // 262144 sh
    unsigned short* hAbf   = (unsigned short*)(scr + 1671168);   // 65536 sh
    float*          qraw   = scr + 1703936;                      // 65536 f
    unsigned short* qwbf   = (unsigned short*)(scr + 1769472);   // 65536 sh
    unsigned short* poolbf = (unsigned short*)(scr + 2097152);   // 9.44M sh
    unsigned short* wkbT   = (unsigned short*)(scr + 7340032);   // 1.18M sh
    unsigned short* biasT  = (unsigned short*)(scr + 8388608);   // 524288 sh
    unsigned short* alphaB = (unsigned short*)(scr + 8912896);   // 524288 sh

    // 0) per-input dtype detection
    P19 ip;
    for (int i = 0; i < 19; i++) { ip.p[i] = d_in[i]; ip.n[i] = in_sizes[i]; }
    detect_all<<<19, 256, 0, stream>>>(ip, flagp);
    // 1) aspect softmax
    softmax4_kernel<<<1, 64, 0, stream>>>(logits, flagp, ws_w);
    // 1b) bf16 converts / transposes for MFMA GEMMs
    pool2bf<<<2048, 256, 0, stream>>>(pool, flagp, poolbf);
    wk2bfT<<<dim3(72, 4), 256, 0, stream>>>(W_K, flagp, wkbT);
    bias2bfT<<<dim3(32, 4), 256, 0, stream>>>(pool, flagp, biasT);
    cvt2bf<<<128, 256, 0, stream>>>(x, IX, flagp, xbf, 131072);
    transp_bf<<<dim3(16, 8, 1), 256, 0, stream>>>(A_w0, IAW0, flagp, aw0T, 512, 1024);
    transp_bf<<<dim3(4, 16, 1), 256, 0, stream>>>(A_w1, IAW1, flagp, aw1T, 1024, 256);
    transp_bf<<<dim3(1, 4, 4), 256, 0, stream>>>(W_Q, IWQ, flagp, wqT, 256, 64);
    // 2) A-MLP via fused MFMA (1-wave blocks, 4x denser grids)
    gemm_mfma_fused<1><<<dim3(8, 16), 64, 0, stream>>>(
        xbf, 512, aw0T, 512, A_b0, IAB0, flagp, nullptr, Gbf, 1024, 512);
    gemm_mfma_fused<0><<<dim3(8, 4), 64, 0, stream>>>(
        Gbf, 1024, aw1T, 1024, A_b1, IAB1, flagp, ws_hA, hAbf, 256, 1024);
    // 3) keys = poolbf @ wkbT^T via MFMA split-K atomic (1-wave), then normalize -> knbf
    init_bias_kernel<<<2048, 256, 0, stream>>>(out_keys, nullptr, -1, flagp, 256, 524288);
    gemm_mfma_atomic<<<dim3(64, 4, 8), 64, 0, stream>>>(
        poolbf, 4608, wkbT, 4608, out_keys, 256, 576);
    knorm_kernel<<<2048, 256, 0, stream>>>(out_keys, knbf);
    // 4) queries: qraw = hAbf @ wqT^T; qnorm folds w[a] -> qwbf
    gemm_mfma_fused<0><<<dim3(8, 4), 64, 0, stream>>>(
        hAbf, 256, wqT, 256, nullptr, -1, flagp, qraw, nullptr, 256, 256);
    qnorm_kernel<<<256, 256, 0, stream>>>(qraw, ws_w, qwbf);
    // 5) scores = qwbf @ knbf^T (direct store)
    gemm_mfma_fused<0><<<dim3(8, 32), 64, 0, stream>>>(
        qwbf, 256, knbf, 256, nullptr, -1, flagp, scores, nullptr, 2048, 256);
    // 6) alpha -> out_alpha (fp32) + alphaT (n-octet bf16) + alphaB (row-major bf16)
    alpha_kernel<<<256, 256, 0, stream>>>(scores, tau, flagp, out_alpha, alpha_bf, alphaB);
    // 7) b_assembled = alpha @ biasT^T + b_base via MFMA split-K atomic (1-wave)
    init_bias_kernel<<<256, 256, 0, stream>>>(ws_bass, b_base, IBBASE, flagp, 256, 65536);
    gemm_mfma_atomic<<<dim3(8, 4, 8), 64, 0, stream>>>(
        alphaB, 2048, biasT, 2048, ws_bass, 256, 256);
    // 8) W_assembled via MFMA (dominant)
    assemble_mfma<<<512, 256, 0, stream>>>(alpha_bf, pool, W_base, flagp, out_W);
    // 8b) B_w0^T transpose (into post-assemble scratch; alphaT region now dead)
    transp_bf<<<dim3(16, 4, 1), 256, 0, stream>>>(B_w0, IBW0, flagp, bw0T, 256, 1024);
    // 9) h_t, y
    hty_kernel<<<dim3(64, 256), 256, 0, stream>>>(out_W, ws_hA, ws_bass, gamma, flagp, ws_y);
    // 10) layernorm -> bf16
    ln_kernel<<<256, 256, 0, stream>>>(ws_y, ln_s, ln_b, flagp, hmidbf);
    // 11) B-MLP1 via fused MFMA (gelu fused) -> T1 bf16
    gemm_mfma_fused<1><<<dim3(8, 16), 64, 0, stream>>>(
        hmidbf, 256, bw0T, 256, B_b0, IBB0, flagp, nullptr, T1bf, 1024, 256);
    // B-MLP2: fp32 split-K atomic reading bf16 T1 (afi=-2), fp32 B_w1
    init_bias_kernel<<<512, 256, 0, stream>>>(out0, B_b1, IBB1, flagp, 512, 131072);
    gemm64_splitk<0><<<dim3(8, 4, 4), 256, 0, stream>>>(
        T1bf, 1024, -2, B_w1, 512, IBW1, 0,
        out0, 512, 256, flagp);
}